// Round 2
// baseline (11019.420 us; speedup 1.0000x reference)
//
#include <hip/hip_runtime.h>
#include <stdint.h>

#define NS 20
#define NP 8
#define NB 128
#define TT 24
#define FF 256
#define FO_ 256
#define ES 100
#define EP 32
#define NN 28

typedef __attribute__((ext_vector_type(8))) __bf16 bf16x8;
typedef __attribute__((ext_vector_type(4))) float f32x4;

__device__ __forceinline__ unsigned short f2bf(float f) {
  union { float f; unsigned int u; } x; x.f = f;
  unsigned int u = x.u + 0x7fffu + ((x.u >> 16) & 1u);
  return (unsigned short)(u >> 16);
}
__device__ __forceinline__ float bf2f(unsigned short h) {
  union { unsigned int u; float f; } x; x.u = (unsigned int)h << 16; return x.f;
}

// ---------------- graph build: dense propagation + Chebyshev matrices ----------------
__global__ void graph_build(const int* __restrict__ ei_s, const float* __restrict__ ew_s,
                            const int* __restrict__ ei_p, const float* __restrict__ ew_p,
                            float* __restrict__ Ms_s, float* __restrict__ Ms_p) {
  __shared__ float Ao[NS*NS], Aiw[NS*NS], dgo[NS], dgi[NS];
  __shared__ float Aop[NP*NP], Aip[NP*NP], dgop[NP], dgip[NP];
  int tid = threadIdx.x;
  for (int i = tid; i < NS*NS; i += blockDim.x) { Ao[i] = 0.f; Aiw[i] = 0.f; }
  for (int i = tid; i < NP*NP; i += blockDim.x) { Aop[i] = 0.f; Aip[i] = 0.f; }
  if (tid < NS) { dgo[tid] = 0.f; dgi[tid] = 0.f; }
  if (tid < NP) { dgop[tid] = 0.f; dgip[tid] = 0.f; }
  __syncthreads();
  if (tid == 0) {
    for (int e = 0; e < ES; ++e) { int r = ei_s[e], c = ei_s[ES+e]; float w = ew_s[e]; dgo[r] += w; dgi[c] += w; }
    for (int e = 0; e < ES; ++e) { int r = ei_s[e], c = ei_s[ES+e]; Ao[c*NS+r] += 1.f/dgo[r]; Aiw[c*NS+r] += 1.f/dgi[r]; }
  }
  if (tid == 1) {
    for (int e = 0; e < EP; ++e) { int r = ei_p[e], c = ei_p[EP+e]; float w = ew_p[e]; dgop[r] += w; dgip[c] += w; }
    for (int e = 0; e < EP; ++e) { int r = ei_p[e], c = ei_p[EP+e]; Aop[c*NP+r] += 1.f/dgop[r]; Aip[c*NP+r] += 1.f/dgip[r]; }
  }
  __syncthreads();
  for (int i = tid; i < NS*NS; i += blockDim.x) {
    int r = i / NS, c = i % NS;
    float so = 0.f, si = 0.f;
    for (int k = 0; k < NS; ++k) { so += Ao[r*NS+k]*Ao[k*NS+c]; si += Aiw[r*NS+k]*Aiw[k*NS+c]; }
    Ms_s[0*NS*NS + i] = Ao[i];
    Ms_s[1*NS*NS + i] = Aiw[i];
    Ms_s[2*NS*NS + i] = 2.f*so - (r==c ? 1.f : 0.f);
    Ms_s[3*NS*NS + i] = 2.f*si - (r==c ? 1.f : 0.f);
  }
  for (int i = tid; i < NP*NP; i += blockDim.x) {
    Ms_p[0*NP*NP + i] = Aop[i];
    Ms_p[1*NP*NP + i] = Aip[i];
  }
}

// ---------------- weight prep: term-concatenated, transposed (N x K), bf16 hi+lo ----------------
__device__ __forceinline__ float wsrc(const float* W, int Kdim, int tau, int i, int jj) {
  // W layout: [2][Kdim][512][256]
  if (tau == 0) return W[(size_t)(0*Kdim+0)*512*256 + (size_t)i*256 + jj]
                     + W[(size_t)(1*Kdim+0)*512*256 + (size_t)i*256 + jj];
  int dir = (tau - 1) & 1;
  int k = (tau + 1) >> 1;
  return W[(size_t)(dir*Kdim + k)*512*256 + (size_t)i*256 + jj];
}

__device__ __forceinline__ void put_hl(unsigned short* dst, size_t idx, size_t plane, float v) {
  unsigned short hi = f2bf(v);
  dst[idx] = hi;
  dst[idx + plane] = f2bf(v - bf2f(hi));
}

__global__ void prep_w(const float* __restrict__ Wz_s, const float* __restrict__ Wr_s, const float* __restrict__ Wh_s,
                       const float* __restrict__ Wz_p, const float* __restrict__ Wr_p, const float* __restrict__ Wh_p,
                       unsigned short* __restrict__ Wzr_s_t, unsigned short* __restrict__ Wh_s_t,
                       unsigned short* __restrict__ Wzr_p_t, unsigned short* __restrict__ Wh_p_t) {
  const int KS = 5*512, KP = 3*512;
  const long n0 = (long)512*KS, n1 = (long)256*KS, n2 = (long)512*KP, n3 = (long)256*KP;
  const long total = n0 + n1 + n2 + n3;
  for (long idx = (long)blockIdx.x*256 + threadIdx.x; idx < total; idx += (long)gridDim.x*256) {
    if (idx < n0) {
      long x = idx; int j = (int)(x / KS), c = (int)(x % KS); int tau = c >> 9, i = c & 511;
      const float* W = (j < 256) ? Wz_s : Wr_s; int jj = j & 255;
      put_hl(Wzr_s_t, (size_t)j*KS + c, n0, wsrc(W, 3, tau, i, jj));
    } else if (idx < n0 + n1) {
      long x = idx - n0; int j = (int)(x / KS), c = (int)(x % KS); int tau = c >> 9, i = c & 511;
      put_hl(Wh_s_t, (size_t)j*KS + c, n1, wsrc(Wh_s, 3, tau, i, j));
    } else if (idx < n0 + n1 + n2) {
      long x = idx - n0 - n1; int j = (int)(x / KP), c = (int)(x % KP); int tau = c >> 9, i = c & 511;
      const float* W = (j < 256) ? Wz_p : Wr_p; int jj = j & 255;
      put_hl(Wzr_p_t, (size_t)j*KP + c, n2, wsrc(W, 2, tau, i, jj));
    } else {
      long x = idx - n0 - n1 - n2; int j = (int)(x / KP), c = (int)(x % KP); int tau = c >> 9, i = c & 511;
      put_hl(Wh_p_t, (size_t)j*KP + c, n3, wsrc(Wh_p, 2, tau, i, j));
    }
  }
}

__global__ void zero_f(float* p, int n) {
  int i = blockIdx.x*256 + threadIdx.x;
  if (i < n) p[i] = 0.f;
}

// ---------------- Chebyshev term expansion: [X_t, Hsrc] -> XT (bf16 hi+lo, term-concat K) ----------------
__global__ __launch_bounds__(256) void cheb(const float* __restrict__ xdis, const float* __restrict__ xpre,
                                            const float* __restrict__ Hsrc,
                                            const float* __restrict__ Ms_s, const float* __restrict__ Ms_p,
                                            unsigned short* __restrict__ XTs, unsigned short* __restrict__ XTp,
                                            size_t planeS, size_t planeP, int t) {
  __shared__ float Xc[NS*512];
  __shared__ float Ml[4*NS*NS];
  int bb = blockIdx.x;
  int tid = threadIdx.x;
  bool isP = (bb >= NB);
  int b = isP ? bb - NB : bb;
  int N = isP ? NP : NS;
  int nt = isP ? 3 : 5;
  int klen = nt * 512;
  const float* X = isP ? (xpre + (size_t)(b*TT + t)*NP*FF) : (xdis + (size_t)(b*TT + t)*NS*FF);
  int hoff = isP ? NS : 0;
  for (int i = tid; i < N*FF; i += 256) {
    int n = i >> 8, f = i & 255;
    Xc[n*512 + f] = X[(size_t)n*FF + f];
    Xc[n*512 + 256 + f] = Hsrc[((size_t)b*NN + hoff + n)*FO_ + f];
  }
  int nm = (nt - 1) * N * N;
  const float* Msrc = isP ? Ms_p : Ms_s;
  for (int i = tid; i < nm; i += 256) Ml[i] = Msrc[i];
  __syncthreads();
  unsigned short* XT = isP ? XTp : XTs;
  size_t plane = isP ? planeP : planeS;
  for (int i = tid; i < N*klen; i += 256) {
    int n = i / klen, c = i % klen;
    int tau = c >> 9, f = c & 511;
    float v;
    if (tau == 0) v = Xc[n*512 + f];
    else {
      const float* M = Ml + (tau-1)*N*N + n*N;
      v = 0.f;
      for (int r = 0; r < N; ++r) v += M[r] * Xc[r*512 + f];
    }
    put_hl(XT, (size_t)(b*N + n)*klen + c, plane, v);
  }
}

// ---------------- split-bf16 MFMA GEMM: C = (Ah+Al)*(Bh+Bl)^T, 3-term; two problems per launch ----------------
__global__ __launch_bounds__(256) void gemm2(
    const unsigned short* __restrict__ A0, const unsigned short* __restrict__ B0, float* __restrict__ C0,
    int nb0, int K0, size_t plA0, size_t plB0,
    const unsigned short* __restrict__ A1, const unsigned short* __restrict__ B1, float* __restrict__ C1,
    int K1_, size_t plA1, size_t plB1, int N) {
  __shared__ __align__(16) unsigned short lA[2][64*64];
  __shared__ __align__(16) unsigned short lB[2][64*64];
  const unsigned short *Ah, *Al, *Bh, *Bl; float* C; int K, row0;
  int bx = blockIdx.x;
  if (bx < nb0) { Ah = A0; Al = A0 + plA0; Bh = B0; Bl = B0 + plB0; C = C0; K = K0; row0 = bx*64; }
  else          { Ah = A1; Al = A1 + plA1; Bh = B1; Bl = B1 + plB1; C = C1; K = K1_; row0 = (bx - nb0)*64; }
  int col0 = blockIdx.y * 64;
  int tid = threadIdx.x;
  int lane = tid & 63;
  int l15 = lane & 15, l4 = lane >> 4;
  int wid = tid >> 6;
  int wr = (wid >> 1) * 32, wc = (wid & 1) * 32;
  f32x4 acc[2][2];
#pragma unroll
  for (int i = 0; i < 2; ++i)
#pragma unroll
    for (int j = 0; j < 2; ++j) acc[i][j] = (f32x4){0.f, 0.f, 0.f, 0.f};

  int lro[2]; size_t goffA[2], goffB[2];
#pragma unroll
  for (int q = 0; q < 2; ++q) {
    int chunk = q*256 + tid;            // 512 chunks of 16B per tile
    int r = chunk >> 3, blk = chunk & 7;
    lro[q] = r*64 + (blk ^ (r & 7))*8;  // XOR-swizzled LDS slot (elements)
    goffA[q] = (size_t)(row0 + r)*K + blk*8;
    goffB[q] = (size_t)(col0 + r)*K + blk*8;
  }

  for (int k0 = 0; k0 < K; k0 += 64) {
    uint4 va[2][2], vb[2][2];
#pragma unroll
    for (int q = 0; q < 2; ++q) {
      va[0][q] = *(const uint4*)(Ah + goffA[q] + k0);
      va[1][q] = *(const uint4*)(Al + goffA[q] + k0);
      vb[0][q] = *(const uint4*)(Bh + goffB[q] + k0);
      vb[1][q] = *(const uint4*)(Bl + goffB[q] + k0);
    }
    __syncthreads();                     // prior iter's LDS reads done
#pragma unroll
    for (int q = 0; q < 2; ++q) {
      *(uint4*)&lA[0][lro[q]] = va[0][q];
      *(uint4*)&lA[1][lro[q]] = va[1][q];
      *(uint4*)&lB[0][lro[q]] = vb[0][q];
      *(uint4*)&lB[1][lro[q]] = vb[1][q];
    }
    __syncthreads();
#pragma unroll
    for (int kk = 0; kk < 2; ++kk) {
      bf16x8 af[2][2], bfr[2][2];   // [plane][frag]
#pragma unroll
      for (int mi = 0; mi < 2; ++mi) {
        int r = wr + mi*16 + l15;
        int sb = (kk*4 + l4) ^ (r & 7);
        af[0][mi] = *(const bf16x8*)&lA[0][r*64 + sb*8];
        af[1][mi] = *(const bf16x8*)&lA[1][r*64 + sb*8];
      }
#pragma unroll
      for (int ni = 0; ni < 2; ++ni) {
        int r = wc + ni*16 + l15;
        int sb = (kk*4 + l4) ^ (r & 7);
        bfr[0][ni] = *(const bf16x8*)&lB[0][r*64 + sb*8];
        bfr[1][ni] = *(const bf16x8*)&lB[1][r*64 + sb*8];
      }
#pragma unroll
      for (int mi = 0; mi < 2; ++mi)
#pragma unroll
        for (int ni = 0; ni < 2; ++ni) {
          acc[mi][ni] = __builtin_amdgcn_mfma_f32_16x16x32_bf16(af[0][mi], bfr[0][ni], acc[mi][ni], 0, 0, 0);
          acc[mi][ni] = __builtin_amdgcn_mfma_f32_16x16x32_bf16(af[0][mi], bfr[1][ni], acc[mi][ni], 0, 0, 0);
          acc[mi][ni] = __builtin_amdgcn_mfma_f32_16x16x32_bf16(af[1][mi], bfr[0][ni], acc[mi][ni], 0, 0, 0);
        }
    }
  }
#pragma unroll
  for (int mi = 0; mi < 2; ++mi)
#pragma unroll
    for (int ni = 0; ni < 2; ++ni) {
      int rowb = row0 + wr + mi*16 + l4*4;
      int col = col0 + wc + ni*16 + l15;
#pragma unroll
      for (int rg = 0; rg < 4; ++rg)
        C[(size_t)(rowb + rg)*N + col] = acc[mi][ni][rg];
    }
}

// ---------------- elementwise GRU pieces ----------------
__global__ __launch_bounds__(256) void gates_k(const float* __restrict__ pZR_s, const float* __restrict__ pZR_p,
                                               const float* __restrict__ bz_s, const float* __restrict__ br_s,
                                               const float* __restrict__ bz_p, const float* __restrict__ br_p,
                                               const float* __restrict__ H, float* __restrict__ Z, float* __restrict__ gH) {
  int idx = blockIdx.x*256 + threadIdx.x;   // < NB*NN*256
  int f = idx & 255;
  int bn = idx >> 8;
  int n = bn % NN, b = bn / NN;
  float pz, pr, bz, br;
  if (n < NS) { const float* p = pZR_s + ((size_t)(b*NS + n))*512; pz = p[f]; pr = p[256+f]; bz = bz_s[f]; br = br_s[f]; }
  else        { const float* p = pZR_p + ((size_t)(b*NP + n - NS))*512; pz = p[f]; pr = p[256+f]; bz = bz_p[f]; br = br_p[f]; }
  float z = 1.f/(1.f + expf(-(pz + bz)));
  float r = 1.f/(1.f + expf(-(pr + br)));
  float h = H[idx];
  Z[idx] = z;
  gH[idx] = h * r;
}

__global__ __launch_bounds__(256) void update_k(const float* __restrict__ pH_s, const float* __restrict__ pH_p,
                                                const float* __restrict__ bh_s, const float* __restrict__ bh_p,
                                                const float* __restrict__ Z, float* __restrict__ H) {
  int idx = blockIdx.x*256 + threadIdx.x;
  int f = idx & 255;
  int bn = idx >> 8;
  int n = bn % NN, b = bn / NN;
  float pre, bh;
  if (n < NS) { pre = pH_s[((size_t)(b*NS + n))*256 + f]; bh = bh_s[f]; }
  else        { pre = pH_p[((size_t)(b*NP + n - NS))*256 + f]; bh = bh_p[f]; }
  float ht = tanhf(pre + bh);
  float z = Z[idx];
  H[idx] = z*H[idx] + (1.f - z)*ht;
}

// ---------------- readout ----------------
__global__ __launch_bounds__(256) void readout_k(const float* __restrict__ H, const float* __restrict__ W_ro,
                                                 const float* __restrict__ b_ro, const float* __restrict__ W_ag,
                                                 const float* __restrict__ b_ag, float* __restrict__ out) {
  __shared__ float red[256];
  __shared__ float o1[NN];
  int b = blockIdx.x, tid = threadIdx.x;
  float wro = W_ro[tid];
  for (int n = 0; n < NN; ++n) {
    red[tid] = H[((size_t)b*NN + n)*256 + tid] * wro;
    __syncthreads();
    for (int s = 128; s > 0; s >>= 1) { if (tid < s) red[tid] += red[tid+s]; __syncthreads(); }
    if (tid == 0) o1[n] = red[0] + b_ro[0];
    __syncthreads();
  }
  if (tid < 5) {
    float s = b_ag[tid];
    for (int n = 0; n < NN; ++n) s += o1[n] * W_ag[n*5 + tid];
    out[b*5 + tid] = s;
  }
}

// ---------------- host ----------------
extern "C" void kernel_launch(void* const* d_in, const int* in_sizes, int n_in,
                              void* d_out, int out_size, void* d_ws, size_t ws_size,
                              hipStream_t stream) {
  const float* xdis = (const float*)d_in[0];
  const float* xpre = (const float*)d_in[1];
  const int*   ei_s = (const int*)d_in[2];
  const int*   ei_p = (const int*)d_in[3];
  const float* ew_s = (const float*)d_in[4];
  const float* ew_p = (const float*)d_in[5];
  const float* Wz_s = (const float*)d_in[6];
  const float* bz_s = (const float*)d_in[7];
  const float* Wr_s = (const float*)d_in[8];
  const float* br_s = (const float*)d_in[9];
  const float* Wh_s = (const float*)d_in[10];
  const float* bh_s = (const float*)d_in[11];
  const float* Wz_p = (const float*)d_in[12];
  const float* bz_p = (const float*)d_in[13];
  const float* Wr_p = (const float*)d_in[14];
  const float* br_p = (const float*)d_in[15];
  const float* Wh_p = (const float*)d_in[16];
  const float* bh_p = (const float*)d_in[17];
  const float* W_ro = (const float*)d_in[18];
  const float* b_ro = (const float*)d_in[19];
  const float* W_ag = (const float*)d_in[20];
  const float* b_ag = (const float*)d_in[21];
  float* out = (float*)d_out;

  char* w = (char*)d_ws;
  size_t off = 0;
  auto alloc = [&](size_t bytes) { void* p = w + off; off = (off + bytes + 255) & ~(size_t)255; return p; };
  const int KS = 2560, KP = 1536, MS = NB*NS, MP = NB*NP;
  // hi/lo plane sizes (elements)
  const size_t plWzr_s = (size_t)512*KS, plWh_s = (size_t)256*KS;
  const size_t plWzr_p = (size_t)512*KP, plWh_p = (size_t)256*KP;
  const size_t plXs = (size_t)MS*KS, plXp = (size_t)MP*KP;
  float* Ms_s = (float*)alloc(4*NS*NS*sizeof(float));
  float* Ms_p = (float*)alloc(2*NP*NP*sizeof(float));
  unsigned short* Wzr_s_t = (unsigned short*)alloc(plWzr_s*2*2);
  unsigned short* Wh_s_t  = (unsigned short*)alloc(plWh_s*2*2);
  unsigned short* Wzr_p_t = (unsigned short*)alloc(plWzr_p*2*2);
  unsigned short* Wh_p_t  = (unsigned short*)alloc(plWh_p*2*2);
  unsigned short* XTs = (unsigned short*)alloc(plXs*2*2);
  unsigned short* XTp = (unsigned short*)alloc(plXp*2*2);
  float* pZR_s = (float*)alloc((size_t)MS*512*4);
  float* pZR_p = (float*)alloc((size_t)MP*512*4);
  float* pH_s  = (float*)alloc((size_t)MS*256*4);
  float* pH_p  = (float*)alloc((size_t)MP*256*4);
  float* H  = (float*)alloc((size_t)NB*NN*256*4);
  float* Z  = (float*)alloc((size_t)NB*NN*256*4);
  float* gH = (float*)alloc((size_t)NB*NN*256*4);
  (void)ws_size; (void)in_sizes; (void)n_in; (void)out_size;

  graph_build<<<1, 64, 0, stream>>>(ei_s, ew_s, ei_p, ew_p, Ms_s, Ms_p);
  prep_w<<<2048, 256, 0, stream>>>(Wz_s, Wr_s, Wh_s, Wz_p, Wr_p, Wh_p, Wzr_s_t, Wh_s_t, Wzr_p_t, Wh_p_t);
  const int nH = NB*NN*256;
  zero_f<<<(nH + 255)/256, 256, 0, stream>>>(H, nH);

  for (int t = 0; t < TT; ++t) {
    cheb<<<256, 256, 0, stream>>>(xdis, xpre, H, Ms_s, Ms_p, XTs, XTp, plXs, plXp, t);
    { dim3 g(40 + 16, 8); gemm2<<<g, 256, 0, stream>>>(XTs, Wzr_s_t, pZR_s, 40, KS, plXs, plWzr_s,
                                                        XTp, Wzr_p_t, pZR_p, KP, plXp, plWzr_p, 512); }
    gates_k<<<nH/256, 256, 0, stream>>>(pZR_s, pZR_p, bz_s, br_s, bz_p, br_p, H, Z, gH);
    cheb<<<256, 256, 0, stream>>>(xdis, xpre, gH, Ms_s, Ms_p, XTs, XTp, plXs, plXp, t);
    { dim3 g(40 + 16, 4); gemm2<<<g, 256, 0, stream>>>(XTs, Wh_s_t, pH_s, 40, KS, plXs, plWh_s,
                                                        XTp, Wh_p_t, pH_p, KP, plXp, plWh_p, 256); }
    update_k<<<nH/256, 256, 0, stream>>>(pH_s, pH_p, bh_s, bh_p, Z, H);
  }
  readout_k<<<NB, 256, 0, stream>>>(H, W_ro, b_ro, W_ag, b_ag, out);
}

// Round 3
// 8771.911 us; speedup vs baseline: 1.2562x; 1.2562x over previous
//
#include <hip/hip_runtime.h>
#include <stdint.h>

#define NSN 20
#define NPN 8
#define NB 128
#define TT 24
#define NN 28
#define ES 100
#define EP 32
#define KHS 1280   // 5*256
#define KHP 768    // 3*256
#define NPRE 768   // z|r|h output cols
#define TCH 4      // precompute time-chunk

typedef __attribute__((ext_vector_type(8))) __bf16 bf16x8;
typedef __attribute__((ext_vector_type(4))) float f32x4;
typedef unsigned short ushort_t;

__device__ __forceinline__ ushort_t f2bf(float f) {
  union { float f; unsigned int u; } x; x.f = f;
  unsigned int u = x.u + 0x7fffu + ((x.u >> 16) & 1u);
  return (ushort_t)(u >> 16);
}
__device__ __forceinline__ float bf2f(ushort_t h) {
  union { unsigned int u; float f; } x; x.u = (unsigned int)h << 16; return x.f;
}
__device__ __forceinline__ void put_hl(ushort_t* dst, size_t idx, size_t plane, float v) {
  ushort_t hi = f2bf(v);
  dst[idx] = hi;
  dst[idx + plane] = f2bf(v - bf2f(hi));
}

// ---------------- graph build: dense propagation + Chebyshev matrices ----------------
__global__ void graph_build(const int* __restrict__ ei_s, const float* __restrict__ ew_s,
                            const int* __restrict__ ei_p, const float* __restrict__ ew_p,
                            float* __restrict__ Ms_s, float* __restrict__ Ms_p) {
  __shared__ float Ao[NSN*NSN], Aiw[NSN*NSN], dgo[NSN], dgi[NSN];
  __shared__ float Aop[NPN*NPN], Aip[NPN*NPN], dgop[NPN], dgip[NPN];
  int tid = threadIdx.x;
  for (int i = tid; i < NSN*NSN; i += blockDim.x) { Ao[i] = 0.f; Aiw[i] = 0.f; }
  for (int i = tid; i < NPN*NPN; i += blockDim.x) { Aop[i] = 0.f; Aip[i] = 0.f; }
  if (tid < NSN) { dgo[tid] = 0.f; dgi[tid] = 0.f; }
  if (tid < NPN) { dgop[tid] = 0.f; dgip[tid] = 0.f; }
  __syncthreads();
  if (tid == 0) {
    for (int e = 0; e < ES; ++e) { int r = ei_s[e], c = ei_s[ES+e]; float w = ew_s[e]; dgo[r] += w; dgi[c] += w; }
    for (int e = 0; e < ES; ++e) { int r = ei_s[e], c = ei_s[ES+e]; Ao[c*NSN+r] += 1.f/dgo[r]; Aiw[c*NSN+r] += 1.f/dgi[r]; }
  }
  if (tid == 1) {
    for (int e = 0; e < EP; ++e) { int r = ei_p[e], c = ei_p[EP+e]; float w = ew_p[e]; dgop[r] += w; dgip[c] += w; }
    for (int e = 0; e < EP; ++e) { int r = ei_p[e], c = ei_p[EP+e]; Aop[c*NPN+r] += 1.f/dgop[r]; Aip[c*NPN+r] += 1.f/dgip[r]; }
  }
  __syncthreads();
  for (int i = tid; i < NSN*NSN; i += blockDim.x) {
    int r = i / NSN, c = i % NSN;
    float so = 0.f, si = 0.f;
    for (int k = 0; k < NSN; ++k) { so += Ao[r*NSN+k]*Ao[k*NSN+c]; si += Aiw[r*NSN+k]*Aiw[k*NSN+c]; }
    Ms_s[0*NSN*NSN + i] = Ao[i];
    Ms_s[1*NSN*NSN + i] = Aiw[i];
    Ms_s[2*NSN*NSN + i] = 2.f*so - (r==c ? 1.f : 0.f);
    Ms_s[3*NSN*NSN + i] = 2.f*si - (r==c ? 1.f : 0.f);
  }
  for (int i = tid; i < NPN*NPN; i += blockDim.x) {
    Ms_p[0*NPN*NPN + i] = Aop[i];
    Ms_p[1*NPN*NPN + i] = Aip[i];
  }
}

// ---------------- weight prep ----------------
// Source W layout [2][Kdim][512][256]. term tau: 0 -> sum dirs k=0; odd -> dir0 k=(tau+1)/2; even -> dir1 k=tau/2+...
__device__ __forceinline__ float wsrc(const float* W, int Kdim, int tau, int i, int jj) {
  if (tau == 0) return W[(size_t)(0*Kdim+0)*512*256 + (size_t)i*256 + jj]
                     + W[(size_t)(1*Kdim+0)*512*256 + (size_t)i*256 + jj];
  int dir = (tau - 1) & 1;
  int k = (tau + 1) >> 1;
  return W[(size_t)(dir*Kdim + k)*512*256 + (size_t)i*256 + jj];
}

// Outputs (Bt layout [j=0..767][K], hi plane then lo plane):
//  WX_*: rows i=f (X half);  WH_*: rows i=256+f (H half). j<256 -> Wz, <512 -> Wr, else Wh.
__global__ void prep_w(const float* __restrict__ Wz_s, const float* __restrict__ Wr_s, const float* __restrict__ Wh_s,
                       const float* __restrict__ Wz_p, const float* __restrict__ Wr_p, const float* __restrict__ Wh_p,
                       ushort_t* __restrict__ WX_s, ushort_t* __restrict__ WH_s,
                       ushort_t* __restrict__ WX_p, ushort_t* __restrict__ WH_p) {
  const long nS = (long)768*KHS, nP = (long)768*KHP;
  const long total = 2*nS + 2*nP;
  for (long idx = (long)blockIdx.x*256 + threadIdx.x; idx < total; idx += (long)gridDim.x*256) {
    ushort_t* buf; long x; int K, Kdim; bool isH; const float *Wz, *Wr, *Wh;
    if (idx < nS)            { buf = WX_s; x = idx;          K = KHS; Kdim = 3; isH = false; Wz=Wz_s; Wr=Wr_s; Wh=Wh_s; }
    else if (idx < 2*nS)     { buf = WH_s; x = idx - nS;     K = KHS; Kdim = 3; isH = true;  Wz=Wz_s; Wr=Wr_s; Wh=Wh_s; }
    else if (idx < 2*nS+nP)  { buf = WX_p; x = idx - 2*nS;   K = KHP; Kdim = 2; isH = false; Wz=Wz_p; Wr=Wr_p; Wh=Wh_p; }
    else                     { buf = WH_p; x = idx - 2*nS-nP; K = KHP; Kdim = 2; isH = true; Wz=Wz_p; Wr=Wr_p; Wh=Wh_p; }
    int j = (int)(x / K), c = (int)(x % K);
    int tau = c >> 8, f = c & 255;
    const float* W = (j < 256) ? Wz : (j < 512) ? Wr : Wh;
    int jj = j & 255;
    int i = isH ? (256 + f) : f;
    put_hl(buf, (size_t)j*K + c, (size_t)768*K, wsrc(W, Kdim, tau, i, jj));
  }
}

__global__ void zero_f(float* p, int n) {
  int i = blockIdx.x*256 + threadIdx.x;
  if (i < n) p[i] = 0.f;
}

// ---------------- cheb expansion of X for a time chunk ----------------
__global__ __launch_bounds__(256) void chebx(const float* __restrict__ xdis, const float* __restrict__ xpre,
                                             const float* __restrict__ Ms_s, const float* __restrict__ Ms_p,
                                             ushort_t* __restrict__ XTs, ushort_t* __restrict__ XTp,
                                             size_t plXs, size_t plXp, int t0) {
  __shared__ float Xc[NSN*256];
  __shared__ float Ml[4*NSN*NSN];
  int bb = blockIdx.x, tid = threadIdx.x;
  bool isP = bb >= NB*TCH;
  int q = isP ? bb - NB*TCH : bb;
  int b = q % NB, tp = q / NB;
  int N = isP ? NPN : NSN, nt = isP ? 3 : 5, KX = nt*256;
  const float* X = isP ? (xpre + (size_t)(b*TT + t0 + tp)*NPN*256)
                       : (xdis + (size_t)(b*TT + t0 + tp)*NSN*256);
  for (int i = tid; i < N*256; i += 256) Xc[i] = X[i];
  int nm = (nt-1)*N*N;
  const float* Msrc = isP ? Ms_p : Ms_s;
  for (int i = tid; i < nm; i += 256) Ml[i] = Msrc[i];
  __syncthreads();
  ushort_t* XT = isP ? XTp : XTs;
  size_t plane = isP ? plXp : plXs;
  size_t rowbase = (size_t)(tp*NB + b)*N;
  for (int i = tid; i < N*KX; i += 256) {
    int n = i / KX, c = i % KX, tau = c >> 8, f = c & 255;
    float v;
    if (tau == 0) v = Xc[n*256 + f];
    else {
      const float* M = Ml + (tau-1)*N*N + n*N;
      v = 0.f;
      for (int r = 0; r < N; ++r) v += M[r]*Xc[r*256 + f];
    }
    put_hl(XT, (rowbase + n)*KX + c, plane, v);
  }
}

// ---------------- cheb expansion of H (or gH) per step ----------------
__global__ __launch_bounds__(256) void cheb_h(const float* __restrict__ Hsrc,
                                              const float* __restrict__ Ms_s, const float* __restrict__ Ms_p,
                                              ushort_t* __restrict__ XTs, ushort_t* __restrict__ XTp,
                                              size_t plXs, size_t plXp) {
  __shared__ float Xc[NSN*256];
  __shared__ float Ml[4*NSN*NSN];
  int bb = blockIdx.x, tid = threadIdx.x;
  bool isP = bb >= NB;
  int b = isP ? bb - NB : bb;
  int N = isP ? NPN : NSN, nt = isP ? 3 : 5, KX = nt*256, hoff = isP ? NSN : 0;
  for (int i = tid; i < N*256; i += 256) {
    int n = i >> 8, f = i & 255;
    Xc[i] = Hsrc[((size_t)b*NN + hoff + n)*256 + f];
  }
  int nm = (nt-1)*N*N;
  const float* Msrc = isP ? Ms_p : Ms_s;
  for (int i = tid; i < nm; i += 256) Ml[i] = Msrc[i];
  __syncthreads();
  ushort_t* XT = isP ? XTp : XTs;
  size_t plane = isP ? plXp : plXs;
  size_t rowbase = (size_t)b*N;
  for (int i = tid; i < N*KX; i += 256) {
    int n = i / KX, c = i % KX, tau = c >> 8, f = c & 255;
    float v;
    if (tau == 0) v = Xc[n*256 + f];
    else {
      const float* M = Ml + (tau-1)*N*N + n*N;
      v = 0.f;
      for (int r = 0; r < N; ++r) v += M[r]*Xc[r*256 + f];
    }
    put_hl(XT, (rowbase + n)*KX + c, plane, v);
  }
}

// ---------------- split-bf16 MFMA GEMM, 64x128 tile, fused epilogues ----------------
// MODE 0: Px_out = bf16(acc + bias)          (precompute, N=768)
// MODE 1: z/r = sigmoid(acc + Px); Z or gH   (N=512: cols<256 z, >=256 r)
// MODE 2: H = Z*H + (1-Z)*tanh(acc + Px_h)   (N=256)
template<int MODE>
__global__ __launch_bounds__(256) void gemm_k(
    const ushort_t* __restrict__ A0, const ushort_t* __restrict__ B0, int K0, size_t plA0, size_t plB0, int rbS,
    const ushort_t* __restrict__ A1, const ushort_t* __restrict__ B1, int K1, size_t plA1, size_t plB1,
    ushort_t* __restrict__ Px0, ushort_t* __restrict__ Px1,
    const float* __restrict__ bz0, const float* __restrict__ br0, const float* __restrict__ bh0,
    const float* __restrict__ bz1, const float* __restrict__ br1, const float* __restrict__ bh1,
    const float* __restrict__ Hin, float* __restrict__ Z, float* __restrict__ gH, float* __restrict__ Hout) {
  __shared__ __align__(16) ushort_t lA[2][64*64];
  __shared__ __align__(16) ushort_t lB[2][128*64];
  int rb = blockIdx.x, cb = blockIdx.y;
  bool isP = rb >= rbS;
  const ushort_t* A = isP ? A1 : A0;
  const ushort_t* B = isP ? B1 : B0;
  int K = isP ? K1 : K0;
  size_t plA = isP ? plA1 : plA0, plB = isP ? plB1 : plB0;
  int row0 = (isP ? rb - rbS : rb) * 64;
  int col0 = cb * 128;
  int tid = threadIdx.x, lane = tid & 63, wid = tid >> 6;
  int l15 = lane & 15, l4 = lane >> 4;
  int wr = (wid >> 1) * 32, wc = (wid & 1) * 64;

  f32x4 acc[2][4];
#pragma unroll
  for (int i = 0; i < 2; ++i)
#pragma unroll
    for (int j = 0; j < 4; ++j) acc[i][j] = (f32x4){0.f,0.f,0.f,0.f};

  // staging geometry: 16B chunks
  int rbase = tid >> 3, kblk = tid & 7;
  int slotA[2], slotB[4];
  size_t goffA[2], goffB[4];
#pragma unroll
  for (int q = 0; q < 2; ++q) {
    int r = rbase + q*32;
    slotA[q] = r*64 + ((kblk ^ (r & 7))*8);
    goffA[q] = (size_t)(row0 + r)*K + kblk*8;
  }
#pragma unroll
  for (int q = 0; q < 4; ++q) {
    int r = rbase + q*32;
    slotB[q] = r*64 + ((kblk ^ (r & 7))*8);
    goffB[q] = (size_t)(col0 + r)*K + kblk*8;
  }

  uint4 vA[2][2], vB[4][2];
#pragma unroll
  for (int q = 0; q < 2; ++q) {
    vA[q][0] = *(const uint4*)(A + goffA[q]);
    vA[q][1] = *(const uint4*)(A + goffA[q] + plA);
  }
#pragma unroll
  for (int q = 0; q < 4; ++q) {
    vB[q][0] = *(const uint4*)(B + goffB[q]);
    vB[q][1] = *(const uint4*)(B + goffB[q] + plB);
  }

  for (int k0 = 0; k0 < K; k0 += 64) {
    __syncthreads();   // prior iter's LDS reads complete
#pragma unroll
    for (int q = 0; q < 2; ++q) {
      *(uint4*)&lA[0][slotA[q]] = vA[q][0];
      *(uint4*)&lA[1][slotA[q]] = vA[q][1];
    }
#pragma unroll
    for (int q = 0; q < 4; ++q) {
      *(uint4*)&lB[0][slotB[q]] = vB[q][0];
      *(uint4*)&lB[1][slotB[q]] = vB[q][1];
    }
    __syncthreads();
    if (k0 + 64 < K) {   // prefetch next K-step while MFMAs run
      int kn = k0 + 64;
#pragma unroll
      for (int q = 0; q < 2; ++q) {
        vA[q][0] = *(const uint4*)(A + goffA[q] + kn);
        vA[q][1] = *(const uint4*)(A + goffA[q] + kn + plA);
      }
#pragma unroll
      for (int q = 0; q < 4; ++q) {
        vB[q][0] = *(const uint4*)(B + goffB[q] + kn);
        vB[q][1] = *(const uint4*)(B + goffB[q] + kn + plB);
      }
    }
#pragma unroll
    for (int kk = 0; kk < 2; ++kk) {
      bf16x8 af[2][2], bq[2][4];
#pragma unroll
      for (int mi = 0; mi < 2; ++mi) {
        int r = wr + mi*16 + l15;
        int sb = (kk*4 + l4) ^ (r & 7);
        af[0][mi] = *(const bf16x8*)&lA[0][r*64 + sb*8];
        af[1][mi] = *(const bf16x8*)&lA[1][r*64 + sb*8];
      }
#pragma unroll
      for (int ni = 0; ni < 4; ++ni) {
        int r = wc + ni*16 + l15;
        int sb = (kk*4 + l4) ^ (r & 7);
        bq[0][ni] = *(const bf16x8*)&lB[0][r*64 + sb*8];
        bq[1][ni] = *(const bf16x8*)&lB[1][r*64 + sb*8];
      }
#pragma unroll
      for (int mi = 0; mi < 2; ++mi)
#pragma unroll
        for (int ni = 0; ni < 4; ++ni) {
          acc[mi][ni] = __builtin_amdgcn_mfma_f32_16x16x32_bf16(af[0][mi], bq[0][ni], acc[mi][ni], 0, 0, 0);
          acc[mi][ni] = __builtin_amdgcn_mfma_f32_16x16x32_bf16(af[0][mi], bq[1][ni], acc[mi][ni], 0, 0, 0);
          acc[mi][ni] = __builtin_amdgcn_mfma_f32_16x16x32_bf16(af[1][mi], bq[0][ni], acc[mi][ni], 0, 0, 0);
        }
    }
  }

  // epilogue
  int NODE = isP ? NPN : NSN;
  int hoff = isP ? NSN : 0;
  const ushort_t* Px = isP ? Px1 : Px0;
  ushort_t* PxO = isP ? Px1 : Px0;
#pragma unroll
  for (int mi = 0; mi < 2; ++mi)
#pragma unroll
    for (int ni = 0; ni < 4; ++ni) {
      int colg = col0 + wc + ni*16 + l15;
#pragma unroll
      for (int rg = 0; rg < 4; ++rg) {
        int grow = row0 + wr + mi*16 + l4*4 + rg;
        float v = acc[mi][ni][rg];
        if constexpr (MODE == 0) {
          const float* bias = (colg < 256) ? (isP ? bz1 : bz0)
                            : (colg < 512) ? (isP ? br1 : br0)
                                           : (isP ? bh1 : bh0);
          PxO[(size_t)grow*NPRE + colg] = f2bf(v + bias[colg & 255]);
        } else {
          int hrow = (grow / NODE)*NN + grow % NODE + hoff;
          if constexpr (MODE == 1) {
            float p = bf2f(Px[(size_t)grow*NPRE + colg]);
            float s = 1.f/(1.f + expf(-(v + p)));
            int hcol = colg & 255;
            size_t hidx = (size_t)hrow*256 + hcol;
            if (colg < 256) Z[hidx] = s;
            else            gH[hidx] = s * Hin[hidx];
          } else {
            float p = bf2f(Px[(size_t)grow*NPRE + 512 + colg]);
            float ht = tanhf(v + p);
            size_t hidx = (size_t)hrow*256 + colg;
            float z = Z[hidx];
            Hout[hidx] = z*Hin[hidx] + (1.f - z)*ht;
          }
        }
      }
    }
}

// ---------------- readout ----------------
__global__ __launch_bounds__(256) void readout_k(const float* __restrict__ H, const float* __restrict__ W_ro,
                                                 const float* __restrict__ b_ro, const float* __restrict__ W_ag,
                                                 const float* __restrict__ b_ag, float* __restrict__ out) {
  __shared__ float red[256];
  __shared__ float o1[NN];
  int b = blockIdx.x, tid = threadIdx.x;
  float wro = W_ro[tid];
  for (int n = 0; n < NN; ++n) {
    red[tid] = H[((size_t)b*NN + n)*256 + tid] * wro;
    __syncthreads();
    for (int s = 128; s > 0; s >>= 1) { if (tid < s) red[tid] += red[tid+s]; __syncthreads(); }
    if (tid == 0) o1[n] = red[0] + b_ro[0];
    __syncthreads();
  }
  if (tid < 5) {
    float s = b_ag[tid];
    for (int n = 0; n < NN; ++n) s += o1[n] * W_ag[n*5 + tid];
    out[b*5 + tid] = s;
  }
}

// ---------------- host ----------------
extern "C" void kernel_launch(void* const* d_in, const int* in_sizes, int n_in,
                              void* d_out, int out_size, void* d_ws, size_t ws_size,
                              hipStream_t stream) {
  const float* xdis = (const float*)d_in[0];
  const float* xpre = (const float*)d_in[1];
  const int*   ei_s = (const int*)d_in[2];
  const int*   ei_p = (const int*)d_in[3];
  const float* ew_s = (const float*)d_in[4];
  const float* ew_p = (const float*)d_in[5];
  const float* Wz_s = (const float*)d_in[6];
  const float* bz_s = (const float*)d_in[7];
  const float* Wr_s = (const float*)d_in[8];
  const float* br_s = (const float*)d_in[9];
  const float* Wh_s = (const float*)d_in[10];
  const float* bh_s = (const float*)d_in[11];
  const float* Wz_p = (const float*)d_in[12];
  const float* bz_p = (const float*)d_in[13];
  const float* Wr_p = (const float*)d_in[14];
  const float* br_p = (const float*)d_in[15];
  const float* Wh_p = (const float*)d_in[16];
  const float* bh_p = (const float*)d_in[17];
  const float* W_ro = (const float*)d_in[18];
  const float* b_ro = (const float*)d_in[19];
  const float* W_ag = (const float*)d_in[20];
  const float* b_ag = (const float*)d_in[21];
  float* out = (float*)d_out;
  (void)in_sizes; (void)n_in; (void)out_size; (void)ws_size;

  char* w = (char*)d_ws;
  size_t off = 0;
  auto alloc = [&](size_t bytes) { void* p = w + off; off = (off + bytes + 255) & ~(size_t)255; return p; };

  // plane sizes (elements)
  const size_t plWXs = (size_t)768*KHS, plWHs = (size_t)768*KHS;
  const size_t plWXp = (size_t)768*KHP, plWHp = (size_t)768*KHP;
  const size_t rowsXs = (size_t)TCH*NB*NSN;   // 10240
  const size_t rowsXp = (size_t)TCH*NB*NPN;   // 4096
  const size_t plXs_pre = rowsXs*KHS, plXp_pre = rowsXp*KHP;
  const size_t plXs_rec = (size_t)NB*NSN*KHS, plXp_rec = (size_t)NB*NPN*KHP;

  float* Ms_s = (float*)alloc(4*NSN*NSN*sizeof(float));
  float* Ms_p = (float*)alloc(2*NPN*NPN*sizeof(float));
  ushort_t* WX_s = (ushort_t*)alloc(plWXs*2*2);
  ushort_t* WH_s = (ushort_t*)alloc(plWHs*2*2);
  ushort_t* WX_p = (ushort_t*)alloc(plWXp*2*2);
  ushort_t* WH_p = (ushort_t*)alloc(plWHp*2*2);
  ushort_t* XT_s = (ushort_t*)alloc(plXs_pre*2*2);   // reused: precompute chunks + recurrent cheb(H)
  ushort_t* XT_p = (ushort_t*)alloc(plXp_pre*2*2);
  ushort_t* Px_s = (ushort_t*)alloc((size_t)TT*NB*NSN*NPRE*2);   // 94.4 MB bf16
  ushort_t* Px_p = (ushort_t*)alloc((size_t)TT*NB*NPN*NPRE*2);   // 37.8 MB
  float* H  = (float*)alloc((size_t)NB*NN*256*4);
  float* Z  = (float*)alloc((size_t)NB*NN*256*4);
  float* gH = (float*)alloc((size_t)NB*NN*256*4);

  graph_build<<<1, 64, 0, stream>>>(ei_s, ew_s, ei_p, ew_p, Ms_s, Ms_p);
  prep_w<<<1024, 256, 0, stream>>>(Wz_s, Wr_s, Wh_s, Wz_p, Wr_p, Wh_p, WX_s, WH_s, WX_p, WH_p);
  const int nH = NB*NN*256;
  zero_f<<<(nH + 255)/256, 256, 0, stream>>>(H, nH);

  // ---- precompute Px over all t, chunked ----
  for (int t0 = 0; t0 < TT; t0 += TCH) {
    chebx<<<2*NB*TCH, 256, 0, stream>>>(xdis, xpre, Ms_s, Ms_p, XT_s, XT_p, plXs_pre, plXp_pre, t0);
    gemm_k<0><<<dim3(224, 6), 256, 0, stream>>>(
        XT_s, WX_s, KHS, plXs_pre, plWXs, 160,
        XT_p, WX_p, KHP, plXp_pre, plWXp,
        Px_s + (size_t)t0*NB*NSN*NPRE, Px_p + (size_t)t0*NB*NPN*NPRE,
        bz_s, br_s, bh_s, bz_p, br_p, bh_p,
        nullptr, nullptr, nullptr, nullptr);
  }

  // ---- recurrence ----
  for (int t = 0; t < TT; ++t) {
    ushort_t* PxS = Px_s + (size_t)t*NB*NSN*NPRE;
    ushort_t* PxP = Px_p + (size_t)t*NB*NPN*NPRE;
    cheb_h<<<2*NB, 256, 0, stream>>>(H, Ms_s, Ms_p, XT_s, XT_p, plXs_rec, plXp_rec);
    gemm_k<1><<<dim3(56, 4), 256, 0, stream>>>(
        XT_s, WH_s, KHS, plXs_rec, plWHs, 40,
        XT_p, WH_p, KHP, plXp_rec, plWHp,
        PxS, PxP,
        nullptr, nullptr, nullptr, nullptr, nullptr, nullptr,
        H, Z, gH, nullptr);
    cheb_h<<<2*NB, 256, 0, stream>>>(gH, Ms_s, Ms_p, XT_s, XT_p, plXs_rec, plXp_rec);
    gemm_k<2><<<dim3(56, 2), 256, 0, stream>>>(
        XT_s, WH_s + (size_t)512*KHS, KHS, plXs_rec, plWHs, 40,
        XT_p, WH_p + (size_t)512*KHP, KHP, plXp_rec, plWHp,
        PxS, PxP,
        nullptr, nullptr, nullptr, nullptr, nullptr, nullptr,
        H, Z, nullptr, H);
  }
  readout_k<<<NB, 256, 0, stream>>>(H, W_ro, b_ro, W_ag, b_ag, out);
}

// Round 4
// 3776.553 us; speedup vs baseline: 2.9179x; 2.3227x over previous
//
#include <hip/hip_runtime.h>
#include <stdint.h>

#define NSN 20
#define NPN 8
#define NB 128
#define TT 24
#define NN 28
#define ES 100
#define EP 32
#define KHS 1280   // 5*256
#define KHP 768    // 3*256
#define NPRE 768   // z|r|h output cols
#define TCH 4      // precompute time-chunk

typedef __attribute__((ext_vector_type(8))) __bf16 bf16x8;
typedef __attribute__((ext_vector_type(4))) float f32x4;
typedef unsigned short ushort_t;

__device__ __forceinline__ ushort_t f2bf(float f) {
  union { float f; unsigned int u; } x; x.f = f;
  unsigned int u = x.u + 0x7fffu + ((x.u >> 16) & 1u);
  return (ushort_t)(u >> 16);
}
__device__ __forceinline__ float bf2f(ushort_t h) {
  union { unsigned int u; float f; } x; x.u = (unsigned int)h << 16; return x.f;
}
__device__ __forceinline__ void put_hl(ushort_t* dst, size_t idx, size_t plane, float v) {
  ushort_t hi = f2bf(v);
  dst[idx] = hi;
  dst[idx + plane] = f2bf(v - bf2f(hi));
}
__device__ __forceinline__ void gl16(const ushort_t* g, ushort_t* l) {
  __builtin_amdgcn_global_load_lds((const __attribute__((address_space(1))) void*)g,
                                   (__attribute__((address_space(3))) void*)l, 16, 0, 0);
}

// ---------------- graph build: dense propagation + Chebyshev matrices ----------------
__global__ void graph_build(const int* __restrict__ ei_s, const float* __restrict__ ew_s,
                            const int* __restrict__ ei_p, const float* __restrict__ ew_p,
                            float* __restrict__ Ms_s, float* __restrict__ Ms_p) {
  __shared__ float Ao[NSN*NSN], Aiw[NSN*NSN], dgo[NSN], dgi[NSN];
  __shared__ float Aop[NPN*NPN], Aip[NPN*NPN], dgop[NPN], dgip[NPN];
  int tid = threadIdx.x;
  for (int i = tid; i < NSN*NSN; i += blockDim.x) { Ao[i] = 0.f; Aiw[i] = 0.f; }
  for (int i = tid; i < NPN*NPN; i += blockDim.x) { Aop[i] = 0.f; Aip[i] = 0.f; }
  if (tid < NSN) { dgo[tid] = 0.f; dgi[tid] = 0.f; }
  if (tid < NPN) { dgop[tid] = 0.f; dgip[tid] = 0.f; }
  __syncthreads();
  if (tid == 0) {
    for (int e = 0; e < ES; ++e) { int r = ei_s[e], c = ei_s[ES+e]; float w = ew_s[e]; dgo[r] += w; dgi[c] += w; }
    for (int e = 0; e < ES; ++e) { int r = ei_s[e], c = ei_s[ES+e]; Ao[c*NSN+r] += 1.f/dgo[r]; Aiw[c*NSN+r] += 1.f/dgi[r]; }
  }
  if (tid == 1) {
    for (int e = 0; e < EP; ++e) { int r = ei_p[e], c = ei_p[EP+e]; float w = ew_p[e]; dgop[r] += w; dgip[c] += w; }
    for (int e = 0; e < EP; ++e) { int r = ei_p[e], c = ei_p[EP+e]; Aop[c*NPN+r] += 1.f/dgop[r]; Aip[c*NPN+r] += 1.f/dgip[r]; }
  }
  __syncthreads();
  for (int i = tid; i < NSN*NSN; i += blockDim.x) {
    int r = i / NSN, c = i % NSN;
    float so = 0.f, si = 0.f;
    for (int k = 0; k < NSN; ++k) { so += Ao[r*NSN+k]*Ao[k*NSN+c]; si += Aiw[r*NSN+k]*Aiw[k*NSN+c]; }
    Ms_s[0*NSN*NSN + i] = Ao[i];
    Ms_s[1*NSN*NSN + i] = Aiw[i];
    Ms_s[2*NSN*NSN + i] = 2.f*so - (r==c ? 1.f : 0.f);
    Ms_s[3*NSN*NSN + i] = 2.f*si - (r==c ? 1.f : 0.f);
  }
  for (int i = tid; i < NPN*NPN; i += blockDim.x) {
    Ms_p[0*NPN*NPN + i] = Aop[i];
    Ms_p[1*NPN*NPN + i] = Aip[i];
  }
}

// ---------------- weight prep ----------------
__device__ __forceinline__ float wsrc(const float* W, int Kdim, int tau, int i, int jj) {
  if (tau == 0) return W[(size_t)(0*Kdim+0)*512*256 + (size_t)i*256 + jj]
                     + W[(size_t)(1*Kdim+0)*512*256 + (size_t)i*256 + jj];
  int dir = (tau - 1) & 1;
  int k = (tau + 1) >> 1;
  return W[(size_t)(dir*Kdim + k)*512*256 + (size_t)i*256 + jj];
}

__global__ void prep_w(const float* __restrict__ Wz_s, const float* __restrict__ Wr_s, const float* __restrict__ Wh_s,
                       const float* __restrict__ Wz_p, const float* __restrict__ Wr_p, const float* __restrict__ Wh_p,
                       ushort_t* __restrict__ WX_s, ushort_t* __restrict__ WH_s,
                       ushort_t* __restrict__ WX_p, ushort_t* __restrict__ WH_p) {
  const long nS = (long)768*KHS, nP = (long)768*KHP;
  const long total = 2*nS + 2*nP;
  for (long idx = (long)blockIdx.x*256 + threadIdx.x; idx < total; idx += (long)gridDim.x*256) {
    ushort_t* buf; long x; int K, Kdim; bool isH; const float *Wz, *Wr, *Wh;
    if (idx < nS)            { buf = WX_s; x = idx;          K = KHS; Kdim = 3; isH = false; Wz=Wz_s; Wr=Wr_s; Wh=Wh_s; }
    else if (idx < 2*nS)     { buf = WH_s; x = idx - nS;     K = KHS; Kdim = 3; isH = true;  Wz=Wz_s; Wr=Wr_s; Wh=Wh_s; }
    else if (idx < 2*nS+nP)  { buf = WX_p; x = idx - 2*nS;   K = KHP; Kdim = 2; isH = false; Wz=Wz_p; Wr=Wr_p; Wh=Wh_p; }
    else                     { buf = WH_p; x = idx - 2*nS-nP; K = KHP; Kdim = 2; isH = true; Wz=Wz_p; Wr=Wr_p; Wh=Wh_p; }
    int j = (int)(x / K), c = (int)(x % K);
    int tau = c >> 8, f = c & 255;
    const float* W = (j < 256) ? Wz : (j < 512) ? Wr : Wh;
    int jj = j & 255;
    int i = isH ? (256 + f) : f;
    put_hl(buf, (size_t)j*K + c, (size_t)768*K, wsrc(W, Kdim, tau, i, jj));
  }
}

__global__ void zero_f(float* p, int n) {
  int i = blockIdx.x*256 + threadIdx.x;
  if (i < n) p[i] = 0.f;
}

// ---------------- cheb core (vectorized 8-wide) ----------------
__device__ __forceinline__ void cheb_core(const float* __restrict__ Xc, const float* __restrict__ Ml,
                                          ushort_t* __restrict__ XT, size_t plane, size_t rowbase,
                                          int N, int KX, int tid) {
  int kc8 = KX >> 3;
  int nch = N * kc8;
  for (int i = tid; i < nch; i += 256) {
    int n = i / kc8, c8 = i - n*kc8;
    int tau = c8 >> 5, f0 = (c8 & 31) << 3;
    float v[8];
    if (tau == 0) {
      const float* xr0 = Xc + n*256 + f0;
#pragma unroll
      for (int j = 0; j < 8; ++j) v[j] = xr0[j];
    } else {
      const float* M = Ml + (tau-1)*N*N + n*N;
#pragma unroll
      for (int j = 0; j < 8; ++j) v[j] = 0.f;
      for (int r = 0; r < N; ++r) {
        float m = M[r];
        const float* xr = Xc + r*256 + f0;
#pragma unroll
        for (int j = 0; j < 8; ++j) v[j] += m*xr[j];
      }
    }
    union { uint4 q; ushort_t u[8]; } hi, lo;
#pragma unroll
    for (int j = 0; j < 8; ++j) {
      ushort_t h = f2bf(v[j]);
      hi.u[j] = h;
      lo.u[j] = f2bf(v[j] - bf2f(h));
    }
    size_t base = (rowbase + n)*(size_t)KX + ((size_t)c8 << 3);
    *(uint4*)(XT + base) = hi.q;
    *(uint4*)(XT + base + plane) = lo.q;
  }
}

// ---------------- cheb expansion of X for a time chunk ----------------
__global__ __launch_bounds__(256) void chebx(const float* __restrict__ xdis, const float* __restrict__ xpre,
                                             const float* __restrict__ Ms_s, const float* __restrict__ Ms_p,
                                             ushort_t* __restrict__ XTs, ushort_t* __restrict__ XTp,
                                             size_t plXs, size_t plXp, int t0) {
  __shared__ float Xc[NSN*256];
  __shared__ float Ml[4*NSN*NSN];
  int bb = blockIdx.x, tid = threadIdx.x;
  bool isP = bb >= NB*TCH;
  int q = isP ? bb - NB*TCH : bb;
  int b = q % NB, tp = q / NB;
  int N = isP ? NPN : NSN, nt = isP ? 3 : 5, KX = nt << 8;
  const float* X = isP ? (xpre + (size_t)(b*TT + t0 + tp)*NPN*256)
                       : (xdis + (size_t)(b*TT + t0 + tp)*NSN*256);
  for (int i = tid; i < N*64; i += 256) ((float4*)Xc)[i] = ((const float4*)X)[i];
  int nm = (nt-1)*N*N;
  const float* Msrc = isP ? Ms_p : Ms_s;
  for (int i = tid; i < nm; i += 256) Ml[i] = Msrc[i];
  __syncthreads();
  cheb_core(Xc, Ml, isP ? XTp : XTs, isP ? plXp : plXs,
            (size_t)(tp*NB + b)*N, N, KX, tid);
}

// ---------------- cheb expansion of H (or gH) per step ----------------
__global__ __launch_bounds__(256) void cheb_h(const float* __restrict__ Hsrc,
                                              const float* __restrict__ Ms_s, const float* __restrict__ Ms_p,
                                              ushort_t* __restrict__ XTs, ushort_t* __restrict__ XTp,
                                              size_t plXs, size_t plXp) {
  __shared__ float Xc[NSN*256];
  __shared__ float Ml[4*NSN*NSN];
  int bb = blockIdx.x, tid = threadIdx.x;
  bool isP = bb >= NB;
  int b = isP ? bb - NB : bb;
  int N = isP ? NPN : NSN, nt = isP ? 3 : 5, KX = nt << 8, hoff = isP ? NSN : 0;
  const float* hb = Hsrc + ((size_t)b*NN + hoff)*256;
  for (int i = tid; i < N*64; i += 256) ((float4*)Xc)[i] = ((const float4*)hb)[i];
  int nm = (nt-1)*N*N;
  const float* Msrc = isP ? Ms_p : Ms_s;
  for (int i = tid; i < nm; i += 256) Ml[i] = Msrc[i];
  __syncthreads();
  cheb_core(Xc, Ml, isP ? XTp : XTs, isP ? plXp : plXs, (size_t)b*N, N, KX, tid);
}

// ---------------- split-bf16 MFMA GEMM, 64x128 tile, gl_lds 3-deep ring, fused epilogues ----------------
// MODE 0: Px_out = bf16(acc + bias)          (N=768)
// MODE 1: z/r = sigmoid(acc + Px); Z or gH   (N=512)
// MODE 2: H = Z*H + (1-Z)*tanh(acc + Px_h)   (N=256)
template<int MODE>
__global__ __launch_bounds__(256) void gemm_k(
    const ushort_t* __restrict__ A0, const ushort_t* __restrict__ B0, int K0, size_t plA0, size_t plB0,
    int rbS, int cbTot,
    const ushort_t* __restrict__ A1, const ushort_t* __restrict__ B1, int K1, size_t plA1, size_t plB1,
    ushort_t* __restrict__ Px0, ushort_t* __restrict__ Px1,
    const float* __restrict__ bz0, const float* __restrict__ br0, const float* __restrict__ bh0,
    const float* __restrict__ bz1, const float* __restrict__ br1, const float* __restrict__ bh1,
    const float* __restrict__ Hin, float* __restrict__ Z, float* __restrict__ gH, float* __restrict__ Hout) {
  // ring of 3 buffers, each: A hi 8KB | A lo 8KB | B hi 16KB | B lo 16KB = 48KB
  __shared__ __align__(16) ushort_t sbuf[3][24576];

  // XCD-chunked decode: xcd = id&7 owns contiguous rb range, cb fastest
  int id = blockIdx.x;
  int xx = id & 7, kq = id >> 3;
  int rbTot8 = (gridDim.x / cbTot) >> 3;
  int rb = xx*rbTot8 + kq / cbTot;
  int cb = kq - (kq / cbTot)*cbTot;

  bool isP = rb >= rbS;
  const ushort_t* A = isP ? A1 : A0;
  const ushort_t* B = isP ? B1 : B0;
  int K = isP ? K1 : K0;
  size_t plA = isP ? plA1 : plA0, plB = isP ? plB1 : plB0;
  int row0 = (isP ? rb - rbS : rb) * 64;
  int col0 = cb * 128;
  int tid = threadIdx.x, lane = tid & 63, w = tid >> 6;
  int l15 = lane & 15, l4 = lane >> 4;
  int wr = (w >> 1) * 32, wc = (w & 1) * 64;

  // per-thread staging sources: 12 wave-level 1KB segments (seg = j*4 + w)
  const ushort_t* srcb[12];
  int ldso[12];
#pragma unroll
  for (int j = 0; j < 12; ++j) {
    int s = j*4 + w;
    int c = (s << 6) + lane;          // chunk 0..3071
    const ushort_t* base;
    if (c < 1024) {                    // A: plane = c>>9
      int pl = c >> 9, a = c & 511, r = a >> 3, kb = a & 7;
      base = A + (size_t)pl*plA + (size_t)(row0 + r)*K + ((kb ^ (r & 7)) << 3);
    } else {                           // B
      int d = c - 1024, pl = d >> 10, bi = d & 1023, r = bi >> 3, kb = bi & 7;
      base = B + (size_t)pl*plB + (size_t)(col0 + r)*K + ((kb ^ (r & 7)) << 3);
    }
    srcb[j] = base;
    ldso[j] = c << 3;                  // element offset in buffer
  }

  f32x4 acc[2][4];
#pragma unroll
  for (int i = 0; i < 2; ++i)
#pragma unroll
    for (int j = 0; j < 4; ++j) acc[i][j] = (f32x4){0.f,0.f,0.f,0.f};

  int nk = K >> 6;
#define STAGE(K0E, BUFP)  { ushort_t* _b = (BUFP); _Pragma("unroll") \
    for (int j = 0; j < 12; ++j) gl16(srcb[j] + (K0E), _b + ldso[j]); }

  STAGE(0,   &sbuf[0][0]);
  STAGE(64,  &sbuf[1][0]);
  STAGE(128, &sbuf[2][0]);

  for (int k = 0; k < nk; ++k) {
    int rem = nk - 1 - k;
    if (rem >= 2)      asm volatile("s_waitcnt vmcnt(24)" ::: "memory");
    else if (rem == 1) asm volatile("s_waitcnt vmcnt(12)" ::: "memory");
    else               asm volatile("s_waitcnt vmcnt(0)"  ::: "memory");
    __builtin_amdgcn_s_barrier();
    int kb3 = k % 3;
    const ushort_t* cur = &sbuf[kb3][0];
    const ushort_t* cA0 = cur;
    const ushort_t* cA1 = cur + 4096;
    const ushort_t* cB0 = cur + 8192;
    const ushort_t* cB1 = cur + 16384;
#pragma unroll
    for (int kk = 0; kk < 2; ++kk) {
      bf16x8 af[2][2], bq[2][4];
#pragma unroll
      for (int mi = 0; mi < 2; ++mi) {
        int r = wr + mi*16 + l15;
        int sb = (kk*4 + l4) ^ (r & 7);
        af[0][mi] = *(const bf16x8*)&cA0[r*64 + sb*8];
        af[1][mi] = *(const bf16x8*)&cA1[r*64 + sb*8];
      }
#pragma unroll
      for (int ni = 0; ni < 4; ++ni) {
        int r = wc + ni*16 + l15;
        int sb = (kk*4 + l4) ^ (r & 7);
        bq[0][ni] = *(const bf16x8*)&cB0[r*64 + sb*8];
        bq[1][ni] = *(const bf16x8*)&cB1[r*64 + sb*8];
      }
#pragma unroll
      for (int mi = 0; mi < 2; ++mi)
#pragma unroll
        for (int ni = 0; ni < 4; ++ni) {
          acc[mi][ni] = __builtin_amdgcn_mfma_f32_16x16x32_bf16(af[0][mi], bq[0][ni], acc[mi][ni], 0, 0, 0);
          acc[mi][ni] = __builtin_amdgcn_mfma_f32_16x16x32_bf16(af[0][mi], bq[1][ni], acc[mi][ni], 0, 0, 0);
          acc[mi][ni] = __builtin_amdgcn_mfma_f32_16x16x32_bf16(af[1][mi], bq[0][ni], acc[mi][ni], 0, 0, 0);
        }
    }
    __builtin_amdgcn_s_barrier();
    if (k + 3 < nk) STAGE((k + 3) << 6, &sbuf[kb3][0]);
  }
#undef STAGE

  // epilogue
  int NODE = isP ? NPN : NSN;
  int hoff = isP ? NSN : 0;
  const ushort_t* Px = isP ? Px1 : Px0;
  ushort_t* PxO = isP ? Px1 : Px0;
#pragma unroll
  for (int mi = 0; mi < 2; ++mi)
#pragma unroll
    for (int ni = 0; ni < 4; ++ni) {
      int colg = col0 + wc + ni*16 + l15;
#pragma unroll
      for (int rg = 0; rg < 4; ++rg) {
        int grow = row0 + wr + mi*16 + l4*4 + rg;
        float v = acc[mi][ni][rg];
        if constexpr (MODE == 0) {
          const float* bias = (colg < 256) ? (isP ? bz1 : bz0)
                            : (colg < 512) ? (isP ? br1 : br0)
                                           : (isP ? bh1 : bh0);
          PxO[(size_t)grow*NPRE + colg] = f2bf(v + bias[colg & 255]);
        } else {
          int hrow = (grow / NODE)*NN + grow % NODE + hoff;
          if constexpr (MODE == 1) {
            float p = bf2f(Px[(size_t)grow*NPRE + colg]);
            float s = 1.f/(1.f + expf(-(v + p)));
            int hcol = colg & 255;
            size_t hidx = (size_t)hrow*256 + hcol;
            if (colg < 256) Z[hidx] = s;
            else            gH[hidx] = s * Hin[hidx];
          } else {
            float p = bf2f(Px[(size_t)grow*NPRE + 512 + colg]);
            float ht = tanhf(v + p);
            size_t hidx = (size_t)hrow*256 + colg;
            float z = Z[hidx];
            Hout[hidx] = z*Hin[hidx] + (1.f - z)*ht;
          }
        }
      }
    }
}

// ---------------- readout ----------------
__global__ __launch_bounds__(256) void readout_k(const float* __restrict__ H, const float* __restrict__ W_ro,
                                                 const float* __restrict__ b_ro, const float* __restrict__ W_ag,
                                                 const float* __restrict__ b_ag, float* __restrict__ out) {
  __shared__ float red[256];
  __shared__ float o1[NN];
  int b = blockIdx.x, tid = threadIdx.x;
  float wro = W_ro[tid];
  for (int n = 0; n < NN; ++n) {
    red[tid] = H[((size_t)b*NN + n)*256 + tid] * wro;
    __syncthreads();
    for (int s = 128; s > 0; s >>= 1) { if (tid < s) red[tid] += red[tid+s]; __syncthreads(); }
    if (tid == 0) o1[n] = red[0] + b_ro[0];
    __syncthreads();
  }
  if (tid < 5) {
    float s = b_ag[tid];
    for (int n = 0; n < NN; ++n) s += o1[n] * W_ag[n*5 + tid];
    out[b*5 + tid] = s;
  }
}

// ---------------- host ----------------
extern "C" void kernel_launch(void* const* d_in, const int* in_sizes, int n_in,
                              void* d_out, int out_size, void* d_ws, size_t ws_size,
                              hipStream_t stream) {
  const float* xdis = (const float*)d_in[0];
  const float* xpre = (const float*)d_in[1];
  const int*   ei_s = (const int*)d_in[2];
  const int*   ei_p = (const int*)d_in[3];
  const float* ew_s = (const float*)d_in[4];
  const float* ew_p = (const float*)d_in[5];
  const float* Wz_s = (const float*)d_in[6];
  const float* bz_s = (const float*)d_in[7];
  const float* Wr_s = (const float*)d_in[8];
  const float* br_s = (const float*)d_in[9];
  const float* Wh_s = (const float*)d_in[10];
  const float* bh_s = (const float*)d_in[11];
  const float* Wz_p = (const float*)d_in[12];
  const float* bz_p = (const float*)d_in[13];
  const float* Wr_p = (const float*)d_in[14];
  const float* br_p = (const float*)d_in[15];
  const float* Wh_p = (const float*)d_in[16];
  const float* bh_p = (const float*)d_in[17];
  const float* W_ro = (const float*)d_in[18];
  const float* b_ro = (const float*)d_in[19];
  const float* W_ag = (const float*)d_in[20];
  const float* b_ag = (const float*)d_in[21];
  float* out = (float*)d_out;
  (void)in_sizes; (void)n_in; (void)out_size; (void)ws_size;

  char* w = (char*)d_ws;
  size_t off = 0;
  auto alloc = [&](size_t bytes) { void* p = w + off; off = (off + bytes + 255) & ~(size_t)255; return p; };

  const size_t plWXs = (size_t)768*KHS, plWHs = (size_t)768*KHS;
  const size_t plWXp = (size_t)768*KHP, plWHp = (size_t)768*KHP;
  const size_t rowsXs = (size_t)TCH*NB*NSN;   // 10240
  const size_t rowsXp = (size_t)TCH*NB*NPN;   // 4096
  const size_t plXs_pre = rowsXs*KHS, plXp_pre = rowsXp*KHP;
  const size_t plXs_rec = (size_t)NB*NSN*KHS, plXp_rec = (size_t)NB*NPN*KHP;

  float* Ms_s = (float*)alloc(4*NSN*NSN*sizeof(float));
  float* Ms_p = (float*)alloc(2*NPN*NPN*sizeof(float));
  ushort_t* WX_s = (ushort_t*)alloc(plWXs*2*2);
  ushort_t* WH_s = (ushort_t*)alloc(plWHs*2*2);
  ushort_t* WX_p = (ushort_t*)alloc(plWXp*2*2);
  ushort_t* WH_p = (ushort_t*)alloc(plWHp*2*2);
  ushort_t* XT_s = (ushort_t*)alloc(plXs_pre*2*2);
  ushort_t* XT_p = (ushort_t*)alloc(plXp_pre*2*2);
  ushort_t* Px_s = (ushort_t*)alloc((size_t)TT*NB*NSN*NPRE*2);
  ushort_t* Px_p = (ushort_t*)alloc((size_t)TT*NB*NPN*NPRE*2);
  float* H  = (float*)alloc((size_t)NB*NN*256*4);
  float* Z  = (float*)alloc((size_t)NB*NN*256*4);
  float* gH = (float*)alloc((size_t)NB*NN*256*4);

  graph_build<<<1, 64, 0, stream>>>(ei_s, ew_s, ei_p, ew_p, Ms_s, Ms_p);
  prep_w<<<1024, 256, 0, stream>>>(Wz_s, Wr_s, Wh_s, Wz_p, Wr_p, Wh_p, WX_s, WH_s, WX_p, WH_p);
  const int nH = NB*NN*256;
  zero_f<<<(nH + 255)/256, 256, 0, stream>>>(H, nH);

  // ---- precompute Px over all t, chunked ----
  for (int t0 = 0; t0 < TT; t0 += TCH) {
    chebx<<<2*NB*TCH, 256, 0, stream>>>(xdis, xpre, Ms_s, Ms_p, XT_s, XT_p, plXs_pre, plXp_pre, t0);
    gemm_k<0><<<224*6, 256, 0, stream>>>(
        XT_s, WX_s, KHS, plXs_pre, plWXs, 160, 6,
        XT_p, WX_p, KHP, plXp_pre, plWXp,
        Px_s + (size_t)t0*NB*NSN*NPRE, Px_p + (size_t)t0*NB*NPN*NPRE,
        bz_s, br_s, bh_s, bz_p, br_p, bh_p,
        nullptr, nullptr, nullptr, nullptr);
  }

  // ---- recurrence ----
  for (int t = 0; t < TT; ++t) {
    ushort_t* PxS = Px_s + (size_t)t*NB*NSN*NPRE;
    ushort_t* PxP = Px_p + (size_t)t*NB*NPN*NPRE;
    cheb_h<<<2*NB, 256, 0, stream>>>(H, Ms_s, Ms_p, XT_s, XT_p, plXs_rec, plXp_rec);
    gemm_k<1><<<56*4, 256, 0, stream>>>(
        XT_s, WH_s, KHS, plXs_rec, plWHs, 40, 4,
        XT_p, WH_p, KHP, plXp_rec, plWHp,
        PxS, PxP,
        nullptr, nullptr, nullptr, nullptr, nullptr, nullptr,
        H, Z, gH, nullptr);
    cheb_h<<<2*NB, 256, 0, stream>>>(gH, Ms_s, Ms_p, XT_s, XT_p, plXs_rec, plXp_rec);
    gemm_k<2><<<56*2, 256, 0, stream>>>(
        XT_s, WH_s + (size_t)512*KHS, KHS, plXs_rec, plWHs, 40, 2,
        XT_p, WH_p + (size_t)512*KHP, KHP, plXp_rec, plWHp,
        PxS, PxP,
        nullptr, nullptr, nullptr, nullptr, nullptr, nullptr,
        H, Z, nullptr, H);
  }
  readout_k<<<NB, 256, 0, stream>>>(H, W_ro, b_ro, W_ag, b_ag, out);
}

// Round 5
// 3430.843 us; speedup vs baseline: 3.2119x; 1.1008x over previous
//
#include <hip/hip_runtime.h>
#include <stdint.h>

#define NSN 20
#define NPN 8
#define NB 128
#define TT 24
#define NN 28
#define ES 100
#define EP 32
#define KHS 1280   // 5*256 (precompute K)
#define KHP 768    // 3*256
#define NPRE 768   // z|r|h output cols
#define TCH 4      // precompute time-chunk

typedef __attribute__((ext_vector_type(8))) __bf16 bf16x8;
typedef __attribute__((ext_vector_type(4))) float f32x4;
typedef unsigned short ushort_t;

__device__ __forceinline__ ushort_t f2bf(float f) {
  union { float f; unsigned int u; } x; x.f = f;
  unsigned int u = x.u + 0x7fffu + ((x.u >> 16) & 1u);
  return (ushort_t)(u >> 16);
}
__device__ __forceinline__ float bf2f(ushort_t h) {
  union { unsigned int u; float f; } x; x.u = (unsigned int)h << 16; return x.f;
}
__device__ __forceinline__ void put_hl(ushort_t* dst, size_t idx, size_t plane, float v) {
  ushort_t hi = f2bf(v);
  dst[idx] = hi;
  dst[idx + plane] = f2bf(v - bf2f(hi));
}
__device__ __forceinline__ void gl16(const ushort_t* g, ushort_t* l) {
  __builtin_amdgcn_global_load_lds((const __attribute__((address_space(1))) void*)g,
                                   (__attribute__((address_space(3))) void*)l, 16, 0, 0);
}

// ---------------- graph build: dense propagation, Chebyshev matrices, Mbig contraction mats ----------------
__global__ void graph_build(const int* __restrict__ ei_s, const float* __restrict__ ew_s,
                            const int* __restrict__ ei_p, const float* __restrict__ ew_p,
                            float* __restrict__ Ms_s, float* __restrict__ Ms_p,
                            float* __restrict__ Mbig_s, float* __restrict__ Mbig_p) {
  __shared__ float Ao[NSN*NSN], Aiw[NSN*NSN], dgo[NSN], dgi[NSN];
  __shared__ float T2o[NSN*NSN], T2i[NSN*NSN];
  __shared__ float Aop[NPN*NPN], Aip[NPN*NPN], dgop[NPN], dgip[NPN];
  int tid = threadIdx.x;
  for (int i = tid; i < NSN*NSN; i += blockDim.x) { Ao[i] = 0.f; Aiw[i] = 0.f; }
  for (int i = tid; i < NPN*NPN; i += blockDim.x) { Aop[i] = 0.f; Aip[i] = 0.f; }
  if (tid < NSN) { dgo[tid] = 0.f; dgi[tid] = 0.f; }
  if (tid < NPN) { dgop[tid] = 0.f; dgip[tid] = 0.f; }
  __syncthreads();
  if (tid == 0) {
    for (int e = 0; e < ES; ++e) { int r = ei_s[e], c = ei_s[ES+e]; float w = ew_s[e]; dgo[r] += w; dgi[c] += w; }
    for (int e = 0; e < ES; ++e) { int r = ei_s[e], c = ei_s[ES+e]; Ao[c*NSN+r] += 1.f/dgo[r]; Aiw[c*NSN+r] += 1.f/dgi[r]; }
  }
  if (tid == 1) {
    for (int e = 0; e < EP; ++e) { int r = ei_p[e], c = ei_p[EP+e]; float w = ew_p[e]; dgop[r] += w; dgip[c] += w; }
    for (int e = 0; e < EP; ++e) { int r = ei_p[e], c = ei_p[EP+e]; Aop[c*NPN+r] += 1.f/dgop[r]; Aip[c*NPN+r] += 1.f/dgip[r]; }
  }
  __syncthreads();
  for (int i = tid; i < NSN*NSN; i += blockDim.x) {
    int r = i / NSN, c = i % NSN;
    float so = 0.f, si = 0.f;
    for (int k = 0; k < NSN; ++k) { so += Ao[r*NSN+k]*Ao[k*NSN+c]; si += Aiw[r*NSN+k]*Aiw[k*NSN+c]; }
    float t2o = 2.f*so - (r==c ? 1.f : 0.f);
    float t2i = 2.f*si - (r==c ? 1.f : 0.f);
    T2o[i] = t2o; T2i[i] = t2i;
    Ms_s[0*NSN*NSN + i] = Ao[i];
    Ms_s[1*NSN*NSN + i] = Aiw[i];
    Ms_s[2*NSN*NSN + i] = t2o;
    Ms_s[3*NSN*NSN + i] = t2i;
  }
  for (int i = tid; i < NPN*NPN; i += blockDim.x) {
    Ms_p[0*NPN*NPN + i] = Aop[i];
    Ms_p[1*NPN*NPN + i] = Aip[i];
  }
  __syncthreads();
  // Mbig_s[n][r*5+tau], tau0=I, 1=Ao, 2=Aiw, 3=T2o, 4=T2i
  for (int i = tid; i < NSN*NSN*5; i += blockDim.x) {
    int n = i / 100, s = i % 100, r = s / 5, tau = s % 5;
    float v;
    if (tau == 0) v = (n == r) ? 1.f : 0.f;
    else if (tau == 1) v = Ao[n*NSN + r];
    else if (tau == 2) v = Aiw[n*NSN + r];
    else if (tau == 3) v = T2o[n*NSN + r];
    else               v = T2i[n*NSN + r];
    Mbig_s[i] = v;
  }
  for (int i = tid; i < NPN*NPN*3; i += blockDim.x) {
    int n = i / 24, s = i % 24, r = s / 3, tau = s % 3;
    float v;
    if (tau == 0) v = (n == r) ? 1.f : 0.f;
    else if (tau == 1) v = Aop[n*NPN + r];
    else               v = Aip[n*NPN + r];
    Mbig_p[i] = v;
  }
}

// ---------------- weight prep ----------------
__device__ __forceinline__ float wsrc(const float* W, int Kdim, int tau, int i, int jj) {
  if (tau == 0) return W[(size_t)(0*Kdim+0)*512*256 + (size_t)i*256 + jj]
                     + W[(size_t)(1*Kdim+0)*512*256 + (size_t)i*256 + jj];
  int dir = (tau - 1) & 1;
  int k = (tau + 1) >> 1;
  return W[(size_t)(dir*Kdim + k)*512*256 + (size_t)i*256 + jj];
}

// WX_*: precompute B, [j=0..767][K] hi/lo planes (rows i=f, X half).
// WH*_big: recurrence B, [c][512] with hi at f, lo at 256+f (rows i=256+f, H half).
__global__ void prep_w(const float* __restrict__ Wz_s, const float* __restrict__ Wr_s, const float* __restrict__ Wh_s,
                       const float* __restrict__ Wz_p, const float* __restrict__ Wr_p, const float* __restrict__ Wh_p,
                       ushort_t* __restrict__ WX_s, ushort_t* __restrict__ WX_p,
                       ushort_t* __restrict__ WHzr_s, ushort_t* __restrict__ WHh_s,
                       ushort_t* __restrict__ WHzr_p, ushort_t* __restrict__ WHh_p) {
  const long c0 = (long)768*KHS;          // WX_s
  const long c1 = c0 + (long)768*KHP;     // WX_p
  const long c2 = c1 + (long)2560*256;    // WHzr_s
  const long c3 = c2 + (long)1280*256;    // WHh_s
  const long c4 = c3 + (long)1536*256;    // WHzr_p
  const long c5 = c4 + (long)768*256;     // WHh_p
  for (long idx = (long)blockIdx.x*256 + threadIdx.x; idx < c5; idx += (long)gridDim.x*256) {
    if (idx < c0) {
      long x = idx; int j = (int)(x / KHS), c = (int)(x % KHS); int tau = c >> 8, f = c & 255;
      const float* W = (j < 256) ? Wz_s : (j < 512) ? Wr_s : Wh_s;
      put_hl(WX_s, x, c0, wsrc(W, 3, tau, f, j & 255));
    } else if (idx < c1) {
      long x = idx - c0; int j = (int)(x / KHP), c = (int)(x % KHP); int tau = c >> 8, f = c & 255;
      const float* W = (j < 256) ? Wz_p : (j < 512) ? Wr_p : Wh_p;
      put_hl(WX_p, x, (long)768*KHP, wsrc(W, 2, tau, f, j & 255));
    } else if (idx < c2) {
      long x = idx - c1; int cc = (int)(x >> 8), f = (int)(x & 255);
      int tau = cc / 512, j = cc % 512;
      const float* W = (j < 256) ? Wz_s : Wr_s;
      put_hl(WHzr_s, (size_t)cc*512 + f, 256, wsrc(W, 3, tau, 256 + f, j & 255));
    } else if (idx < c3) {
      long x = idx - c2; int cc = (int)(x >> 8), f = (int)(x & 255);
      int tau = cc >> 8, j = cc & 255;
      put_hl(WHh_s, (size_t)cc*512 + f, 256, wsrc(Wh_s, 3, tau, 256 + f, j));
    } else if (idx < c4) {
      long x = idx - c3; int cc = (int)(x >> 8), f = (int)(x & 255);
      int tau = cc / 512, j = cc % 512;
      const float* W = (j < 256) ? Wz_p : Wr_p;
      put_hl(WHzr_p, (size_t)cc*512 + f, 256, wsrc(W, 2, tau, 256 + f, j & 255));
    } else {
      long x = idx - c4; int cc = (int)(x >> 8), f = (int)(x & 255);
      int tau = cc >> 8, j = cc & 255;
      put_hl(WHh_p, (size_t)cc*512 + f, 256, wsrc(Wh_p, 2, tau, 256 + f, j));
    }
  }
}

__global__ void zero_f(float* p, long n) {
  long i = (long)blockIdx.x*256 + threadIdx.x;
  if (i < n) p[i] = 0.f;
}

// ---------------- cheb expansion of X for a time chunk (precompute A) ----------------
__global__ __launch_bounds__(256) void chebx(const float* __restrict__ xdis, const float* __restrict__ xpre,
                                             const float* __restrict__ Ms_s, const float* __restrict__ Ms_p,
                                             ushort_t* __restrict__ XTs, ushort_t* __restrict__ XTp,
                                             size_t plXs, size_t plXp, int t0) {
  __shared__ float Xc[NSN*256];
  __shared__ float Ml[4*NSN*NSN];
  int bb = blockIdx.x, tid = threadIdx.x;
  bool isP = bb >= NB*TCH;
  int q = isP ? bb - NB*TCH : bb;
  int b = q % NB, tp = q / NB;
  int N = isP ? NPN : NSN, nt = isP ? 3 : 5, KX = nt << 8;
  const float* X = isP ? (xpre + (size_t)(b*TT + t0 + tp)*NPN*256)
                       : (xdis + (size_t)(b*TT + t0 + tp)*NSN*256);
  for (int i = tid; i < N*64; i += 256) ((float4*)Xc)[i] = ((const float4*)X)[i];
  int nm = (nt-1)*N*N;
  const float* Msrc = isP ? Ms_p : Ms_s;
  for (int i = tid; i < nm; i += 256) Ml[i] = Msrc[i];
  __syncthreads();
  ushort_t* XT = isP ? XTp : XTs;
  size_t plane = isP ? plXp : plXs;
  size_t rowbase = (size_t)(tp*NB + b)*N;
  int kc8 = KX >> 3, nch = N * kc8;
  for (int i = tid; i < nch; i += 256) {
    int n = i / kc8, c8 = i - n*kc8;
    int tau = c8 >> 5, f0 = (c8 & 31) << 3;
    float v[8];
    if (tau == 0) {
      const float* xr0 = Xc + n*256 + f0;
#pragma unroll
      for (int j = 0; j < 8; ++j) v[j] = xr0[j];
    } else {
      const float* M = Ml + (tau-1)*N*N + n*N;
#pragma unroll
      for (int j = 0; j < 8; ++j) v[j] = 0.f;
      for (int r = 0; r < N; ++r) {
        float m = M[r];
        const float* xr = Xc + r*256 + f0;
#pragma unroll
        for (int j = 0; j < 8; ++j) v[j] += m*xr[j];
      }
    }
    union { uint4 q; ushort_t u[8]; } hi, lo;
#pragma unroll
    for (int j = 0; j < 8; ++j) {
      ushort_t h = f2bf(v[j]);
      hi.u[j] = h;
      lo.u[j] = f2bf(v[j] - bf2f(h));
    }
    size_t base = (rowbase + n)*(size_t)KX + ((size_t)c8 << 3);
    *(uint4*)(XT + base) = hi.q;
    *(uint4*)(XT + base + plane) = lo.q;
  }
}

// ---------------- precompute GEMM (64x128, gl_lds ring-3, XCD swizzle): Px = bf16(XT@WX + bias) ----------------
__global__ __launch_bounds__(256) void gemm_pre(
    const ushort_t* __restrict__ A0, const ushort_t* __restrict__ B0, int K0, size_t plA0, size_t plB0,
    int rbS, int cbTot,
    const ushort_t* __restrict__ A1, const ushort_t* __restrict__ B1, int K1, size_t plA1, size_t plB1,
    ushort_t* __restrict__ Px0, ushort_t* __restrict__ Px1,
    const float* __restrict__ bz0, const float* __restrict__ br0, const float* __restrict__ bh0,
    const float* __restrict__ bz1, const float* __restrict__ br1, const float* __restrict__ bh1) {
  __shared__ __align__(16) ushort_t sbuf[3][24576];
  int id = blockIdx.x;
  int xx = id & 7, kq = id >> 3;
  int rbTot8 = (gridDim.x / cbTot) >> 3;
  int rb = xx*rbTot8 + kq / cbTot;
  int cb = kq - (kq / cbTot)*cbTot;

  bool isP = rb >= rbS;
  const ushort_t* A = isP ? A1 : A0;
  const ushort_t* B = isP ? B1 : B0;
  int K = isP ? K1 : K0;
  size_t plA = isP ? plA1 : plA0, plB = isP ? plB1 : plB0;
  int row0 = (isP ? rb - rbS : rb) * 64;
  int col0 = cb * 128;
  int tid = threadIdx.x, lane = tid & 63, w = tid >> 6;
  int l15 = lane & 15, l4 = lane >> 4;
  int wr = (w >> 1) * 32, wc = (w & 1) * 64;

  const ushort_t* srcb[12];
  int ldso[12];
#pragma unroll
  for (int j = 0; j < 12; ++j) {
    int s = j*4 + w;
    int c = (s << 6) + lane;
    const ushort_t* base;
    if (c < 1024) {
      int pl = c >> 9, a = c & 511, r = a >> 3, kb = a & 7;
      base = A + (size_t)pl*plA + (size_t)(row0 + r)*K + ((kb ^ (r & 7)) << 3);
    } else {
      int d = c - 1024, pl = d >> 10, bi = d & 1023, r = bi >> 3, kb = bi & 7;
      base = B + (size_t)pl*plB + (size_t)(col0 + r)*K + ((kb ^ (r & 7)) << 3);
    }
    srcb[j] = base;
    ldso[j] = c << 3;
  }

  f32x4 acc[2][4];
#pragma unroll
  for (int i = 0; i < 2; ++i)
#pragma unroll
    for (int j = 0; j < 4; ++j) acc[i][j] = (f32x4){0.f,0.f,0.f,0.f};

  int nk = K >> 6;
#define STAGE(K0E, BUFP)  { ushort_t* _b = (BUFP); _Pragma("unroll") \
    for (int j = 0; j < 12; ++j) gl16(srcb[j] + (K0E), _b + ldso[j]); }

  STAGE(0,   &sbuf[0][0]);
  STAGE(64,  &sbuf[1][0]);
  STAGE(128, &sbuf[2][0]);

  for (int k = 0; k < nk; ++k) {
    int rem = nk - 1 - k;
    if (rem >= 2)      asm volatile("s_waitcnt vmcnt(24)" ::: "memory");
    else if (rem == 1) asm volatile("s_waitcnt vmcnt(12)" ::: "memory");
    else               asm volatile("s_waitcnt vmcnt(0)"  ::: "memory");
    __builtin_amdgcn_s_barrier();
    int kb3 = k % 3;
    const ushort_t* cur = &sbuf[kb3][0];
    const ushort_t* cA0 = cur;
    const ushort_t* cA1 = cur + 4096;
    const ushort_t* cB0 = cur + 8192;
    const ushort_t* cB1 = cur + 16384;
#pragma unroll
    for (int kk = 0; kk < 2; ++kk) {
      bf16x8 af[2][2], bq[2][4];
#pragma unroll
      for (int mi = 0; mi < 2; ++mi) {
        int r = wr + mi*16 + l15;
        int sb = (kk*4 + l4) ^ (r & 7);
        af[0][mi] = *(const bf16x8*)&cA0[r*64 + sb*8];
        af[1][mi] = *(const bf16x8*)&cA1[r*64 + sb*8];
      }
#pragma unroll
      for (int ni = 0; ni < 4; ++ni) {
        int r = wc + ni*16 + l15;
        int sb = (kk*4 + l4) ^ (r & 7);
        bq[0][ni] = *(const bf16x8*)&cB0[r*64 + sb*8];
        bq[1][ni] = *(const bf16x8*)&cB1[r*64 + sb*8];
      }
#pragma unroll
      for (int mi = 0; mi < 2; ++mi)
#pragma unroll
        for (int ni = 0; ni < 4; ++ni) {
          acc[mi][ni] = __builtin_amdgcn_mfma_f32_16x16x32_bf16(af[0][mi], bq[0][ni], acc[mi][ni], 0, 0, 0);
          acc[mi][ni] = __builtin_amdgcn_mfma_f32_16x16x32_bf16(af[0][mi], bq[1][ni], acc[mi][ni], 0, 0, 0);
          acc[mi][ni] = __builtin_amdgcn_mfma_f32_16x16x32_bf16(af[1][mi], bq[0][ni], acc[mi][ni], 0, 0, 0);
        }
    }
    __builtin_amdgcn_s_barrier();
    if (k + 3 < nk) STAGE((k + 3) << 6, &sbuf[kb3][0]);
  }

  ushort_t* PxO = isP ? Px1 : Px0;
#pragma unroll
  for (int mi = 0; mi < 2; ++mi)
#pragma unroll
    for (int ni = 0; ni < 4; ++ni) {
      int colg = col0 + wc + ni*16 + l15;
      const float* bias = (colg < 256) ? (isP ? bz1 : bz0)
                        : (colg < 512) ? (isP ? br1 : br0)
                                       : (isP ? bh1 : bh0);
#pragma unroll
      for (int rg = 0; rg < 4; ++rg) {
        int grow = row0 + wr + mi*16 + l4*4 + rg;
        PxO[(size_t)grow*NPRE + colg] = f2bf(acc[mi][ni][rg] + bias[colg & 255]);
      }
    }
}

// ---------------- recurrence GEMM: Y = Ahl @ Bhl^T, K=256 (rows [512] hi|lo), fp32 out ----------------
__global__ __launch_bounds__(256) void gemm_y(
    const ushort_t* __restrict__ A0, const ushort_t* __restrict__ B0, float* __restrict__ C0, int NC0, int cb0, int nb0,
    const ushort_t* __restrict__ A1, const ushort_t* __restrict__ B1, float* __restrict__ C1, int NC1, int cb1) {
  __shared__ __align__(16) ushort_t sbuf[3][24576];
  int id = blockIdx.x;
  int rb, cb; const ushort_t *A, *B; float* C; int NC;
  if (id < nb0) { rb = id / cb0; cb = id % cb0; A = A0; B = B0; C = C0; NC = NC0; }
  else { int q = id - nb0; rb = q / cb1; cb = q % cb1; A = A1; B = B1; C = C1; NC = NC1; }
  int row0 = rb*64, col0 = cb*128;
  int tid = threadIdx.x, lane = tid & 63, w = tid >> 6;
  int l15 = lane & 15, l4 = lane >> 4;
  int wr = (w >> 1) * 32, wc = (w & 1) * 64;

  const ushort_t* srcb[12];
  int ldso[12];
#pragma unroll
  for (int j = 0; j < 12; ++j) {
    int s = j*4 + w;
    int c = (s << 6) + lane;
    const ushort_t* base;
    if (c < 1024) {
      int pl = c >> 9, a = c & 511, r = a >> 3, kb = a & 7;
      base = A + (size_t)(row0 + r)*512 + pl*256 + ((kb ^ (r & 7)) << 3);
    } else {
      int d = c - 1024, pl = d >> 10, bi = d & 1023, r = bi >> 3, kb = bi & 7;
      base = B + (size_t)(col0 + r)*512 + pl*256 + ((kb ^ (r & 7)) << 3);
    }
    srcb[j] = base;
    ldso[j] = c << 3;
  }

  f32x4 acc[2][4];
#pragma unroll
  for (int i = 0; i < 2; ++i)
#pragma unroll
    for (int j = 0; j < 4; ++j) acc[i][j] = (f32x4){0.f,0.f,0.f,0.f};

  STAGE(0,   &sbuf[0][0]);
  STAGE(64,  &sbuf[1][0]);
  STAGE(128, &sbuf[2][0]);

  for (int k = 0; k < 4; ++k) {
    int rem = 3 - k;
    if (rem >= 2)      asm volatile("s_waitcnt vmcnt(24)" ::: "memory");
    else if (rem == 1) asm volatile("s_waitcnt vmcnt(12)" ::: "memory");
    else               asm volatile("s_waitcnt vmcnt(0)"  ::: "memory");
    __builtin_amdgcn_s_barrier();
    int kb3 = k % 3;
    const ushort_t* cur = &sbuf[kb3][0];
    const ushort_t* cA0 = cur;
    const ushort_t* cA1 = cur + 4096;
    const ushort_t* cB0 = cur + 8192;
    const ushort_t* cB1 = cur + 16384;
#pragma unroll
    for (int kk = 0; kk < 2; ++kk) {
      bf16x8 af[2][2], bq[2][4];
#pragma unroll
      for (int mi = 0; mi < 2; ++mi) {
        int r = wr + mi*16 + l15;
        int sb = (kk*4 + l4) ^ (r & 7);
        af[0][mi] = *(const bf16x8*)&cA0[r*64 + sb*8];
        af[1][mi] = *(const bf16x8*)&cA1[r*64 + sb*8];
      }
#pragma unroll
      for (int ni = 0; ni < 4; ++ni) {
        int r = wc + ni*16 + l15;
        int sb = (kk*4 + l4) ^ (r & 7);
        bq[0][ni] = *(const bf16x8*)&cB0[r*64 + sb*8];
        bq[1][ni] = *(const bf16x8*)&cB1[r*64 + sb*8];
      }
#pragma unroll
      for (int mi = 0; mi < 2; ++mi)
#pragma unroll
        for (int ni = 0; ni < 4; ++ni) {
          acc[mi][ni] = __builtin_amdgcn_mfma_f32_16x16x32_bf16(af[0][mi], bq[0][ni], acc[mi][ni], 0, 0, 0);
          acc[mi][ni] = __builtin_amdgcn_mfma_f32_16x16x32_bf16(af[0][mi], bq[1][ni], acc[mi][ni], 0, 0, 0);
          acc[mi][ni] = __builtin_amdgcn_mfma_f32_16x16x32_bf16(af[1][mi], bq[0][ni], acc[mi][ni], 0, 0, 0);
        }
    }
    __builtin_amdgcn_s_barrier();
    if (k + 3 < 4) STAGE((k + 3) << 6, &sbuf[kb3][0]);
  }
#undef STAGE

#pragma unroll
  for (int mi = 0; mi < 2; ++mi)
#pragma unroll
    for (int ni = 0; ni < 4; ++ni) {
      int colg = col0 + wc + ni*16 + l15;
#pragma unroll
      for (int rg = 0; rg < 4; ++rg) {
        int grow = row0 + wr + mi*16 + l4*4 + rg;
        C[(size_t)grow*NC + colg] = acc[mi][ni][rg];
      }
    }
}

// ---------------- node contraction + GRU epilogues ----------------
// GATE 0: P = Mbig@Y + Px(z|r); j<256: Z=sig(P); else gHhl=bf16hl(sig(P)*H)
// GATE 1: P = Mbig@Y + Px(h); H = Z*H + (1-Z)*tanh(P); write H fp32 + Hhl
template<int GATE>
__global__ __launch_bounds__(256) void contract_k(
    const float* __restrict__ Ys, const float* __restrict__ Yp,
    const ushort_t* __restrict__ Px_s, const ushort_t* __restrict__ Px_p,
    const float* __restrict__ Mb_s, const float* __restrict__ Mb_p,
    const float* __restrict__ Hin, float* __restrict__ Z,
    ushort_t* __restrict__ Out_s, ushort_t* __restrict__ Out_p,
    float* __restrict__ Hout) {
  constexpr int JB = GATE ? 2 : 4;          // j-blocks of 128
  constexpr int JW = GATE ? 256 : 512;      // per-tau col width in Y
  __shared__ float Yl[100*128];
  __shared__ float Mb[NSN*100];
  int id = blockIdx.x, tid = threadIdx.x;
  bool isP = id >= NB*JB;
  int q = isP ? id - NB*JB : id;
  int b = q / JB, jb = q % JB;
  int N = isP ? NPN : NSN, ntau = isP ? 3 : 5;
  int nseg = N * ntau;
  int NC = ntau * JW;
  const float* Y = isP ? Yp : Ys;
  const float* Mbg = isP ? Mb_p : Mb_s;
  int tot = nseg << 7;
  for (int i = tid; i < tot; i += 256) {
    int seg = i >> 7, jc = i & 127;
    int r = seg / ntau, tau = seg - r*ntau;
    Yl[i] = Y[(size_t)(b*N + r)*NC + tau*JW + jb*128 + jc];
  }
  for (int i = tid; i < N*nseg; i += 256) Mb[i] = Mbg[i];
  __syncthreads();
  const ushort_t* Px = isP ? Px_p : Px_s;
  ushort_t* Out = isP ? Out_p : Out_s;
  int hoff = isP ? NSN : 0;
  int nout = N << 7;
  for (int o = tid; o < nout; o += 256) {
    int n = o >> 7, jc = o & 127;
    int j = jb*128 + jc;
    float p = 0.f;
    const float* mrow = Mb + n*nseg;
    for (int s = 0; s < nseg; ++s) p += mrow[s] * Yl[(s << 7) + jc];
    p += bf2f(Px[(size_t)(b*N + n)*NPRE + (GATE ? 512 : 0) + j]);
    if constexpr (GATE == 0) {
      float sg = 1.f/(1.f + expf(-p));
      if (j < 256) {
        Z[((size_t)b*NN + hoff + n)*256 + j] = sg;
      } else {
        int f = j - 256;
        float gh = sg * Hin[((size_t)b*NN + hoff + n)*256 + f];
        ushort_t hi = f2bf(gh);
        ushort_t* op = Out + (size_t)(b*N + n)*512 + f;
        op[0] = hi; op[256] = f2bf(gh - bf2f(hi));
      }
    } else {
      float ht = tanhf(p);
      size_t hidx = ((size_t)b*NN + hoff + n)*256 + j;
      float z = Z[hidx];
      float hn = z*Hin[hidx] + (1.f - z)*ht;
      Hout[hidx] = hn;
      ushort_t hi = f2bf(hn);
      ushort_t* op = Out + (size_t)(b*N + n)*512 + j;
      op[0] = hi; op[256] = f2bf(hn - bf2f(hi));
    }
  }
}

// ---------------- readout ----------------
__global__ __launch_bounds__(256) void readout_k(const float* __restrict__ H, const float* __restrict__ W_ro,
                                                 const float* __restrict__ b_ro, const float* __restrict__ W_ag,
                                                 const float* __restrict__ b_ag, float* __restrict__ out) {
  __shared__ float red[256];
  __shared__ float o1[NN];
  int b = blockIdx.x, tid = threadIdx.x;
  float wro = W_ro[tid];
  for (int n = 0; n < NN; ++n) {
    red[tid] = H[((size_t)b*NN + n)*256 + tid] * wro;
    __syncthreads();
    for (int s = 128; s > 0; s >>= 1) { if (tid < s) red[tid] += red[tid+s]; __syncthreads(); }
    if (tid == 0) o1[n] = red[0] + b_ro[0];
    __syncthreads();
  }
  if (tid < 5) {
    float s = b_ag[tid];
    for (int n = 0; n < NN; ++n) s += o1[n] * W_ag[n*5 + tid];
    out[b*5 + tid] = s;
  }
}

// ---------------- host ----------------
extern "C" void kernel_launch(void* const* d_in, const int* in_sizes, int n_in,
                              void* d_out, int out_size, void* d_ws, size_t ws_size,
                              hipStream_t stream) {
  const float* xdis = (const float*)d_in[0];
  const float* xpre = (const float*)d_in[1];
  const int*   ei_s = (const int*)d_in[2];
  const int*   ei_p = (const int*)d_in[3];
  const float* ew_s = (const float*)d_in[4];
  const float* ew_p = (const float*)d_in[5];
  const float* Wz_s = (const float*)d_in[6];
  const float* bz_s = (const float*)d_in[7];
  const float* Wr_s = (const float*)d_in[8];
  const float* br_s = (const float*)d_in[9];
  const float* Wh_s = (const float*)d_in[10];
  const float* bh_s = (const float*)d_in[11];
  const float* Wz_p = (const float*)d_in[12];
  const float* bz_p = (const float*)d_in[13];
  const float* Wr_p = (const float*)d_in[14];
  const float* br_p = (const float*)d_in[15];
  const float* Wh_p = (const float*)d_in[16];
  const float* bh_p = (const float*)d_in[17];
  const float* W_ro = (const float*)d_in[18];
  const float* b_ro = (const float*)d_in[19];
  const float* W_ag = (const float*)d_in[20];
  const float* b_ag = (const float*)d_in[21];
  float* out = (float*)d_out;
  (void)in_sizes; (void)n_in; (void)out_size; (void)ws_size;

  char* w = (char*)d_ws;
  size_t off = 0;
  auto alloc = [&](size_t bytes) { void* p = w + off; off = (off + bytes + 255) & ~(size_t)255; return p; };

  const size_t plWXs = (size_t)768*KHS, plWXp = (size_t)768*KHP;
  const size_t rowsXs = (size_t)TCH*NB*NSN, rowsXp = (size_t)TCH*NB*NPN;
  const size_t plXs_pre = rowsXs*KHS, plXp_pre = rowsXp*KHP;

  float* Ms_s = (float*)alloc(4*NSN*NSN*sizeof(float));
  float* Ms_p = (float*)alloc(2*NPN*NPN*sizeof(float));
  float* Mbig_s = (float*)alloc(NSN*100*sizeof(float));
  float* Mbig_p = (float*)alloc(NPN*24*sizeof(float));
  ushort_t* WX_s = (ushort_t*)alloc(plWXs*2*2);
  ushort_t* WX_p = (ushort_t*)alloc(plWXp*2*2);
  ushort_t* WHzr_s = (ushort_t*)alloc((size_t)2560*512*2);
  ushort_t* WHh_s  = (ushort_t*)alloc((size_t)1280*512*2);
  ushort_t* WHzr_p = (ushort_t*)alloc((size_t)1536*512*2);
  ushort_t* WHh_p  = (ushort_t*)alloc((size_t)768*512*2);
  ushort_t* XT_s = (ushort_t*)alloc(plXs_pre*2*2);
  ushort_t* XT_p = (ushort_t*)alloc(plXp_pre*2*2);
  ushort_t* Px_s = (ushort_t*)alloc((size_t)TT*NB*NSN*NPRE*2);
  ushort_t* Px_p = (ushort_t*)alloc((size_t)TT*NB*NPN*NPRE*2);
  float* Yzr_s = (float*)alloc((size_t)NB*NSN*2560*4);   // aliased for Yh_s (1280 cols)
  float* Yzr_p = (float*)alloc((size_t)NB*NPN*1536*4);   // aliased for Yh_p (768 cols)
  float* H  = (float*)alloc((size_t)NB*NN*256*4);
  float* Z  = (float*)alloc((size_t)NB*NN*256*4);
  ushort_t* Hhl_s  = (ushort_t*)alloc((size_t)NB*NSN*512*2);
  ushort_t* Hhl_p  = (ushort_t*)alloc((size_t)NB*NPN*512*2);
  ushort_t* gHhl_s = (ushort_t*)alloc((size_t)NB*NSN*512*2);
  ushort_t* gHhl_p = (ushort_t*)alloc((size_t)NB*NPN*512*2);

  graph_build<<<1, 64, 0, stream>>>(ei_s, ew_s, ei_p, ew_p, Ms_s, Ms_p, Mbig_s, Mbig_p);
  prep_w<<<1024, 256, 0, stream>>>(Wz_s, Wr_s, Wh_s, Wz_p, Wr_p, Wh_p,
                                   WX_s, WX_p, WHzr_s, WHh_s, WHzr_p, WHh_p);
  const long nH = (long)NB*NN*256;
  zero_f<<<(nH + 255)/256, 256, 0, stream>>>(H, nH);
  const long nHhl = ((long)NB*NSN*512 + (long)NB*NPN*512) / 2;  // Hhl_s+Hhl_p as floats (contiguous)
  zero_f<<<(nHhl + 255)/256, 256, 0, stream>>>((float*)Hhl_s, nHhl);

  // ---- precompute Px ----
  for (int t0 = 0; t0 < TT; t0 += TCH) {
    chebx<<<2*NB*TCH, 256, 0, stream>>>(xdis, xpre, Ms_s, Ms_p, XT_s, XT_p, plXs_pre, plXp_pre, t0);
    gemm_pre<<<224*6, 256, 0, stream>>>(
        XT_s, WX_s, KHS, plXs_pre, plWXs, 160, 6,
        XT_p, WX_p, KHP, plXp_pre, plWXp,
        Px_s + (size_t)t0*NB*NSN*NPRE, Px_p + (size_t)t0*NB*NPN*NPRE,
        bz_s, br_s, bh_s, bz_p, br_p, bh_p);
  }

  // ---- recurrence ----
  for (int t = 0; t < TT; ++t) {
    const ushort_t* PxS = Px_s + (size_t)t*NB*NSN*NPRE;
    const ushort_t* PxP = Px_p + (size_t)t*NB*NPN*NPRE;
    gemm_y<<<800 + 192, 256, 0, stream>>>(Hhl_s, WHzr_s, Yzr_s, 2560, 20, 800,
                                          Hhl_p, WHzr_p, Yzr_p, 1536, 12);
    contract_k<0><<<NB*4*2, 256, 0, stream>>>(Yzr_s, Yzr_p, PxS, PxP, Mbig_s, Mbig_p,
                                              H, Z, gHhl_s, gHhl_p, nullptr);
    gemm_y<<<400 + 96, 256, 0, stream>>>(gHhl_s, WHh_s, Yzr_s, 1280, 10, 400,
                                         gHhl_p, WHh_p, Yzr_p, 768, 6);
    contract_k<1><<<NB*2*2, 256, 0, stream>>>(Yzr_s, Yzr_p, PxS, PxP, Mbig_s, Mbig_p,
                                              H, Z, Hhl_s, Hhl_p, H);
  }
  readout_k<<<NB, 256, 0, stream>>>(H, W_ro, b_ro, W_ag, b_ag, out);
}

// Round 6
// 2601.021 us; speedup vs baseline: 4.2366x; 1.3190x over previous
//
#include <hip/hip_runtime.h>
#include <stdint.h>

#define NSN 20
#define NPN 8
#define NB 128
#define TT 24
#define NN 28
#define ES 100
#define EP 32
#define KHS 1280   // 5*256 (precompute K)
#define KHP 768    // 3*256
#define NPRE 768   // z|r|h output cols
#define TCH 4      // precompute time-chunk

typedef __attribute__((ext_vector_type(8))) __bf16 bf16x8;
typedef __attribute__((ext_vector_type(4))) float f32x4;
typedef unsigned short ushort_t;

__device__ __forceinline__ ushort_t f2bf(float f) {
  union { float f; unsigned int u; } x; x.f = f;
  unsigned int u = x.u + 0x7fffu + ((x.u >> 16) & 1u);
  return (ushort_t)(u >> 16);
}
__device__ __forceinline__ float bf2f(ushort_t h) {
  union { unsigned int u; float f; } x; x.u = (unsigned int)h << 16; return x.f;
}
__device__ __forceinline__ void put_hl(ushort_t* dst, size_t idx, size_t plane, float v) {
  ushort_t hi = f2bf(v);
  dst[idx] = hi;
  dst[idx + plane] = f2bf(v - bf2f(hi));
}
__device__ __forceinline__ void gl16(const ushort_t* g, ushort_t* l) {
  __builtin_amdgcn_global_load_lds((const __attribute__((address_space(1))) void*)g,
                                   (__attribute__((address_space(3))) void*)l, 16, 0, 0);
}

// ---------------- graph build ----------------
__global__ void graph_build(const int* __restrict__ ei_s, const float* __restrict__ ew_s,
                            const int* __restrict__ ei_p, const float* __restrict__ ew_p,
                            float* __restrict__ Ms_s, float* __restrict__ Ms_p,
                            float* __restrict__ Mbig_s, float* __restrict__ Mbig_p) {
  __shared__ float Ao[NSN*NSN], Aiw[NSN*NSN], dgo[NSN], dgi[NSN];
  __shared__ float T2o[NSN*NSN], T2i[NSN*NSN];
  __shared__ float Aop[NPN*NPN], Aip[NPN*NPN], dgop[NPN], dgip[NPN];
  int tid = threadIdx.x;
  for (int i = tid; i < NSN*NSN; i += blockDim.x) { Ao[i] = 0.f; Aiw[i] = 0.f; }
  for (int i = tid; i < NPN*NPN; i += blockDim.x) { Aop[i] = 0.f; Aip[i] = 0.f; }
  if (tid < NSN) { dgo[tid] = 0.f; dgi[tid] = 0.f; }
  if (tid < NPN) { dgop[tid] = 0.f; dgip[tid] = 0.f; }
  __syncthreads();
  if (tid == 0) {
    for (int e = 0; e < ES; ++e) { int r = ei_s[e], c = ei_s[ES+e]; float w = ew_s[e]; dgo[r] += w; dgi[c] += w; }
    for (int e = 0; e < ES; ++e) { int r = ei_s[e], c = ei_s[ES+e]; Ao[c*NSN+r] += 1.f/dgo[r]; Aiw[c*NSN+r] += 1.f/dgi[r]; }
  }
  if (tid == 1) {
    for (int e = 0; e < EP; ++e) { int r = ei_p[e], c = ei_p[EP+e]; float w = ew_p[e]; dgop[r] += w; dgip[c] += w; }
    for (int e = 0; e < EP; ++e) { int r = ei_p[e], c = ei_p[EP+e]; Aop[c*NPN+r] += 1.f/dgop[r]; Aip[c*NPN+r] += 1.f/dgip[r]; }
  }
  __syncthreads();
  for (int i = tid; i < NSN*NSN; i += blockDim.x) {
    int r = i / NSN, c = i % NSN;
    float so = 0.f, si = 0.f;
    for (int k = 0; k < NSN; ++k) { so += Ao[r*NSN+k]*Ao[k*NSN+c]; si += Aiw[r*NSN+k]*Aiw[k*NSN+c]; }
    float t2o = 2.f*so - (r==c ? 1.f : 0.f);
    float t2i = 2.f*si - (r==c ? 1.f : 0.f);
    T2o[i] = t2o; T2i[i] = t2i;
    Ms_s[0*NSN*NSN + i] = Ao[i];
    Ms_s[1*NSN*NSN + i] = Aiw[i];
    Ms_s[2*NSN*NSN + i] = t2o;
    Ms_s[3*NSN*NSN + i] = t2i;
  }
  for (int i = tid; i < NPN*NPN; i += blockDim.x) {
    Ms_p[0*NPN*NPN + i] = Aop[i];
    Ms_p[1*NPN*NPN + i] = Aip[i];
  }
  __syncthreads();
  for (int i = tid; i < NSN*NSN*5; i += blockDim.x) {
    int n = i / 100, s = i % 100, r = s / 5, tau = s % 5;
    float v;
    if (tau == 0) v = (n == r) ? 1.f : 0.f;
    else if (tau == 1) v = Ao[n*NSN + r];
    else if (tau == 2) v = Aiw[n*NSN + r];
    else if (tau == 3) v = T2o[n*NSN + r];
    else               v = T2i[n*NSN + r];
    Mbig_s[i] = v;
  }
  for (int i = tid; i < NPN*NPN*3; i += blockDim.x) {
    int n = i / 24, s = i % 24, r = s / 3, tau = s % 3;
    float v;
    if (tau == 0) v = (n == r) ? 1.f : 0.f;
    else if (tau == 1) v = Aop[n*NPN + r];
    else               v = Aip[n*NPN + r];
    Mbig_p[i] = v;
  }
}

// ---------------- weight prep ----------------
__device__ __forceinline__ float wsrc(const float* W, int Kdim, int tau, int i, int jj) {
  if (tau == 0) return W[(size_t)(0*Kdim+0)*512*256 + (size_t)i*256 + jj]
                     + W[(size_t)(1*Kdim+0)*512*256 + (size_t)i*256 + jj];
  int dir = (tau - 1) & 1;
  int k = (tau + 1) >> 1;
  return W[(size_t)(dir*Kdim + k)*512*256 + (size_t)i*256 + jj];
}

__global__ void prep_w(const float* __restrict__ Wz_s, const float* __restrict__ Wr_s, const float* __restrict__ Wh_s,
                       const float* __restrict__ Wz_p, const float* __restrict__ Wr_p, const float* __restrict__ Wh_p,
                       ushort_t* __restrict__ WX_s, ushort_t* __restrict__ WX_p,
                       ushort_t* __restrict__ WHzr_s, ushort_t* __restrict__ WHh_s,
                       ushort_t* __restrict__ WHzr_p, ushort_t* __restrict__ WHh_p) {
  const long c0 = (long)768*KHS;
  const long c1 = c0 + (long)768*KHP;
  const long c2 = c1 + (long)2560*256;
  const long c3 = c2 + (long)1280*256;
  const long c4 = c3 + (long)1536*256;
  const long c5 = c4 + (long)768*256;
  for (long idx = (long)blockIdx.x*256 + threadIdx.x; idx < c5; idx += (long)gridDim.x*256) {
    if (idx < c0) {
      long x = idx; int j = (int)(x / KHS), c = (int)(x % KHS); int tau = c >> 8;
      const float* W = (j < 256) ? Wz_s : (j < 512) ? Wr_s : Wh_s;
      put_hl(WX_s, x, c0, wsrc(W, 3, tau, c & 255, j & 255));
    } else if (idx < c1) {
      long x = idx - c0; int j = (int)(x / KHP), c = (int)(x % KHP); int tau = c >> 8;
      const float* W = (j < 256) ? Wz_p : (j < 512) ? Wr_p : Wh_p;
      put_hl(WX_p, x, (long)768*KHP, wsrc(W, 2, tau, c & 255, j & 255));
    } else if (idx < c2) {
      long x = idx - c1; int cc = (int)(x >> 8), f = (int)(x & 255);
      int tau = cc / 512, j = cc % 512;
      const float* W = (j < 256) ? Wz_s : Wr_s;
      put_hl(WHzr_s, (size_t)cc*512 + f, 256, wsrc(W, 3, tau, 256 + f, j & 255));
    } else if (idx < c3) {
      long x = idx - c2; int cc = (int)(x >> 8), f = (int)(x & 255);
      int tau = cc >> 8, j = cc & 255;
      put_hl(WHh_s, (size_t)cc*512 + f, 256, wsrc(Wh_s, 3, tau, 256 + f, j));
    } else if (idx < c4) {
      long x = idx - c3; int cc = (int)(x >> 8), f = (int)(x & 255);
      int tau = cc / 512, j = cc % 512;
      const float* W = (j < 256) ? Wz_p : Wr_p;
      put_hl(WHzr_p, (size_t)cc*512 + f, 256, wsrc(W, 2, tau, 256 + f, j & 255));
    } else {
      long x = idx - c4; int cc = (int)(x >> 8), f = (int)(x & 255);
      int tau = cc >> 8, j = cc & 255;
      put_hl(WHh_p, (size_t)cc*512 + f, 256, wsrc(Wh_p, 2, tau, 256 + f, j));
    }
  }
}

__global__ void zero_f(float* p, long n) {
  long i = (long)blockIdx.x*256 + threadIdx.x;
  if (i < n) p[i] = 0.f;
}

// ---------------- cheb expansion of X (precompute A) ----------------
__global__ __launch_bounds__(256) void chebx(const float* __restrict__ xdis, const float* __restrict__ xpre,
                                             const float* __restrict__ Ms_s, const float* __restrict__ Ms_p,
                                             ushort_t* __restrict__ XTs, ushort_t* __restrict__ XTp,
                                             size_t plXs, size_t plXp, int t0) {
  __shared__ float Xc[NSN*256];
  __shared__ float Ml[4*NSN*NSN];
  int bb = blockIdx.x, tid = threadIdx.x;
  bool isP = bb >= NB*TCH;
  int q = isP ? bb - NB*TCH : bb;
  int b = q % NB, tp = q / NB;
  int N = isP ? NPN : NSN, nt = isP ? 3 : 5, KX = nt << 8;
  const float* X = isP ? (xpre + (size_t)(b*TT + t0 + tp)*NPN*256)
                       : (xdis + (size_t)(b*TT + t0 + tp)*NSN*256);
  for (int i = tid; i < N*64; i += 256) ((float4*)Xc)[i] = ((const float4*)X)[i];
  int nm = (nt-1)*N*N;
  const float* Msrc = isP ? Ms_p : Ms_s;
  for (int i = tid; i < nm; i += 256) Ml[i] = Msrc[i];
  __syncthreads();
  ushort_t* XT = isP ? XTp : XTs;
  size_t plane = isP ? plXp : plXs;
  size_t rowbase = (size_t)(tp*NB + b)*N;
  int kc8 = KX >> 3, nch = N * kc8;
  for (int i = tid; i < nch; i += 256) {
    int n = i / kc8, c8 = i - n*kc8;
    int tau = c8 >> 5, f0 = (c8 & 31) << 3;
    float v[8];
    if (tau == 0) {
      const float* xr0 = Xc + n*256 + f0;
#pragma unroll
      for (int j = 0; j < 8; ++j) v[j] = xr0[j];
    } else {
      const float* M = Ml + (tau-1)*N*N + n*N;
#pragma unroll
      for (int j = 0; j < 8; ++j) v[j] = 0.f;
      for (int r = 0; r < N; ++r) {
        float m = M[r];
        const float* xr = Xc + r*256 + f0;
#pragma unroll
        for (int j = 0; j < 8; ++j) v[j] += m*xr[j];
      }
    }
    union { uint4 q; ushort_t u[8]; } hi, lo;
#pragma unroll
    for (int j = 0; j < 8; ++j) {
      ushort_t h = f2bf(v[j]);
      hi.u[j] = h;
      lo.u[j] = f2bf(v[j] - bf2f(h));
    }
    size_t base = (rowbase + n)*(size_t)KX + ((size_t)c8 << 3);
    *(uint4*)(XT + base) = hi.q;
    *(uint4*)(XT + base + plane) = lo.q;
  }
}

// ---------------- precompute GEMM: 64x128 tile, 512 thr (8 waves), ring-3, XCD swizzle ----------------
__global__ __launch_bounds__(512) void gemm_pre(
    const ushort_t* __restrict__ A0, const ushort_t* __restrict__ B0, int K0, size_t plA0, size_t plB0,
    int rbS, int cbTot,
    const ushort_t* __restrict__ A1, const ushort_t* __restrict__ B1, int K1, size_t plA1, size_t plB1,
    ushort_t* __restrict__ Px0, ushort_t* __restrict__ Px1,
    const float* __restrict__ bz0, const float* __restrict__ br0, const float* __restrict__ bh0,
    const float* __restrict__ bz1, const float* __restrict__ br1, const float* __restrict__ bh1) {
  __shared__ __align__(16) ushort_t sbuf[3][24576];
  int id = blockIdx.x;
  int xx = id & 7, kq = id >> 3;
  int rbTot8 = (gridDim.x / cbTot) >> 3;
  int rb = xx*rbTot8 + kq / cbTot;
  int cb = kq - (kq / cbTot)*cbTot;

  bool isP = rb >= rbS;
  const ushort_t* A = isP ? A1 : A0;
  const ushort_t* B = isP ? B1 : B0;
  int K = isP ? K1 : K0;
  size_t plA = isP ? plA1 : plA0, plB = isP ? plB1 : plB0;
  int row0 = (isP ? rb - rbS : rb) * 64;
  int col0 = cb * 128;
  int tid = threadIdx.x, lane = tid & 63, w = tid >> 6;
  int l15 = lane & 15, l4 = lane >> 4;
  int wr = (w >> 2) * 32, wc = (w & 3) * 32;

  const ushort_t* srcb[6];
  int ldso[6];
#pragma unroll
  for (int j = 0; j < 6; ++j) {
    int s = j*8 + w;
    int c = (s << 6) + lane;
    const ushort_t* base;
    if (c < 1024) {
      int pl = c >> 9, a = c & 511, r = a >> 3, kb = a & 7;
      base = A + (size_t)pl*plA + (size_t)(row0 + r)*K + ((kb ^ (r & 7)) << 3);
    } else {
      int d = c - 1024, pl = d >> 10, bi = d & 1023, r = bi >> 3, kb = bi & 7;
      base = B + (size_t)pl*plB + (size_t)(col0 + r)*K + ((kb ^ (r & 7)) << 3);
    }
    srcb[j] = base;
    ldso[j] = c << 3;
  }

  f32x4 acc[2][2];
#pragma unroll
  for (int i = 0; i < 2; ++i)
#pragma unroll
    for (int j = 0; j < 2; ++j) acc[i][j] = (f32x4){0.f,0.f,0.f,0.f};

  int nk = K >> 6;
#define STAGEP(K0E, BUFP)  { ushort_t* _b = (BUFP); _Pragma("unroll") \
    for (int j = 0; j < 6; ++j) gl16(srcb[j] + (K0E), _b + ldso[j]); }

  STAGEP(0,   &sbuf[0][0]);
  STAGEP(64,  &sbuf[1][0]);
  STAGEP(128, &sbuf[2][0]);

  for (int k = 0; k < nk; ++k) {
    int rem = nk - 1 - k;
    if (rem >= 2)      asm volatile("s_waitcnt vmcnt(12)" ::: "memory");
    else if (rem == 1) asm volatile("s_waitcnt vmcnt(6)" ::: "memory");
    else               asm volatile("s_waitcnt vmcnt(0)" ::: "memory");
    __builtin_amdgcn_s_barrier();
    int kb3 = k % 3;
    const ushort_t* cur = &sbuf[kb3][0];
    const ushort_t* cA0 = cur;
    const ushort_t* cA1 = cur + 4096;
    const ushort_t* cB0 = cur + 8192;
    const ushort_t* cB1 = cur + 16384;
#pragma unroll
    for (int kk = 0; kk < 2; ++kk) {
      bf16x8 af[2][2], bq[2][2];
#pragma unroll
      for (int mi = 0; mi < 2; ++mi) {
        int r = wr + mi*16 + l15;
        int sb = (kk*4 + l4) ^ (r & 7);
        af[0][mi] = *(const bf16x8*)&cA0[r*64 + sb*8];
        af[1][mi] = *(const bf16x8*)&cA1[r*64 + sb*8];
      }
#pragma unroll
      for (int ni = 0; ni < 2; ++ni) {
        int r = wc + ni*16 + l15;
        int sb = (kk*4 + l4) ^ (r & 7);
        bq[0][ni] = *(const bf16x8*)&cB0[r*64 + sb*8];
        bq[1][ni] = *(const bf16x8*)&cB1[r*64 + sb*8];
      }
#pragma unroll
      for (int mi = 0; mi < 2; ++mi)
#pragma unroll
        for (int ni = 0; ni < 2; ++ni) {
          acc[mi][ni] = __builtin_amdgcn_mfma_f32_16x16x32_bf16(af[0][mi], bq[0][ni], acc[mi][ni], 0, 0, 0);
          acc[mi][ni] = __builtin_amdgcn_mfma_f32_16x16x32_bf16(af[0][mi], bq[1][ni], acc[mi][ni], 0, 0, 0);
          acc[mi][ni] = __builtin_amdgcn_mfma_f32_16x16x32_bf16(af[1][mi], bq[0][ni], acc[mi][ni], 0, 0, 0);
        }
    }
    __builtin_amdgcn_s_barrier();
    if (k + 3 < nk) STAGEP((k + 3) << 6, &sbuf[kb3][0]);
  }
#undef STAGEP

  ushort_t* PxO = isP ? Px1 : Px0;
#pragma unroll
  for (int mi = 0; mi < 2; ++mi)
#pragma unroll
    for (int ni = 0; ni < 2; ++ni) {
      int colg = col0 + wc + ni*16 + l15;
      const float* bias = (colg < 256) ? (isP ? bz1 : bz0)
                        : (colg < 512) ? (isP ? br1 : br0)
                                       : (isP ? bh1 : bh0);
#pragma unroll
      for (int rg = 0; rg < 4; ++rg) {
        int grow = row0 + wr + mi*16 + l4*4 + rg;
        PxO[(size_t)grow*NPRE + colg] = f2bf(acc[mi][ni][rg] + bias[colg & 255]);
      }
    }
}

// ---------------- recurrence GEMM: Y = Ahl @ Bhl^T, K=256, k32 chunks, ring-3 (72KB), 512 thr ----------------
__global__ __launch_bounds__(512) void gemm_y(
    const ushort_t* __restrict__ A0, const ushort_t* __restrict__ B0, float* __restrict__ C0, int NC0, int cb0, int nb0,
    const ushort_t* __restrict__ A1, const ushort_t* __restrict__ B1, float* __restrict__ C1, int NC1, int cb1) {
  __shared__ __align__(16) ushort_t sbuf[3][12288];
  int id = blockIdx.x;
  int rb, cb; const ushort_t *A, *B; float* C; int NC;
  if (id < nb0) { rb = id / cb0; cb = id % cb0; A = A0; B = B0; C = C0; NC = NC0; }
  else { int q = id - nb0; rb = q / cb1; cb = q % cb1; A = A1; B = B1; C = C1; NC = NC1; }
  int row0 = rb*64, col0 = cb*128;
  int tid = threadIdx.x, lane = tid & 63, w = tid >> 6;
  int l15 = lane & 15, l4 = lane >> 4;
  int wr = (w >> 2) * 32, wc = (w & 3) * 32;

  // chunk = 32 k-elems; buffer: A[pl][64r][32] | B[pl][128r][32], linear (64B rows -> no swizzle needed)
  const ushort_t* srcb[3];
  int ldso[3];
#pragma unroll
  for (int j = 0; j < 3; ++j) {
    int s = j*8 + w;
    int c = (s << 6) + lane;          // 0..1535
    const ushort_t* base;
    if (c < 512) {
      int pl = c >> 8, a = c & 255, r = a >> 2, kb = a & 3;
      base = A + (size_t)(row0 + r)*512 + pl*256 + kb*8;
    } else {
      int d = c - 512, pl = d >> 9, bi = d & 511, r = bi >> 2, kb = bi & 3;
      base = B + (size_t)(col0 + r)*512 + pl*256 + kb*8;
    }
    srcb[j] = base;
    ldso[j] = c << 3;
  }

  f32x4 acc[2][2];
#pragma unroll
  for (int i = 0; i < 2; ++i)
#pragma unroll
    for (int j = 0; j < 2; ++j) acc[i][j] = (f32x4){0.f,0.f,0.f,0.f};

#define STAGEY(K0E, BUFP)  { ushort_t* _b = (BUFP); _Pragma("unroll") \
    for (int j = 0; j < 3; ++j) gl16(srcb[j] + (K0E), _b + ldso[j]); }

  STAGEY(0,  &sbuf[0][0]);
  STAGEY(32, &sbuf[1][0]);
  STAGEY(64, &sbuf[2][0]);

  for (int k = 0; k < 8; ++k) {
    int rem = 7 - k;
    if (rem >= 2)      asm volatile("s_waitcnt vmcnt(6)" ::: "memory");
    else if (rem == 1) asm volatile("s_waitcnt vmcnt(3)" ::: "memory");
    else               asm volatile("s_waitcnt vmcnt(0)" ::: "memory");
    __builtin_amdgcn_s_barrier();
    int kb3 = k % 3;
    const ushort_t* cur = &sbuf[kb3][0];
    bf16x8 af[2][2], bq[2][2];
#pragma unroll
    for (int mi = 0; mi < 2; ++mi) {
      int r = wr + mi*16 + l15;
      af[0][mi] = *(const bf16x8*)&cur[r*32 + l4*8];
      af[1][mi] = *(const bf16x8*)&cur[2048 + r*32 + l4*8];
    }
#pragma unroll
    for (int ni = 0; ni < 2; ++ni) {
      int r = wc + ni*16 + l15;
      bq[0][ni] = *(const bf16x8*)&cur[4096 + r*32 + l4*8];
      bq[1][ni] = *(const bf16x8*)&cur[8192 + r*32 + l4*8];
    }
#pragma unroll
    for (int mi = 0; mi < 2; ++mi)
#pragma unroll
      for (int ni = 0; ni < 2; ++ni) {
        acc[mi][ni] = __builtin_amdgcn_mfma_f32_16x16x32_bf16(af[0][mi], bq[0][ni], acc[mi][ni], 0, 0, 0);
        acc[mi][ni] = __builtin_amdgcn_mfma_f32_16x16x32_bf16(af[0][mi], bq[1][ni], acc[mi][ni], 0, 0, 0);
        acc[mi][ni] = __builtin_amdgcn_mfma_f32_16x16x32_bf16(af[1][mi], bq[0][ni], acc[mi][ni], 0, 0, 0);
      }
    __builtin_amdgcn_s_barrier();
    if (k + 3 < 8) STAGEY((k + 3) << 5, &sbuf[kb3][0]);
  }
#undef STAGEY

#pragma unroll
  for (int mi = 0; mi < 2; ++mi)
#pragma unroll
    for (int ni = 0; ni < 2; ++ni) {
      int colg = col0 + wc + ni*16 + l15;
#pragma unroll
      for (int rg = 0; rg < 4; ++rg) {
        int grow = row0 + wr + mi*16 + l4*4 + rg;
        C[(size_t)grow*NC + colg] = acc[mi][ni][rg];
      }
    }
}

// ---------------- node contraction + GRU epilogues (vectorized) ----------------
template<int GATE>
__global__ __launch_bounds__(256) void contract_k(
    const float* __restrict__ Ys, const float* __restrict__ Yp,
    const ushort_t* __restrict__ Px_s, const ushort_t* __restrict__ Px_p,
    const float* __restrict__ Mb_s, const float* __restrict__ Mb_p,
    const float* __restrict__ Hin, float* __restrict__ Z,
    ushort_t* __restrict__ Out_s, ushort_t* __restrict__ Out_p,
    float* __restrict__ Hout) {
  constexpr int JB = GATE ? 2 : 4;
  constexpr int JW = GATE ? 256 : 512;
  __shared__ float Yl[100*128];
  __shared__ float Mb[NSN*100];
  int id = blockIdx.x, tid = threadIdx.x;
  bool isP = id >= NB*JB;
  int q = isP ? id - NB*JB : id;
  int b = q / JB, jb = q % JB;
  int N = isP ? NPN : NSN, ntau = isP ? 3 : 5;
  int nseg = N * ntau;
  int NC = ntau * JW;
  const float* Y = isP ? Yp : Ys;
  const float* Mbg = isP ? Mb_p : Mb_s;
  f32x4* Yl4 = (f32x4*)Yl;
  int tot4 = nseg << 5;
  for (int i = tid; i < tot4; i += 256) {
    int seg = i >> 5, q4 = i & 31;
    int r = seg / ntau, tau = seg - r*ntau;
    Yl4[i] = *(const f32x4*)&Y[(size_t)(b*N + r)*NC + tau*JW + jb*128 + (q4 << 2)];
  }
  for (int i = tid; i < N*nseg; i += 256) Mb[i] = Mbg[i];
  __syncthreads();
  const ushort_t* Px = isP ? Px_p : Px_s;
  ushort_t* Out = isP ? Out_p : Out_s;
  int hoff = isP ? NSN : 0;
  int nout4 = N << 5;
  for (int o = tid; o < nout4; o += 256) {
    int n = o >> 5, j4 = o & 31;
    int j = jb*128 + (j4 << 2);
    f32x4 p = (f32x4){0.f,0.f,0.f,0.f};
    const float* mrow = Mb + n*nseg;
    for (int s = 0; s < nseg; ++s) {
      float m = mrow[s];
      f32x4 y = Yl4[(s << 5) + j4];
      p += m*y;
    }
    const ushort_t* pxp = Px + (size_t)(b*N + n)*NPRE + (GATE ? 512 : 0) + j;
#pragma unroll
    for (int e = 0; e < 4; ++e) p[e] += bf2f(pxp[e]);
    if constexpr (GATE == 0) {
      if (j < 256) {
        f32x4 sg;
#pragma unroll
        for (int e = 0; e < 4; ++e) sg[e] = 1.f/(1.f + expf(-p[e]));
        *(f32x4*)&Z[((size_t)b*NN + hoff + n)*256 + j] = sg;
      } else {
        int f = j - 256;
        f32x4 h = *(const f32x4*)&Hin[((size_t)b*NN + hoff + n)*256 + f];
        union { uint2 q; ushort_t u[4]; } hi, lo;
#pragma unroll
        for (int e = 0; e < 4; ++e) {
          float gh = h[e]/(1.f + expf(-p[e]));
          ushort_t hb = f2bf(gh);
          hi.u[e] = hb; lo.u[e] = f2bf(gh - bf2f(hb));
        }
        ushort_t* op = Out + (size_t)(b*N + n)*512 + f;
        *(uint2*)op = hi.q;
        *(uint2*)(op + 256) = lo.q;
      }
    } else {
      size_t hidx = ((size_t)b*NN + hoff + n)*256 + j;
      f32x4 zv = *(const f32x4*)&Z[hidx];
      f32x4 hv = *(const f32x4*)&Hin[hidx];
      f32x4 hn;
      union { uint2 q; ushort_t u[4]; } hi, lo;
#pragma unroll
      for (int e = 0; e < 4; ++e) {
        float ht = tanhf(p[e]);
        hn[e] = zv[e]*hv[e] + (1.f - zv[e])*ht;
        ushort_t hb = f2bf(hn[e]);
        hi.u[e] = hb; lo.u[e] = f2bf(hn[e] - bf2f(hb));
      }
      *(f32x4*)&Hout[hidx] = hn;
      ushort_t* op = Out + (size_t)(b*N + n)*512 + j;
      *(uint2*)op = hi.q;
      *(uint2*)(op + 256) = lo.q;
    }
  }
}

// ---------------- readout ----------------
__global__ __launch_bounds__(256) void readout_k(const float* __restrict__ H, const float* __restrict__ W_ro,
                                                 const float* __restrict__ b_ro, const float* __restrict__ W_ag,
                                                 const float* __restrict__ b_ag, float* __restrict__ out) {
  __shared__ float red[256];
  __shared__ float o1[NN];
  int b = blockIdx.x, tid = threadIdx.x;
  float wro = W_ro[tid];
  for (int n = 0; n < NN; ++n) {
    red[tid] = H[((size_t)b*NN + n)*256 + tid] * wro;
    __syncthreads();
    for (int s = 128; s > 0; s >>= 1) { if (tid < s) red[tid] += red[tid+s]; __syncthreads(); }
    if (tid == 0) o1[n] = red[0] + b_ro[0];
    __syncthreads();
  }
  if (tid < 5) {
    float s = b_ag[tid];
    for (int n = 0; n < NN; ++n) s += o1[n] * W_ag[n*5 + tid];
    out[b*5 + tid] = s;
  }
}

// ---------------- host ----------------
extern "C" void kernel_launch(void* const* d_in, const int* in_sizes, int n_in,
                              void* d_out, int out_size, void* d_ws, size_t ws_size,
                              hipStream_t stream) {
  const float* xdis = (const float*)d_in[0];
  const float* xpre = (const float*)d_in[1];
  const int*   ei_s = (const int*)d_in[2];
  const int*   ei_p = (const int*)d_in[3];
  const float* ew_s = (const float*)d_in[4];
  const float* ew_p = (const float*)d_in[5];
  const float* Wz_s = (const float*)d_in[6];
  const float* bz_s = (const float*)d_in[7];
  const float* Wr_s = (const float*)d_in[8];
  const float* br_s = (const float*)d_in[9];
  const float* Wh_s = (const float*)d_in[10];
  const float* bh_s = (const float*)d_in[11];
  const float* Wz_p = (const float*)d_in[12];
  const float* bz_p = (const float*)d_in[13];
  const float* Wr_p = (const float*)d_in[14];
  const float* br_p = (const float*)d_in[15];
  const float* Wh_p = (const float*)d_in[16];
  const float* bh_p = (const float*)d_in[17];
  const float* W_ro = (const float*)d_in[18];
  const float* b_ro = (const float*)d_in[19];
  const float* W_ag = (const float*)d_in[20];
  const float* b_ag = (const float*)d_in[21];
  float* out = (float*)d_out;
  (void)in_sizes; (void)n_in; (void)out_size; (void)ws_size;

  char* w = (char*)d_ws;
  size_t off = 0;
  auto alloc = [&](size_t bytes) { void* p = w + off; off = (off + bytes + 255) & ~(size_t)255; return p; };

  const size_t plWXs = (size_t)768*KHS, plWXp = (size_t)768*KHP;
  const size_t rowsXs = (size_t)TCH*NB*NSN, rowsXp = (size_t)TCH*NB*NPN;
  const size_t plXs_pre = rowsXs*KHS, plXp_pre = rowsXp*KHP;

  float* Ms_s = (float*)alloc(4*NSN*NSN*sizeof(float));
  float* Ms_p = (float*)alloc(2*NPN*NPN*sizeof(float));
  float* Mbig_s = (float*)alloc(NSN*100*sizeof(float));
  float* Mbig_p = (float*)alloc(NPN*24*sizeof(float));
  ushort_t* WX_s = (ushort_t*)alloc(plWXs*2*2);
  ushort_t* WX_p = (ushort_t*)alloc(plWXp*2*2);
  ushort_t* WHzr_s = (ushort_t*)alloc((size_t)2560*512*2);
  ushort_t* WHh_s  = (ushort_t*)alloc((size_t)1280*512*2);
  ushort_t* WHzr_p = (ushort_t*)alloc((size_t)1536*512*2);
  ushort_t* WHh_p  = (ushort_t*)alloc((size_t)768*512*2);
  ushort_t* XT_s = (ushort_t*)alloc(plXs_pre*2*2);
  ushort_t* XT_p = (ushort_t*)alloc(plXp_pre*2*2);
  ushort_t* Px_s = (ushort_t*)alloc((size_t)TT*NB*NSN*NPRE*2);
  ushort_t* Px_p = (ushort_t*)alloc((size_t)TT*NB*NPN*NPRE*2);
  float* Yzr_s = (float*)alloc((size_t)NB*NSN*2560*4);
  float* Yzr_p = (float*)alloc((size_t)NB*NPN*1536*4);
  float* H  = (float*)alloc((size_t)NB*NN*256*4);
  float* Z  = (float*)alloc((size_t)NB*NN*256*4);
  ushort_t* Hhl_s  = (ushort_t*)alloc((size_t)NB*NSN*512*2);
  ushort_t* Hhl_p  = (ushort_t*)alloc((size_t)NB*NPN*512*2);
  ushort_t* gHhl_s = (ushort_t*)alloc((size_t)NB*NSN*512*2);
  ushort_t* gHhl_p = (ushort_t*)alloc((size_t)NB*NPN*512*2);

  graph_build<<<1, 64, 0, stream>>>(ei_s, ew_s, ei_p, ew_p, Ms_s, Ms_p, Mbig_s, Mbig_p);
  prep_w<<<1024, 256, 0, stream>>>(Wz_s, Wr_s, Wh_s, Wz_p, Wr_p, Wh_p,
                                   WX_s, WX_p, WHzr_s, WHh_s, WHzr_p, WHh_p);
  const long nH = (long)NB*NN*256;
  zero_f<<<(nH + 255)/256, 256, 0, stream>>>(H, nH);
  const long nHhl = ((long)NB*NSN*512 + (long)NB*NPN*512) / 2;
  zero_f<<<(nHhl + 255)/256, 256, 0, stream>>>((float*)Hhl_s, nHhl);

  // ---- precompute Px ----
  for (int t0 = 0; t0 < TT; t0 += TCH) {
    chebx<<<2*NB*TCH, 256, 0, stream>>>(xdis, xpre, Ms_s, Ms_p, XT_s, XT_p, plXs_pre, plXp_pre, t0);
    gemm_pre<<<224*6, 512, 0, stream>>>(
        XT_s, WX_s, KHS, plXs_pre, plWXs, 160, 6,
        XT_p, WX_p, KHP, plXp_pre, plWXp,
        Px_s + (size_t)t0*NB*NSN*NPRE, Px_p + (size_t)t0*NB*NPN*NPRE,
        bz_s, br_s, bh_s, bz_p, br_p, bh_p);
  }

  // ---- recurrence ----
  for (int t = 0; t < TT; ++t) {
    const ushort_t* PxS = Px_s + (size_t)t*NB*NSN*NPRE;
    const ushort_t* PxP = Px_p + (size_t)t*NB*NPN*NPRE;
    gemm_y<<<800 + 192, 512, 0, stream>>>(Hhl_s, WHzr_s, Yzr_s, 2560, 20, 800,
                                          Hhl_p, WHzr_p, Yzr_p, 1536, 12);
    contract_k<0><<<NB*4*2, 256, 0, stream>>>(Yzr_s, Yzr_p, PxS, PxP, Mbig_s, Mbig_p,
                                              H, Z, gHhl_s, gHhl_p, nullptr);
    gemm_y<<<400 + 96, 512, 0, stream>>>(gHhl_s, WHh_s, Yzr_s, 1280, 10, 400,
                                         gHhl_p, WHh_p, Yzr_p, 768, 6);
    contract_k<1><<<NB*2*2, 256, 0, stream>>>(Yzr_s, Yzr_p, PxS, PxP, Mbig_s, Mbig_p,
                                              H, Z, Hhl_s, Hhl_p, H);
  }
  readout_k<<<NB, 256, 0, stream>>>(H, W_ro, b_ro, W_ag, b_ag, out);
}

// Round 7
// 2167.893 us; speedup vs baseline: 5.0830x; 1.1998x over previous
//
#include <hip/hip_runtime.h>
#include <stdint.h>

#define NSN 20
#define NPN 8
#define NB 128
#define TT 24
#define NN 28
#define ES 100
#define EP 32
#define KHS 1280   // 5*256 (precompute K)
#define KHP 768    // 3*256
#define NPRE 768   // z|r|h output cols
#define TCH 4      // precompute time-chunk

typedef __attribute__((ext_vector_type(8))) __bf16 bf16x8;
typedef __attribute__((ext_vector_type(4))) float f32x4;
typedef unsigned short ushort_t;

__device__ __forceinline__ ushort_t f2bf(float f) {
  union { float f; unsigned int u; } x; x.f = f;
  unsigned int u = x.u + 0x7fffu + ((x.u >> 16) & 1u);
  return (ushort_t)(u >> 16);
}
__device__ __forceinline__ float bf2f(ushort_t h) {
  union { unsigned int u; float f; } x; x.u = (unsigned int)h << 16; return x.f;
}
__device__ __forceinline__ void put_hl(ushort_t* dst, size_t idx, size_t plane, float v) {
  ushort_t hi = f2bf(v);
  dst[idx] = hi;
  dst[idx + plane] = f2bf(v - bf2f(hi));
}
__device__ __forceinline__ void gl16(const ushort_t* g, ushort_t* l) {
  __builtin_amdgcn_global_load_lds((const __attribute__((address_space(1))) void*)g,
                                   (__attribute__((address_space(3))) void*)l, 16, 0, 0);
}

// ---------------- graph build ----------------
__global__ void graph_build(const int* __restrict__ ei_s, const float* __restrict__ ew_s,
                            const int* __restrict__ ei_p, const float* __restrict__ ew_p,
                            float* __restrict__ Ms_s, float* __restrict__ Ms_p,
                            float* __restrict__ Mbig_s, float* __restrict__ Mbig_p) {
  __shared__ float Ao[NSN*NSN], Aiw[NSN*NSN], dgo[NSN], dgi[NSN];
  __shared__ float T2o[NSN*NSN], T2i[NSN*NSN];
  __shared__ float Aop[NPN*NPN], Aip[NPN*NPN], dgop[NPN], dgip[NPN];
  int tid = threadIdx.x;
  for (int i = tid; i < NSN*NSN; i += blockDim.x) { Ao[i] = 0.f; Aiw[i] = 0.f; }
  for (int i = tid; i < NPN*NPN; i += blockDim.x) { Aop[i] = 0.f; Aip[i] = 0.f; }
  if (tid < NSN) { dgo[tid] = 0.f; dgi[tid] = 0.f; }
  if (tid < NPN) { dgop[tid] = 0.f; dgip[tid] = 0.f; }
  __syncthreads();
  if (tid == 0) {
    for (int e = 0; e < ES; ++e) { int r = ei_s[e], c = ei_s[ES+e]; float w = ew_s[e]; dgo[r] += w; dgi[c] += w; }
    for (int e = 0; e < ES; ++e) { int r = ei_s[e], c = ei_s[ES+e]; Ao[c*NSN+r] += 1.f/dgo[r]; Aiw[c*NSN+r] += 1.f/dgi[r]; }
  }
  if (tid == 1) {
    for (int e = 0; e < EP; ++e) { int r = ei_p[e], c = ei_p[EP+e]; float w = ew_p[e]; dgop[r] += w; dgip[c] += w; }
    for (int e = 0; e < EP; ++e) { int r = ei_p[e], c = ei_p[EP+e]; Aop[c*NPN+r] += 1.f/dgop[r]; Aip[c*NPN+r] += 1.f/dgip[r]; }
  }
  __syncthreads();
  for (int i = tid; i < NSN*NSN; i += blockDim.x) {
    int r = i / NSN, c = i % NSN;
    float so = 0.f, si = 0.f;
    for (int k = 0; k < NSN; ++k) { so += Ao[r*NSN+k]*Ao[k*NSN+c]; si += Aiw[r*NSN+k]*Aiw[k*NSN+c]; }
    float t2o = 2.f*so - (r==c ? 1.f : 0.f);
    float t2i = 2.f*si - (r==c ? 1.f : 0.f);
    T2o[i] = t2o; T2i[i] = t2i;
    Ms_s[0*NSN*NSN + i] = Ao[i];
    Ms_s[1*NSN*NSN + i] = Aiw[i];
    Ms_s[2*NSN*NSN + i] = t2o;
    Ms_s[3*NSN*NSN + i] = t2i;
  }
  for (int i = tid; i < NPN*NPN; i += blockDim.x) {
    Ms_p[0*NPN*NPN + i] = Aop[i];
    Ms_p[1*NPN*NPN + i] = Aip[i];
  }
  __syncthreads();
  for (int i = tid; i < NSN*NSN*5; i += blockDim.x) {
    int n = i / 100, s = i % 100, r = s / 5, tau = s % 5;
    float v;
    if (tau == 0) v = (n == r) ? 1.f : 0.f;
    else if (tau == 1) v = Ao[n*NSN + r];
    else if (tau == 2) v = Aiw[n*NSN + r];
    else if (tau == 3) v = T2o[n*NSN + r];
    else               v = T2i[n*NSN + r];
    Mbig_s[i] = v;
  }
  for (int i = tid; i < NPN*NPN*3; i += blockDim.x) {
    int n = i / 24, s = i % 24, r = s / 3, tau = s % 3;
    float v;
    if (tau == 0) v = (n == r) ? 1.f : 0.f;
    else if (tau == 1) v = Aop[n*NPN + r];
    else               v = Aip[n*NPN + r];
    Mbig_p[i] = v;
  }
}

// ---------------- weight prep ----------------
__device__ __forceinline__ float wsrc(const float* W, int Kdim, int tau, int i, int jj) {
  if (tau == 0) return W[(size_t)(0*Kdim+0)*512*256 + (size_t)i*256 + jj]
                     + W[(size_t)(1*Kdim+0)*512*256 + (size_t)i*256 + jj];
  int dir = (tau - 1) & 1;
  int k = (tau + 1) >> 1;
  return W[(size_t)(dir*Kdim + k)*512*256 + (size_t)i*256 + jj];
}

__global__ void prep_w(const float* __restrict__ Wz_s, const float* __restrict__ Wr_s, const float* __restrict__ Wh_s,
                       const float* __restrict__ Wz_p, const float* __restrict__ Wr_p, const float* __restrict__ Wh_p,
                       ushort_t* __restrict__ WX_s, ushort_t* __restrict__ WX_p,
                       ushort_t* __restrict__ WHzr_s, ushort_t* __restrict__ WHh_s,
                       ushort_t* __restrict__ WHzr_p, ushort_t* __restrict__ WHh_p) {
  const long c0 = (long)768*KHS;
  const long c1 = c0 + (long)768*KHP;
  const long c2 = c1 + (long)2560*256;
  const long c3 = c2 + (long)1280*256;
  const long c4 = c3 + (long)1536*256;
  const long c5 = c4 + (long)768*256;
  for (long idx = (long)blockIdx.x*256 + threadIdx.x; idx < c5; idx += (long)gridDim.x*256) {
    if (idx < c0) {
      long x = idx; int j = (int)(x / KHS), c = (int)(x % KHS); int tau = c >> 8;
      const float* W = (j < 256) ? Wz_s : (j < 512) ? Wr_s : Wh_s;
      // hi plane only used by gemm_pre (2-term); write hi only
      WX_s[x] = f2bf(wsrc(W, 3, tau, c & 255, j & 255));
    } else if (idx < c1) {
      long x = idx - c0; int j = (int)(x / KHP), c = (int)(x % KHP); int tau = c >> 8;
      const float* W = (j < 256) ? Wz_p : (j < 512) ? Wr_p : Wh_p;
      WX_p[x] = f2bf(wsrc(W, 2, tau, c & 255, j & 255));
    } else if (idx < c2) {
      long x = idx - c1; int cc = (int)(x >> 8), f = (int)(x & 255);
      int tau = cc / 512, j = cc % 512;
      const float* W = (j < 256) ? Wz_s : Wr_s;
      put_hl(WHzr_s, (size_t)cc*512 + f, 256, wsrc(W, 3, tau, 256 + f, j & 255));
    } else if (idx < c3) {
      long x = idx - c2; int cc = (int)(x >> 8), f = (int)(x & 255);
      int tau = cc >> 8, j = cc & 255;
      put_hl(WHh_s, (size_t)cc*512 + f, 256, wsrc(Wh_s, 3, tau, 256 + f, j));
    } else if (idx < c4) {
      long x = idx - c3; int cc = (int)(x >> 8), f = (int)(x & 255);
      int tau = cc / 512, j = cc % 512;
      const float* W = (j < 256) ? Wz_p : Wr_p;
      put_hl(WHzr_p, (size_t)cc*512 + f, 256, wsrc(W, 2, tau, 256 + f, j & 255));
    } else {
      long x = idx - c4; int cc = (int)(x >> 8), f = (int)(x & 255);
      int tau = cc >> 8, j = cc & 255;
      put_hl(WHh_p, (size_t)cc*512 + f, 256, wsrc(Wh_p, 2, tau, 256 + f, j));
    }
  }
}

__global__ void zero_f(float* p, long n) {
  long i = (long)blockIdx.x*256 + threadIdx.x;
  if (i < n) p[i] = 0.f;
}

// ---------------- cheb expansion of X (precompute A) ----------------
__global__ __launch_bounds__(256) void chebx(const float* __restrict__ xdis, const float* __restrict__ xpre,
                                             const float* __restrict__ Ms_s, const float* __restrict__ Ms_p,
                                             ushort_t* __restrict__ XTs, ushort_t* __restrict__ XTp,
                                             size_t plXs, size_t plXp, int t0) {
  __shared__ float Xc[NSN*256];
  __shared__ float Ml[4*NSN*NSN];
  int bb = blockIdx.x, tid = threadIdx.x;
  bool isP = bb >= NB*TCH;
  int q = isP ? bb - NB*TCH : bb;
  int b = q % NB, tp = q / NB;
  int N = isP ? NPN : NSN, nt = isP ? 3 : 5, KX = nt << 8;
  const float* X = isP ? (xpre + (size_t)(b*TT + t0 + tp)*NPN*256)
                       : (xdis + (size_t)(b*TT + t0 + tp)*NSN*256);
  for (int i = tid; i < N*64; i += 256) ((float4*)Xc)[i] = ((const float4*)X)[i];
  int nm = (nt-1)*N*N;
  const float* Msrc = isP ? Ms_p : Ms_s;
  for (int i = tid; i < nm; i += 256) Ml[i] = Msrc[i];
  __syncthreads();
  ushort_t* XT = isP ? XTp : XTs;
  size_t plane = isP ? plXp : plXs;
  size_t rowbase = (size_t)(tp*NB + b)*N;
  int kc8 = KX >> 3, nch = N * kc8;
  for (int i = tid; i < nch; i += 256) {
    int n = i / kc8, c8 = i - n*kc8;
    int tau = c8 >> 5, f0 = (c8 & 31) << 3;
    float v[8];
    if (tau == 0) {
      const float* xr0 = Xc + n*256 + f0;
#pragma unroll
      for (int j = 0; j < 8; ++j) v[j] = xr0[j];
    } else {
      const float* M = Ml + (tau-1)*N*N + n*N;
#pragma unroll
      for (int j = 0; j < 8; ++j) v[j] = 0.f;
      for (int r = 0; r < N; ++r) {
        float m = M[r];
        const float* xr = Xc + r*256 + f0;
#pragma unroll
        for (int j = 0; j < 8; ++j) v[j] += m*xr[j];
      }
    }
    union { uint4 q; ushort_t u[8]; } hi, lo;
#pragma unroll
    for (int j = 0; j < 8; ++j) {
      ushort_t h = f2bf(v[j]);
      hi.u[j] = h;
      lo.u[j] = f2bf(v[j] - bf2f(h));
    }
    size_t base = (rowbase + n)*(size_t)KX + ((size_t)c8 << 3);
    *(uint4*)(XT + base) = hi.q;
    *(uint4*)(XT + base + plane) = lo.q;
  }
}

// ---------------- precompute GEMM: 2-term (A hi+lo, B hi), BK=32, ring-3 48KB (3 blocks/CU) ----------------
__global__ __launch_bounds__(512) void gemm_pre(
    const ushort_t* __restrict__ A0, const ushort_t* __restrict__ B0, int K0, size_t plA0,
    int rbS, int cbTot,
    const ushort_t* __restrict__ A1, const ushort_t* __restrict__ B1, int K1, size_t plA1,
    ushort_t* __restrict__ Px0, ushort_t* __restrict__ Px1,
    const float* __restrict__ bz0, const float* __restrict__ br0, const float* __restrict__ bh0,
    const float* __restrict__ bz1, const float* __restrict__ br1, const float* __restrict__ bh1) {
  __shared__ __align__(16) ushort_t sbuf[3][8192];   // per buf: A 2pl x 64x32 | B hi 128x32
  int id = blockIdx.x;
  int xx = id & 7, kq = id >> 3;
  int rbTot8 = (gridDim.x / cbTot) >> 3;
  int rb = xx*rbTot8 + kq / cbTot;
  int cb = kq - (kq / cbTot)*cbTot;

  bool isP = rb >= rbS;
  const ushort_t* A = isP ? A1 : A0;
  const ushort_t* B = isP ? B1 : B0;
  int K = isP ? K1 : K0;
  size_t plA = isP ? plA1 : plA0;
  int row0 = (isP ? rb - rbS : rb) * 64;
  int col0 = cb * 128;
  int tid = threadIdx.x, lane = tid & 63, w = tid >> 6;
  int l15 = lane & 15, l4 = lane >> 4;
  int wr = (w >> 2) * 32, wc = (w & 3) * 32;

  const ushort_t* srcb[2];
  int ldso[2];
#pragma unroll
  for (int j = 0; j < 2; ++j) {
    int c = ((j*8 + w) << 6) + lane;     // 0..1023 chunks of 16B
    const ushort_t* base;
    if (c < 512) {
      int pl = c >> 8, a = c & 255, r = a >> 2, kb = a & 3;
      base = A + (size_t)pl*plA + (size_t)(row0 + r)*K + ((kb ^ ((r >> 1) & 3)) << 3);
    } else {
      int d = c - 512, r = d >> 2, kb = d & 3;
      base = B + (size_t)(col0 + r)*K + ((kb ^ ((r >> 1) & 3)) << 3);
    }
    srcb[j] = base;
    ldso[j] = c << 3;
  }

  f32x4 acc[2][2];
#pragma unroll
  for (int i = 0; i < 2; ++i)
#pragma unroll
    for (int j = 0; j < 2; ++j) acc[i][j] = (f32x4){0.f,0.f,0.f,0.f};

  int nk = K >> 5;
#define STAGEP(K0E, BUFP)  { ushort_t* _b = (BUFP); _Pragma("unroll") \
    for (int j = 0; j < 2; ++j) gl16(srcb[j] + (K0E), _b + ldso[j]); }

  STAGEP(0,  &sbuf[0][0]);
  STAGEP(32, &sbuf[1][0]);
  STAGEP(64, &sbuf[2][0]);

  for (int k = 0; k < nk; ++k) {
    int rem = nk - 1 - k;
    if (rem >= 2)      asm volatile("s_waitcnt vmcnt(4)" ::: "memory");
    else if (rem == 1) asm volatile("s_waitcnt vmcnt(2)" ::: "memory");
    else               asm volatile("s_waitcnt vmcnt(0)" ::: "memory");
    __builtin_amdgcn_s_barrier();
    const ushort_t* cur = &sbuf[k % 3][0];
    bf16x8 af[2][2], bq[2];
#pragma unroll
    for (int mi = 0; mi < 2; ++mi) {
      int r = wr + mi*16 + l15;
      int sb = l4 ^ ((r >> 1) & 3);
      af[0][mi] = *(const bf16x8*)&cur[r*32 + sb*8];
      af[1][mi] = *(const bf16x8*)&cur[2048 + r*32 + sb*8];
    }
#pragma unroll
    for (int ni = 0; ni < 2; ++ni) {
      int r = wc + ni*16 + l15;
      int sb = l4 ^ ((r >> 1) & 3);
      bq[ni] = *(const bf16x8*)&cur[4096 + r*32 + sb*8];
    }
#pragma unroll
    for (int mi = 0; mi < 2; ++mi)
#pragma unroll
      for (int ni = 0; ni < 2; ++ni) {
        acc[mi][ni] = __builtin_amdgcn_mfma_f32_16x16x32_bf16(af[0][mi], bq[ni], acc[mi][ni], 0, 0, 0);
        acc[mi][ni] = __builtin_amdgcn_mfma_f32_16x16x32_bf16(af[1][mi], bq[ni], acc[mi][ni], 0, 0, 0);
      }
    __builtin_amdgcn_s_barrier();
    if (k + 3 < nk) STAGEP((k + 3) << 5, &sbuf[k % 3][0]);
  }
#undef STAGEP

  ushort_t* PxO = isP ? Px1 : Px0;
#pragma unroll
  for (int mi = 0; mi < 2; ++mi)
#pragma unroll
    for (int ni = 0; ni < 2; ++ni) {
      int colg = col0 + wc + ni*16 + l15;
      const float* bias = (colg < 256) ? (isP ? bz1 : bz0)
                        : (colg < 512) ? (isP ? br1 : br0)
                                       : (isP ? bh1 : bh0);
#pragma unroll
      for (int rg = 0; rg < 4; ++rg) {
        int grow = row0 + wr + mi*16 + l4*4 + rg;
        PxO[(size_t)grow*NPRE + colg] = f2bf(acc[mi][ni][rg] + bias[colg & 255]);
      }
    }
}

// ---------------- recurrence GEMM: Y(bf16) = Ahl @ Bhl^T, K=256, BK=32 ring-3 72KB ----------------
__global__ __launch_bounds__(512) void gemm_y(
    const ushort_t* __restrict__ A0, const ushort_t* __restrict__ B0, ushort_t* __restrict__ C0, int NC0, int cb0, int nb0,
    const ushort_t* __restrict__ A1, const ushort_t* __restrict__ B1, ushort_t* __restrict__ C1, int NC1, int cb1) {
  __shared__ __align__(16) ushort_t sbuf[3][12288];
  int id = blockIdx.x;
  int rb, cb; const ushort_t *A, *B; ushort_t* C; int NC;
  if (id < nb0) { rb = id / cb0; cb = id % cb0; A = A0; B = B0; C = C0; NC = NC0; }
  else { int q = id - nb0; rb = q / cb1; cb = q % cb1; A = A1; B = B1; C = C1; NC = NC1; }
  int row0 = rb*64, col0 = cb*128;
  int tid = threadIdx.x, lane = tid & 63, w = tid >> 6;
  int l15 = lane & 15, l4 = lane >> 4;
  int wr = (w >> 2) * 32, wc = (w & 3) * 32;

  const ushort_t* srcb[3];
  int ldso[3];
#pragma unroll
  for (int j = 0; j < 3; ++j) {
    int s = j*8 + w;
    int c = (s << 6) + lane;          // 0..1535
    const ushort_t* base;
    if (c < 512) {
      int pl = c >> 8, a = c & 255, r = a >> 2, kb = a & 3;
      base = A + (size_t)(row0 + r)*512 + pl*256 + ((kb ^ ((r >> 1) & 3)) << 3);
    } else {
      int d = c - 512, pl = d >> 9, bi = d & 511, r = bi >> 2, kb = bi & 3;
      base = B + (size_t)(col0 + r)*512 + pl*256 + ((kb ^ ((r >> 1) & 3)) << 3);
    }
    srcb[j] = base;
    ldso[j] = c << 3;
  }

  f32x4 acc[2][2];
#pragma unroll
  for (int i = 0; i < 2; ++i)
#pragma unroll
    for (int j = 0; j < 2; ++j) acc[i][j] = (f32x4){0.f,0.f,0.f,0.f};

#define STAGEY(K0E, BUFP)  { ushort_t* _b = (BUFP); _Pragma("unroll") \
    for (int j = 0; j < 3; ++j) gl16(srcb[j] + (K0E), _b + ldso[j]); }

  STAGEY(0,  &sbuf[0][0]);
  STAGEY(32, &sbuf[1][0]);
  STAGEY(64, &sbuf[2][0]);

  for (int k = 0; k < 8; ++k) {
    int rem = 7 - k;
    if (rem >= 2)      asm volatile("s_waitcnt vmcnt(6)" ::: "memory");
    else if (rem == 1) asm volatile("s_waitcnt vmcnt(3)" ::: "memory");
    else               asm volatile("s_waitcnt vmcnt(0)" ::: "memory");
    __builtin_amdgcn_s_barrier();
    const ushort_t* cur = &sbuf[k % 3][0];
    bf16x8 af[2][2], bq[2][2];
#pragma unroll
    for (int mi = 0; mi < 2; ++mi) {
      int r = wr + mi*16 + l15;
      int sb = l4 ^ ((r >> 1) & 3);
      af[0][mi] = *(const bf16x8*)&cur[r*32 + sb*8];
      af[1][mi] = *(const bf16x8*)&cur[2048 + r*32 + sb*8];
    }
#pragma unroll
    for (int ni = 0; ni < 2; ++ni) {
      int r = wc + ni*16 + l15;
      int sb = l4 ^ ((r >> 1) & 3);
      bq[0][ni] = *(const bf16x8*)&cur[4096 + r*32 + sb*8];
      bq[1][ni] = *(const bf16x8*)&cur[8192 + r*32 + sb*8];
    }
#pragma unroll
    for (int mi = 0; mi < 2; ++mi)
#pragma unroll
      for (int ni = 0; ni < 2; ++ni) {
        acc[mi][ni] = __builtin_amdgcn_mfma_f32_16x16x32_bf16(af[0][mi], bq[0][ni], acc[mi][ni], 0, 0, 0);
        acc[mi][ni] = __builtin_amdgcn_mfma_f32_16x16x32_bf16(af[0][mi], bq[1][ni], acc[mi][ni], 0, 0, 0);
        acc[mi][ni] = __builtin_amdgcn_mfma_f32_16x16x32_bf16(af[1][mi], bq[0][ni], acc[mi][ni], 0, 0, 0);
      }
    __builtin_amdgcn_s_barrier();
    if (k + 3 < 8) STAGEY((k + 3) << 5, &sbuf[k % 3][0]);
  }
#undef STAGEY

#pragma unroll
  for (int mi = 0; mi < 2; ++mi)
#pragma unroll
    for (int ni = 0; ni < 2; ++ni) {
      int colg = col0 + wc + ni*16 + l15;
#pragma unroll
      for (int rg = 0; rg < 4; ++rg) {
        int grow = row0 + wr + mi*16 + l4*4 + rg;
        C[(size_t)grow*NC + colg] = f2bf(acc[mi][ni][rg]);
      }
    }
}

// ---------------- node contraction + GRU epilogues (bf16 Y in) ----------------
template<int GATE>
__global__ __launch_bounds__(256) void contract_k(
    const ushort_t* __restrict__ Ys, const ushort_t* __restrict__ Yp,
    const ushort_t* __restrict__ Px_s, const ushort_t* __restrict__ Px_p,
    const float* __restrict__ Mb_s, const float* __restrict__ Mb_p,
    const float* __restrict__ Hin, float* __restrict__ Z,
    ushort_t* __restrict__ Out_s, ushort_t* __restrict__ Out_p,
    float* __restrict__ Hout) {
  constexpr int JB = GATE ? 2 : 4;
  constexpr int JW = GATE ? 256 : 512;
  __shared__ float Yl[100*128];
  __shared__ float Mb[NSN*100];
  int id = blockIdx.x, tid = threadIdx.x;
  bool isP = id >= NB*JB;
  int q = isP ? id - NB*JB : id;
  int b = q / JB, jb = q % JB;
  int N = isP ? NPN : NSN, ntau = isP ? 3 : 5;
  int nseg = N * ntau;
  int NC = ntau * JW;
  const ushort_t* Y = isP ? Yp : Ys;
  const float* Mbg = isP ? Mb_p : Mb_s;
  int tot8 = nseg << 4;   // 16 groups of 8 per 128-col seg
  for (int i = tid; i < tot8; i += 256) {
    int seg = i >> 4, q8 = i & 15;
    int r = seg / ntau, tau = seg - r*ntau;
    union { uint4 qq; ushort_t u[8]; } uu;
    uu.qq = *(const uint4*)&Y[(size_t)(b*N + r)*NC + tau*JW + jb*128 + (q8 << 3)];
    float* dst = Yl + (seg << 7) + (q8 << 3);
#pragma unroll
    for (int e = 0; e < 8; ++e) dst[e] = bf2f(uu.u[e]);
  }
  for (int i = tid; i < N*nseg; i += 256) Mb[i] = Mbg[i];
  __syncthreads();
  f32x4* Yl4 = (f32x4*)Yl;
  const ushort_t* Px = isP ? Px_p : Px_s;
  ushort_t* Out = isP ? Out_p : Out_s;
  int hoff = isP ? NSN : 0;
  int nout4 = N << 5;
  for (int o = tid; o < nout4; o += 256) {
    int n = o >> 5, j4 = o & 31;
    int j = jb*128 + (j4 << 2);
    f32x4 p = (f32x4){0.f,0.f,0.f,0.f};
    const float* mrow = Mb + n*nseg;
    for (int s = 0; s < nseg; ++s) {
      float m = mrow[s];
      f32x4 y = Yl4[(s << 5) + j4];
      p += m*y;
    }
    union { uint2 qq; ushort_t u[4]; } pu;
    pu.qq = *(const uint2*)&Px[(size_t)(b*N + n)*NPRE + (GATE ? 512 : 0) + j];
#pragma unroll
    for (int e = 0; e < 4; ++e) p[e] += bf2f(pu.u[e]);
    if constexpr (GATE == 0) {
      if (j < 256) {
        f32x4 sg;
#pragma unroll
        for (int e = 0; e < 4; ++e) sg[e] = 1.f/(1.f + expf(-p[e]));
        *(f32x4*)&Z[((size_t)b*NN + hoff + n)*256 + j] = sg;
      } else {
        int f = j - 256;
        f32x4 h = *(const f32x4*)&Hin[((size_t)b*NN + hoff + n)*256 + f];
        union { uint2 qq; ushort_t u[4]; } hi, lo;
#pragma unroll
        for (int e = 0; e < 4; ++e) {
          float gh = h[e]/(1.f + expf(-p[e]));
          ushort_t hb = f2bf(gh);
          hi.u[e] = hb; lo.u[e] = f2bf(gh - bf2f(hb));
        }
        ushort_t* op = Out + (size_t)(b*N + n)*512 + f;
        *(uint2*)op = hi.qq;
        *(uint2*)(op + 256) = lo.qq;
      }
    } else {
      size_t hidx = ((size_t)b*NN + hoff + n)*256 + j;
      f32x4 zv = *(const f32x4*)&Z[hidx];
      f32x4 hv = *(const f32x4*)&Hin[hidx];
      f32x4 hn;
      union { uint2 qq; ushort_t u[4]; } hi, lo;
#pragma unroll
      for (int e = 0; e < 4; ++e) {
        float ht = tanhf(p[e]);
        hn[e] = zv[e]*hv[e] + (1.f - zv[e])*ht;
        ushort_t hb = f2bf(hn[e]);
        hi.u[e] = hb; lo.u[e] = f2bf(hn[e] - bf2f(hb));
      }
      *(f32x4*)&Hout[hidx] = hn;
      ushort_t* op = Out + (size_t)(b*N + n)*512 + j;
      *(uint2*)op = hi.qq;
      *(uint2*)(op + 256) = lo.qq;
    }
  }
}

// ---------------- readout ----------------
__global__ __launch_bounds__(256) void readout_k(const float* __restrict__ H, const float* __restrict__ W_ro,
                                                 const float* __restrict__ b_ro, const float* __restrict__ W_ag,
                                                 const float* __restrict__ b_ag, float* __restrict__ out) {
  __shared__ float red[256];
  __shared__ float o1[NN];
  int b = blockIdx.x, tid = threadIdx.x;
  float wro = W_ro[tid];
  for (int n = 0; n < NN; ++n) {
    red[tid] = H[((size_t)b*NN + n)*256 + tid] * wro;
    __syncthreads();
    for (int s = 128; s > 0; s >>= 1) { if (tid < s) red[tid] += red[tid+s]; __syncthreads(); }
    if (tid == 0) o1[n] = red[0] + b_ro[0];
    __syncthreads();
  }
  if (tid < 5) {
    float s = b_ag[tid];
    for (int n = 0; n < NN; ++n) s += o1[n] * W_ag[n*5 + tid];
    out[b*5 + tid] = s;
  }
}

// ---------------- host ----------------
extern "C" void kernel_launch(void* const* d_in, const int* in_sizes, int n_in,
                              void* d_out, int out_size, void* d_ws, size_t ws_size,
                              hipStream_t stream) {
  const float* xdis = (const float*)d_in[0];
  const float* xpre = (const float*)d_in[1];
  const int*   ei_s = (const int*)d_in[2];
  const int*   ei_p = (const int*)d_in[3];
  const float* ew_s = (const float*)d_in[4];
  const float* ew_p = (const float*)d_in[5];
  const float* Wz_s = (const float*)d_in[6];
  const float* bz_s = (const float*)d_in[7];
  const float* Wr_s = (const float*)d_in[8];
  const float* br_s = (const float*)d_in[9];
  const float* Wh_s = (const float*)d_in[10];
  const float* bh_s = (const float*)d_in[11];
  const float* Wz_p = (const float*)d_in[12];
  const float* bz_p = (const float*)d_in[13];
  const float* Wr_p = (const float*)d_in[14];
  const float* br_p = (const float*)d_in[15];
  const float* Wh_p = (const float*)d_in[16];
  const float* bh_p = (const float*)d_in[17];
  const float* W_ro = (const float*)d_in[18];
  const float* b_ro = (const float*)d_in[19];
  const float* W_ag = (const float*)d_in[20];
  const float* b_ag = (const float*)d_in[21];
  float* out = (float*)d_out;
  (void)in_sizes; (void)n_in; (void)out_size; (void)ws_size;

  char* w = (char*)d_ws;
  size_t off = 0;
  auto alloc = [&](size_t bytes) { void* p = w + off; off = (off + bytes + 255) & ~(size_t)255; return p; };

  const size_t plWXs = (size_t)768*KHS, plWXp = (size_t)768*KHP;
  const size_t rowsXs = (size_t)TCH*NB*NSN, rowsXp = (size_t)TCH*NB*NPN;
  const size_t plXs_pre = rowsXs*KHS, plXp_pre = rowsXp*KHP;

  float* Ms_s = (float*)alloc(4*NSN*NSN*sizeof(float));
  float* Ms_p = (float*)alloc(2*NPN*NPN*sizeof(float));
  float* Mbig_s = (float*)alloc(NSN*100*sizeof(float));
  float* Mbig_p = (float*)alloc(NPN*24*sizeof(float));
  ushort_t* WX_s = (ushort_t*)alloc(plWXs*2);          // hi only
  ushort_t* WX_p = (ushort_t*)alloc(plWXp*2);
  ushort_t* WHzr_s = (ushort_t*)alloc((size_t)2560*512*2);
  ushort_t* WHh_s  = (ushort_t*)alloc((size_t)1280*512*2);
  ushort_t* WHzr_p = (ushort_t*)alloc((size_t)1536*512*2);
  ushort_t* WHh_p  = (ushort_t*)alloc((size_t)768*512*2);
  ushort_t* XT_s = (ushort_t*)alloc(plXs_pre*2*2);
  ushort_t* XT_p = (ushort_t*)alloc(plXp_pre*2*2);
  ushort_t* Px_s = (ushort_t*)alloc((size_t)TT*NB*NSN*NPRE*2);
  ushort_t* Px_p = (ushort_t*)alloc((size_t)TT*NB*NPN*NPRE*2);
  ushort_t* Yzr_s = (ushort_t*)alloc((size_t)NB*NSN*2560*2);
  ushort_t* Yzr_p = (ushort_t*)alloc((size_t)NB*NPN*1536*2);
  float* H  = (float*)alloc((size_t)NB*NN*256*4);
  float* Z  = (float*)alloc((size_t)NB*NN*256*4);
  ushort_t* Hhl_s  = (ushort_t*)alloc((size_t)NB*NSN*512*2);
  ushort_t* Hhl_p  = (ushort_t*)alloc((size_t)NB*NPN*512*2);
  ushort_t* gHhl_s = (ushort_t*)alloc((size_t)NB*NSN*512*2);
  ushort_t* gHhl_p = (ushort_t*)alloc((size_t)NB*NPN*512*2);

  graph_build<<<1, 64, 0, stream>>>(ei_s, ew_s, ei_p, ew_p, Ms_s, Ms_p, Mbig_s, Mbig_p);
  prep_w<<<1024, 256, 0, stream>>>(Wz_s, Wr_s, Wh_s, Wz_p, Wr_p, Wh_p,
                                   WX_s, WX_p, WHzr_s, WHh_s, WHzr_p, WHh_p);
  const long nH = (long)NB*NN*256;
  zero_f<<<(nH + 255)/256, 256, 0, stream>>>(H, nH);
  const long nHhl = ((long)NB*NSN*512 + (long)NB*NPN*512) / 2;
  zero_f<<<(nHhl + 255)/256, 256, 0, stream>>>((float*)Hhl_s, nHhl);

  // ---- precompute Px ----
  for (int t0 = 0; t0 < TT; t0 += TCH) {
    chebx<<<2*NB*TCH, 256, 0, stream>>>(xdis, xpre, Ms_s, Ms_p, XT_s, XT_p, plXs_pre, plXp_pre, t0);
    gemm_pre<<<224*6, 512, 0, stream>>>(
        XT_s, WX_s, KHS, plXs_pre, 160, 6,
        XT_p, WX_p, KHP, plXp_pre,
        Px_s + (size_t)t0*NB*NSN*NPRE, Px_p + (size_t)t0*NB*NPN*NPRE,
        bz_s, br_s, bh_s, bz_p, br_p, bh_p);
  }

  // ---- recurrence ----
  for (int t = 0; t < TT; ++t) {
    const ushort_t* PxS = Px_s + (size_t)t*NB*NSN*NPRE;
    const ushort_t* PxP = Px_p + (size_t)t*NB*NPN*NPRE;
    gemm_y<<<800 + 192, 512, 0, stream>>>(Hhl_s, WHzr_s, Yzr_s, 2560, 20, 800,
                                          Hhl_p, WHzr_p, Yzr_p, 1536, 12);
    contract_k<0><<<NB*4*2, 256, 0, stream>>>(Yzr_s, Yzr_p, PxS, PxP, Mbig_s, Mbig_p,
                                              H, Z, gHhl_s, gHhl_p, nullptr);
    gemm_y<<<400 + 96, 512, 0, stream>>>(gHhl_s, WHh_s, Yzr_s, 1280, 10, 400,
                                         gHhl_p, WHh_p, Yzr_p, 768, 6);
    contract_k<1><<<NB*2*2, 256, 0, stream>>>(Yzr_s, Yzr_p, PxS, PxP, Mbig_s, Mbig_p,
                                              H, Z, Hhl_s, Hhl_p, H);
  }
  readout_k<<<NB, 256, 0, stream>>>(H, W_ro, b_ro, W_ag, b_ag, out);
}

// Round 8
// 1692.758 us; speedup vs baseline: 6.5097x; 1.2807x over previous
//
#include <hip/hip_runtime.h>
#include <stdint.h>

#define NSN 20
#define NPN 8
#define NB 128
#define TT 24
#define NN 28
#define ES 100
#define EP 32
#define KHS 1280   // 5*256 (precompute K)
#define KHP 768    // 3*256
#define NPRE 768   // z|r|h output cols
#define TCH 4      // precompute time-chunk

typedef _Float16 half_t;
typedef __attribute__((ext_vector_type(8))) _Float16 f16x8;
typedef __attribute__((ext_vector_type(4))) float f32x4;

__device__ __forceinline__ void gl16(const half_t* g, half_t* l) {
  __builtin_amdgcn_global_load_lds((const __attribute__((address_space(1))) void*)g,
                                   (__attribute__((address_space(3))) void*)l, 16, 0, 0);
}

// ---------------- graph build ----------------
__global__ void graph_build(const int* __restrict__ ei_s, const float* __restrict__ ew_s,
                            const int* __restrict__ ei_p, const float* __restrict__ ew_p,
                            float* __restrict__ Ms_s, float* __restrict__ Ms_p,
                            float* __restrict__ Mbig_s, float* __restrict__ Mbig_p) {
  __shared__ float Ao[NSN*NSN], Aiw[NSN*NSN], dgo[NSN], dgi[NSN];
  __shared__ float T2o[NSN*NSN], T2i[NSN*NSN];
  __shared__ float Aop[NPN*NPN], Aip[NPN*NPN], dgop[NPN], dgip[NPN];
  int tid = threadIdx.x;
  for (int i = tid; i < NSN*NSN; i += blockDim.x) { Ao[i] = 0.f; Aiw[i] = 0.f; }
  for (int i = tid; i < NPN*NPN; i += blockDim.x) { Aop[i] = 0.f; Aip[i] = 0.f; }
  if (tid < NSN) { dgo[tid] = 0.f; dgi[tid] = 0.f; }
  if (tid < NPN) { dgop[tid] = 0.f; dgip[tid] = 0.f; }
  __syncthreads();
  if (tid == 0) {
    for (int e = 0; e < ES; ++e) { int r = ei_s[e], c = ei_s[ES+e]; float w = ew_s[e]; dgo[r] += w; dgi[c] += w; }
    for (int e = 0; e < ES; ++e) { int r = ei_s[e], c = ei_s[ES+e]; Ao[c*NSN+r] += 1.f/dgo[r]; Aiw[c*NSN+r] += 1.f/dgi[r]; }
  }
  if (tid == 1) {
    for (int e = 0; e < EP; ++e) { int r = ei_p[e], c = ei_p[EP+e]; float w = ew_p[e]; dgop[r] += w; dgip[c] += w; }
    for (int e = 0; e < EP; ++e) { int r = ei_p[e], c = ei_p[EP+e]; Aop[c*NPN+r] += 1.f/dgop[r]; Aip[c*NPN+r] += 1.f/dgip[r]; }
  }
  __syncthreads();
  for (int i = tid; i < NSN*NSN; i += blockDim.x) {
    int r = i / NSN, c = i % NSN;
    float so = 0.f, si = 0.f;
    for (int k = 0; k < NSN; ++k) { so += Ao[r*NSN+k]*Ao[k*NSN+c]; si += Aiw[r*NSN+k]*Aiw[k*NSN+c]; }
    float t2o = 2.f*so - (r==c ? 1.f : 0.f);
    float t2i = 2.f*si - (r==c ? 1.f : 0.f);
    T2o[i] = t2o; T2i[i] = t2i;
    Ms_s[0*NSN*NSN + i] = Ao[i];
    Ms_s[1*NSN*NSN + i] = Aiw[i];
    Ms_s[2*NSN*NSN + i] = t2o;
    Ms_s[3*NSN*NSN + i] = t2i;
  }
  for (int i = tid; i < NPN*NPN; i += blockDim.x) {
    Ms_p[0*NPN*NPN + i] = Aop[i];
    Ms_p[1*NPN*NPN + i] = Aip[i];
  }
  __syncthreads();
  for (int i = tid; i < NSN*NSN*5; i += blockDim.x) {
    int n = i / 100, s = i % 100, r = s / 5, tau = s % 5;
    float v;
    if (tau == 0) v = (n == r) ? 1.f : 0.f;
    else if (tau == 1) v = Ao[n*NSN + r];
    else if (tau == 2) v = Aiw[n*NSN + r];
    else if (tau == 3) v = T2o[n*NSN + r];
    else               v = T2i[n*NSN + r];
    Mbig_s[i] = v;
  }
  for (int i = tid; i < NPN*NPN*3; i += blockDim.x) {
    int n = i / 24, s = i % 24, r = s / 3, tau = s % 3;
    float v;
    if (tau == 0) v = (n == r) ? 1.f : 0.f;
    else if (tau == 1) v = Aop[n*NPN + r];
    else               v = Aip[n*NPN + r];
    Mbig_p[i] = v;
  }
}

// ---------------- weight prep (all single-plane fp16) ----------------
__device__ __forceinline__ float wsrc(const float* W, int Kdim, int tau, int i, int jj) {
  if (tau == 0) return W[(size_t)(0*Kdim+0)*512*256 + (size_t)i*256 + jj]
                     + W[(size_t)(1*Kdim+0)*512*256 + (size_t)i*256 + jj];
  int dir = (tau - 1) & 1;
  int k = (tau + 1) >> 1;
  return W[(size_t)(dir*Kdim + k)*512*256 + (size_t)i*256 + jj];
}

__global__ void prep_w(const float* __restrict__ Wz_s, const float* __restrict__ Wr_s, const float* __restrict__ Wh_s,
                       const float* __restrict__ Wz_p, const float* __restrict__ Wr_p, const float* __restrict__ Wh_p,
                       half_t* __restrict__ WX_s, half_t* __restrict__ WX_p,
                       half_t* __restrict__ WHzr_s, half_t* __restrict__ WHh_s,
                       half_t* __restrict__ WHzr_p, half_t* __restrict__ WHh_p) {
  const long c0 = (long)768*KHS;
  const long c1 = c0 + (long)768*KHP;
  const long c2 = c1 + (long)2560*256;
  const long c3 = c2 + (long)1280*256;
  const long c4 = c3 + (long)1536*256;
  const long c5 = c4 + (long)768*256;
  for (long idx = (long)blockIdx.x*256 + threadIdx.x; idx < c5; idx += (long)gridDim.x*256) {
    if (idx < c0) {
      long x = idx; int j = (int)(x / KHS), c = (int)(x % KHS); int tau = c >> 8;
      const float* W = (j < 256) ? Wz_s : (j < 512) ? Wr_s : Wh_s;
      WX_s[x] = (half_t)wsrc(W, 3, tau, c & 255, j & 255);
    } else if (idx < c1) {
      long x = idx - c0; int j = (int)(x / KHP), c = (int)(x % KHP); int tau = c >> 8;
      const float* W = (j < 256) ? Wz_p : (j < 512) ? Wr_p : Wh_p;
      WX_p[x] = (half_t)wsrc(W, 2, tau, c & 255, j & 255);
    } else if (idx < c2) {
      long x = idx - c1; int cc = (int)(x >> 8), f = (int)(x & 255);
      int tau = cc / 512, j = cc % 512;
      const float* W = (j < 256) ? Wz_s : Wr_s;
      WHzr_s[(size_t)cc*256 + f] = (half_t)wsrc(W, 3, tau, 256 + f, j & 255);
    } else if (idx < c3) {
      long x = idx - c2; int cc = (int)(x >> 8), f = (int)(x & 255);
      int tau = cc >> 8, j = cc & 255;
      WHh_s[(size_t)cc*256 + f] = (half_t)wsrc(Wh_s, 3, tau, 256 + f, j);
    } else if (idx < c4) {
      long x = idx - c3; int cc = (int)(x >> 8), f = (int)(x & 255);
      int tau = cc / 512, j = cc % 512;
      const float* W = (j < 256) ? Wz_p : Wr_p;
      WHzr_p[(size_t)cc*256 + f] = (half_t)wsrc(W, 2, tau, 256 + f, j & 255);
    } else {
      long x = idx - c4; int cc = (int)(x >> 8), f = (int)(x & 255);
      int tau = cc >> 8, j = cc & 255;
      WHh_p[(size_t)cc*256 + f] = (half_t)wsrc(Wh_p, 2, tau, 256 + f, j);
    }
  }
}

__global__ void zero_f(float* p, long n) {
  long i = (long)blockIdx.x*256 + threadIdx.x;
  if (i < n) p[i] = 0.f;
}

// ---------------- cheb expansion of X (precompute A), fp16 single plane ----------------
__global__ __launch_bounds__(256) void chebx(const float* __restrict__ xdis, const float* __restrict__ xpre,
                                             const float* __restrict__ Ms_s, const float* __restrict__ Ms_p,
                                             half_t* __restrict__ XTs, half_t* __restrict__ XTp, int t0) {
  __shared__ float Xc[NSN*256];
  __shared__ float Ml[4*NSN*NSN];
  int bb = blockIdx.x, tid = threadIdx.x;
  bool isP = bb >= NB*TCH;
  int q = isP ? bb - NB*TCH : bb;
  int b = q % NB, tp = q / NB;
  int N = isP ? NPN : NSN, nt = isP ? 3 : 5, KX = nt << 8;
  const float* X = isP ? (xpre + (size_t)(b*TT + t0 + tp)*NPN*256)
                       : (xdis + (size_t)(b*TT + t0 + tp)*NSN*256);
  for (int i = tid; i < N*64; i += 256) ((float4*)Xc)[i] = ((const float4*)X)[i];
  int nm = (nt-1)*N*N;
  const float* Msrc = isP ? Ms_p : Ms_s;
  for (int i = tid; i < nm; i += 256) Ml[i] = Msrc[i];
  __syncthreads();
  half_t* XT = isP ? XTp : XTs;
  size_t rowbase = (size_t)(tp*NB + b)*N;
  int kc8 = KX >> 3, nch = N * kc8;
  for (int i = tid; i < nch; i += 256) {
    int n = i / kc8, c8 = i - n*kc8;
    int tau = c8 >> 5, f0 = (c8 & 31) << 3;
    float v[8];
    if (tau == 0) {
      const float* xr0 = Xc + n*256 + f0;
#pragma unroll
      for (int j = 0; j < 8; ++j) v[j] = xr0[j];
    } else {
      const float* M = Ml + (tau-1)*N*N + n*N;
#pragma unroll
      for (int j = 0; j < 8; ++j) v[j] = 0.f;
      for (int r = 0; r < N; ++r) {
        float m = M[r];
        const float* xr = Xc + r*256 + f0;
#pragma unroll
        for (int j = 0; j < 8; ++j) v[j] += m*xr[j];
      }
    }
    union { uint4 q; half_t u[8]; } hv;
#pragma unroll
    for (int j = 0; j < 8; ++j) hv.u[j] = (half_t)v[j];
    *(uint4*)(XT + (rowbase + n)*(size_t)KX + ((size_t)c8 << 3)) = hv.q;
  }
}

// ---------------- precompute GEMM: fp16 1-term, 64x128 tile, BK=64, ring-3 72KB ----------------
__global__ __launch_bounds__(512) void gemm_pre(
    const half_t* __restrict__ A0, const half_t* __restrict__ B0, int K0,
    int rbS, int cbTot,
    const half_t* __restrict__ A1, const half_t* __restrict__ B1, int K1,
    half_t* __restrict__ Px0, half_t* __restrict__ Px1,
    const float* __restrict__ bz0, const float* __restrict__ br0, const float* __restrict__ bh0,
    const float* __restrict__ bz1, const float* __restrict__ br1, const float* __restrict__ bh1) {
  __shared__ __align__(16) half_t sbuf[3][12288];   // per buf: A 64x64 | B 128x64
  int id = blockIdx.x;
  int xx = id & 7, kq = id >> 3;
  int rbTot8 = (gridDim.x / cbTot) >> 3;
  int rb = xx*rbTot8 + kq / cbTot;
  int cb = kq - (kq / cbTot)*cbTot;

  bool isP = rb >= rbS;
  const half_t* A = isP ? A1 : A0;
  const half_t* B = isP ? B1 : B0;
  int K = isP ? K1 : K0;
  int row0 = (isP ? rb - rbS : rb) * 64;
  int col0 = cb * 128;
  int tid = threadIdx.x, lane = tid & 63, w = tid >> 6;
  int l15 = lane & 15, l4 = lane >> 4;
  int wr = (w >> 2) * 32, wc = (w & 3) * 32;

  const half_t* srcb[3];
  int ldso[3];
#pragma unroll
  for (int j = 0; j < 3; ++j) {
    int c = ((j*8 + w) << 6) + lane;     // 0..1535 chunks of 16B
    const half_t* base;
    if (c < 512) {                        // A: 64 rows x 8 kchunks
      int r = c >> 3, kb = c & 7;
      base = A + (size_t)(row0 + r)*K + ((kb ^ (r & 7)) << 3);
    } else {                              // B: 128 rows x 8
      int d = c - 512, r = d >> 3, kb = d & 7;
      base = B + (size_t)(col0 + r)*K + ((kb ^ (r & 7)) << 3);
    }
    srcb[j] = base;
    ldso[j] = c << 3;
  }

  f32x4 acc[2][2];
#pragma unroll
  for (int i = 0; i < 2; ++i)
#pragma unroll
    for (int j = 0; j < 2; ++j) acc[i][j] = (f32x4){0.f,0.f,0.f,0.f};

  int nk = K >> 6;
#define STAGEP(K0E, BUFP)  { half_t* _b = (BUFP); _Pragma("unroll") \
    for (int j = 0; j < 3; ++j) gl16(srcb[j] + (K0E), _b + ldso[j]); }

  STAGEP(0,   &sbuf[0][0]);
  STAGEP(64,  &sbuf[1][0]);
  STAGEP(128, &sbuf[2][0]);

  for (int k = 0; k < nk; ++k) {
    int rem = nk - 1 - k;
    if (rem >= 2)      asm volatile("s_waitcnt vmcnt(6)" ::: "memory");
    else if (rem == 1) asm volatile("s_waitcnt vmcnt(3)" ::: "memory");
    else               asm volatile("s_waitcnt vmcnt(0)" ::: "memory");
    __builtin_amdgcn_s_barrier();
    const half_t* cur = &sbuf[k % 3][0];
    const half_t* cB = cur + 4096;
#pragma unroll
    for (int kk = 0; kk < 2; ++kk) {
      f16x8 af[2], bq[2];
#pragma unroll
      for (int mi = 0; mi < 2; ++mi) {
        int r = wr + mi*16 + l15;
        int sb = (kk*4 + l4) ^ (r & 7);
        af[mi] = *(const f16x8*)&cur[r*64 + sb*8];
      }
#pragma unroll
      for (int ni = 0; ni < 2; ++ni) {
        int r = wc + ni*16 + l15;
        int sb = (kk*4 + l4) ^ (r & 7);
        bq[ni] = *(const f16x8*)&cB[r*64 + sb*8];
      }
#pragma unroll
      for (int mi = 0; mi < 2; ++mi)
#pragma unroll
        for (int ni = 0; ni < 2; ++ni)
          acc[mi][ni] = __builtin_amdgcn_mfma_f32_16x16x32_f16(af[mi], bq[ni], acc[mi][ni], 0, 0, 0);
    }
    __builtin_amdgcn_s_barrier();
    if (k + 3 < nk) STAGEP((k + 3) << 6, &sbuf[k % 3][0]);
  }
#undef STAGEP

  half_t* PxO = isP ? Px1 : Px0;
#pragma unroll
  for (int mi = 0; mi < 2; ++mi)
#pragma unroll
    for (int ni = 0; ni < 2; ++ni) {
      int colg = col0 + wc + ni*16 + l15;
      const float* bias = (colg < 256) ? (isP ? bz1 : bz0)
                        : (colg < 512) ? (isP ? br1 : br0)
                                       : (isP ? bh1 : bh0);
#pragma unroll
      for (int rg = 0; rg < 4; ++rg) {
        int grow = row0 + wr + mi*16 + l4*4 + rg;
        PxO[(size_t)grow*NPRE + colg] = (half_t)(acc[mi][ni][rg] + bias[colg & 255]);
      }
    }
}

// ---------------- recurrence GEMM: Y(f16) = Hf @ WH^T, K=256, BK=64, ring-3 36KB ----------------
__global__ __launch_bounds__(512) void gemm_y(
    const half_t* __restrict__ A0, const half_t* __restrict__ B0, half_t* __restrict__ C0, int NC0, int cb0, int nb0,
    const half_t* __restrict__ A1, const half_t* __restrict__ B1, half_t* __restrict__ C1, int NC1, int cb1) {
  __shared__ __align__(16) half_t sbuf[3][12288];
  int id = blockIdx.x;
  int rb, cb; const half_t *A, *B; half_t* C; int NC;
  if (id < nb0) { rb = id / cb0; cb = id % cb0; A = A0; B = B0; C = C0; NC = NC0; }
  else { int q = id - nb0; rb = q / cb1; cb = q % cb1; A = A1; B = B1; C = C1; NC = NC1; }
  int row0 = rb*64, col0 = cb*128;
  int tid = threadIdx.x, lane = tid & 63, w = tid >> 6;
  int l15 = lane & 15, l4 = lane >> 4;
  int wr = (w >> 2) * 32, wc = (w & 3) * 32;

  const half_t* srcb[3];
  int ldso[3];
#pragma unroll
  for (int j = 0; j < 3; ++j) {
    int c = ((j*8 + w) << 6) + lane;
    const half_t* base;
    if (c < 512) {
      int r = c >> 3, kb = c & 7;
      base = A + (size_t)(row0 + r)*256 + ((kb ^ (r & 7)) << 3);
    } else {
      int d = c - 512, r = d >> 3, kb = d & 7;
      base = B + (size_t)(col0 + r)*256 + ((kb ^ (r & 7)) << 3);
    }
    srcb[j] = base;
    ldso[j] = c << 3;
  }

  f32x4 acc[2][2];
#pragma unroll
  for (int i = 0; i < 2; ++i)
#pragma unroll
    for (int j = 0; j < 2; ++j) acc[i][j] = (f32x4){0.f,0.f,0.f,0.f};

#define STAGEY(K0E, BUFP)  { half_t* _b = (BUFP); _Pragma("unroll") \
    for (int j = 0; j < 3; ++j) gl16(srcb[j] + (K0E), _b + ldso[j]); }

  STAGEY(0,   &sbuf[0][0]);
  STAGEY(64,  &sbuf[1][0]);
  STAGEY(128, &sbuf[2][0]);

  for (int k = 0; k < 4; ++k) {
    int rem = 3 - k;
    if (rem >= 2)      asm volatile("s_waitcnt vmcnt(6)" ::: "memory");
    else if (rem == 1) asm volatile("s_waitcnt vmcnt(3)" ::: "memory");
    else               asm volatile("s_waitcnt vmcnt(0)" ::: "memory");
    __builtin_amdgcn_s_barrier();
    const half_t* cur = &sbuf[k % 3][0];
    const half_t* cB = cur + 4096;
#pragma unroll
    for (int kk = 0; kk < 2; ++kk) {
      f16x8 af[2], bq[2];
#pragma unroll
      for (int mi = 0; mi < 2; ++mi) {
        int r = wr + mi*16 + l15;
        int sb = (kk*4 + l4) ^ (r & 7);
        af[mi] = *(const f16x8*)&cur[r*64 + sb*8];
      }
#pragma unroll
      for (int ni = 0; ni < 2; ++ni) {
        int r = wc + ni*16 + l15;
        int sb = (kk*4 + l4) ^ (r & 7);
        bq[ni] = *(const f16x8*)&cB[r*64 + sb*8];
      }
#pragma unroll
      for (int mi = 0; mi < 2; ++mi)
#pragma unroll
        for (int ni = 0; ni < 2; ++ni)
          acc[mi][ni] = __builtin_amdgcn_mfma_f32_16x16x32_f16(af[mi], bq[ni], acc[mi][ni], 0, 0, 0);
    }
    __builtin_amdgcn_s_barrier();
    if (k + 3 < 4) STAGEY((k + 3) << 6, &sbuf[k % 3][0]);
  }
#undef STAGEY

#pragma unroll
  for (int mi = 0; mi < 2; ++mi)
#pragma unroll
    for (int ni = 0; ni < 2; ++ni) {
      int colg = col0 + wc + ni*16 + l15;
#pragma unroll
      for (int rg = 0; rg < 4; ++rg) {
        int grow = row0 + wr + mi*16 + l4*4 + rg;
        C[(size_t)grow*NC + colg] = (half_t)acc[mi][ni][rg];
      }
    }
}

// ---------------- node contraction + GRU epilogues ----------------
// GATE 0: P = Mbig@Y + Px(z|r); j<256: Z=sig(P); else gHf=f16(sig(P)*H)
// GATE 1: P = Mbig@Y + Px(h); H = Z*H + (1-Z)*tanh(P); write H fp32 + Hf f16
template<int GATE>
__global__ __launch_bounds__(256) void contract_k(
    const half_t* __restrict__ Ys, const half_t* __restrict__ Yp,
    const half_t* __restrict__ Px_s, const half_t* __restrict__ Px_p,
    const float* __restrict__ Mb_s, const float* __restrict__ Mb_p,
    const float* __restrict__ Hin, float* __restrict__ Z,
    half_t* __restrict__ Out_s, half_t* __restrict__ Out_p,
    float* __restrict__ Hout) {
  constexpr int JB = GATE ? 2 : 4;
  constexpr int JW = GATE ? 256 : 512;
  __shared__ float Yl[100*128];
  __shared__ float Mb[NSN*100];
  int id = blockIdx.x, tid = threadIdx.x;
  bool isP = id >= NB*JB;
  int q = isP ? id - NB*JB : id;
  int b = q / JB, jb = q % JB;
  int N = isP ? NPN : NSN, ntau = isP ? 3 : 5;
  int nseg = N * ntau;
  int NC = ntau * JW;
  const half_t* Y = isP ? Yp : Ys;
  const float* Mbg = isP ? Mb_p : Mb_s;
  int tot8 = nseg << 4;
  for (int i = tid; i < tot8; i += 256) {
    int seg = i >> 4, q8 = i & 15;
    int r = seg / ntau, tau = seg - r*ntau;
    union { uint4 qq; half_t u[8]; } uu;
    uu.qq = *(const uint4*)&Y[(size_t)(b*N + r)*NC + tau*JW + jb*128 + (q8 << 3)];
    float* dst = Yl + (seg << 7) + (q8 << 3);
#pragma unroll
    for (int e = 0; e < 8; ++e) dst[e] = (float)uu.u[e];
  }
  for (int i = tid; i < N*nseg; i += 256) Mb[i] = Mbg[i];
  __syncthreads();
  f32x4* Yl4 = (f32x4*)Yl;
  const half_t* Px = isP ? Px_p : Px_s;
  half_t* Out = isP ? Out_p : Out_s;
  int hoff = isP ? NSN : 0;
  int nout4 = N << 5;
  for (int o = tid; o < nout4; o += 256) {
    int n = o >> 5, j4 = o & 31;
    int j = jb*128 + (j4 << 2);
    f32x4 p = (f32x4){0.f,0.f,0.f,0.f};
    const float* mrow = Mb + n*nseg;
    for (int s = 0; s < nseg; ++s) {
      float m = mrow[s];
      f32x4 y = Yl4[(s << 5) + j4];
      p += m*y;
    }
    union { uint2 qq; half_t u[4]; } pu;
    pu.qq = *(const uint2*)&Px[(size_t)(b*N + n)*NPRE + (GATE ? 512 : 0) + j];
#pragma unroll
    for (int e = 0; e < 4; ++e) p[e] += (float)pu.u[e];
    if constexpr (GATE == 0) {
      if (j < 256) {
        f32x4 sg;
#pragma unroll
        for (int e = 0; e < 4; ++e) sg[e] = 1.f/(1.f + expf(-p[e]));
        *(f32x4*)&Z[((size_t)b*NN + hoff + n)*256 + j] = sg;
      } else {
        int f = j - 256;
        f32x4 h = *(const f32x4*)&Hin[((size_t)b*NN + hoff + n)*256 + f];
        union { uint2 qq; half_t u[4]; } ho;
#pragma unroll
        for (int e = 0; e < 4; ++e) ho.u[e] = (half_t)(h[e]/(1.f + expf(-p[e])));
        *(uint2*)(Out + (size_t)(b*N + n)*256 + f) = ho.qq;
      }
    } else {
      size_t hidx = ((size_t)b*NN + hoff + n)*256 + j;
      f32x4 zv = *(const f32x4*)&Z[hidx];
      f32x4 hv = *(const f32x4*)&Hin[hidx];
      f32x4 hn;
      union { uint2 qq; half_t u[4]; } ho;
#pragma unroll
      for (int e = 0; e < 4; ++e) {
        float ht = tanhf(p[e]);
        hn[e] = zv[e]*hv[e] + (1.f - zv[e])*ht;
        ho.u[e] = (half_t)hn[e];
      }
      *(f32x4*)&Hout[hidx] = hn;
      *(uint2*)(Out + (size_t)(b*N + n)*256 + j) = ho.qq;
    }
  }
}

// ---------------- readout ----------------
__global__ __launch_bounds__(256) void readout_k(const float* __restrict__ H, const float* __restrict__ W_ro,
                                                 const float* __restrict__ b_ro, const float* __restrict__ W_ag,
                                                 const float* __restrict__ b_ag, float* __restrict__ out) {
  __shared__ float red[256];
  __shared__ float o1[NN];
  int b = blockIdx.x, tid = threadIdx.x;
  float wro = W_ro[tid];
  for (int n = 0; n < NN; ++n) {
    red[tid] = H[((size_t)b*NN + n)*256 + tid] * wro;
    __syncthreads();
    for (int s = 128; s > 0; s >>= 1) { if (tid < s) red[tid] += red[tid+s]; __syncthreads(); }
    if (tid == 0) o1[n] = red[0] + b_ro[0];
    __syncthreads();
  }
  if (tid < 5) {
    float s = b_ag[tid];
    for (int n = 0; n < NN; ++n) s += o1[n] * W_ag[n*5 + tid];
    out[b*5 + tid] = s;
  }
}

// ---------------- host ----------------
extern "C" void kernel_launch(void* const* d_in, const int* in_sizes, int n_in,
                              void* d_out, int out_size, void* d_ws, size_t ws_size,
                              hipStream_t stream) {
  const float* xdis = (const float*)d_in[0];
  const float* xpre = (const float*)d_in[1];
  const int*   ei_s = (const int*)d_in[2];
  const int*   ei_p = (const int*)d_in[3];
  const float* ew_s = (const float*)d_in[4];
  const float* ew_p = (const float*)d_in[5];
  const float* Wz_s = (const float*)d_in[6];
  const float* bz_s = (const float*)d_in[7];
  const float* Wr_s = (const float*)d_in[8];
  const float* br_s = (const float*)d_in[9];
  const float* Wh_s = (const float*)d_in[10];
  const float* bh_s = (const float*)d_in[11];
  const float* Wz_p = (const float*)d_in[12];
  const float* bz_p = (const float*)d_in[13];
  const float* Wr_p = (const float*)d_in[14];
  const float* br_p = (const float*)d_in[15];
  const float* Wh_p = (const float*)d_in[16];
  const float* bh_p = (const float*)d_in[17];
  const float* W_ro = (const float*)d_in[18];
  const float* b_ro = (const float*)d_in[19];
  const float* W_ag = (const float*)d_in[20];
  const float* b_ag = (const float*)d_in[21];
  float* out = (float*)d_out;
  (void)in_sizes; (void)n_in; (void)out_size; (void)ws_size;

  char* w = (char*)d_ws;
  size_t off = 0;
  auto alloc = [&](size_t bytes) { void* p = w + off; off = (off + bytes + 255) & ~(size_t)255; return p; };

  const size_t rowsXs = (size_t)TCH*NB*NSN, rowsXp = (size_t)TCH*NB*NPN;

  float* Ms_s = (float*)alloc(4*NSN*NSN*sizeof(float));
  float* Ms_p = (float*)alloc(2*NPN*NPN*sizeof(float));
  float* Mbig_s = (float*)alloc(NSN*100*sizeof(float));
  float* Mbig_p = (float*)alloc(NPN*24*sizeof(float));
  half_t* WX_s = (half_t*)alloc((size_t)768*KHS*2);
  half_t* WX_p = (half_t*)alloc((size_t)768*KHP*2);
  half_t* WHzr_s = (half_t*)alloc((size_t)2560*256*2);
  half_t* WHh_s  = (half_t*)alloc((size_t)1280*256*2);
  half_t* WHzr_p = (half_t*)alloc((size_t)1536*256*2);
  half_t* WHh_p  = (half_t*)alloc((size_t)768*256*2);
  half_t* XT_s = (half_t*)alloc(rowsXs*KHS*2);
  half_t* XT_p = (half_t*)alloc(rowsXp*KHP*2);
  half_t* Px_s = (half_t*)alloc((size_t)TT*NB*NSN*NPRE*2);
  half_t* Px_p = (half_t*)alloc((size_t)TT*NB*NPN*NPRE*2);
  half_t* Y_s = (half_t*)alloc((size_t)NB*NSN*2560*2);
  half_t* Y_p = (half_t*)alloc((size_t)NB*NPN*1536*2);
  float* H  = (float*)alloc((size_t)NB*NN*256*4);
  float* Z  = (float*)alloc((size_t)NB*NN*256*4);
  half_t* Hf  = (half_t*)alloc((size_t)NB*NN*256*2);   // S part then P part
  half_t* gHf = (half_t*)alloc((size_t)NB*NN*256*2);
  half_t* Hf_s = Hf,  * Hf_p = Hf + (size_t)NB*NSN*256;
  half_t* gHf_s = gHf, * gHf_p = gHf + (size_t)NB*NSN*256;

  graph_build<<<1, 64, 0, stream>>>(ei_s, ew_s, ei_p, ew_p, Ms_s, Ms_p, Mbig_s, Mbig_p);
  prep_w<<<1024, 256, 0, stream>>>(Wz_s, Wr_s, Wh_s, Wz_p, Wr_p, Wh_p,
                                   WX_s, WX_p, WHzr_s, WHh_s, WHzr_p, WHh_p);
  const long nH = (long)NB*NN*256;
  zero_f<<<(nH + 255)/256, 256, 0, stream>>>(H, nH);
  zero_f<<<(nH/2 + 255)/256, 256, 0, stream>>>((float*)Hf, nH/2);

  // ---- precompute Px ----
  for (int t0 = 0; t0 < TT; t0 += TCH) {
    chebx<<<2*NB*TCH, 256, 0, stream>>>(xdis, xpre, Ms_s, Ms_p, XT_s, XT_p, t0);
    gemm_pre<<<224*6, 512, 0, stream>>>(
        XT_s, WX_s, KHS, 160, 6,
        XT_p, WX_p, KHP,
        Px_s + (size_t)t0*NB*NSN*NPRE, Px_p + (size_t)t0*NB*NPN*NPRE,
        bz_s, br_s, bh_s, bz_p, br_p, bh_p);
  }

  // ---- recurrence ----
  for (int t = 0; t < TT; ++t) {
    const half_t* PxS = Px_s + (size_t)t*NB*NSN*NPRE;
    const half_t* PxP = Px_p + (size_t)t*NB*NPN*NPRE;
    gemm_y<<<800 + 192, 512, 0, stream>>>(Hf_s, WHzr_s, Y_s, 2560, 20, 800,
                                          Hf_p, WHzr_p, Y_p, 1536, 12);
    contract_k<0><<<NB*4*2, 256, 0, stream>>>(Y_s, Y_p, PxS, PxP, Mbig_s, Mbig_p,
                                              H, Z, gHf_s, gHf_p, nullptr);
    gemm_y<<<400 + 96, 512, 0, stream>>>(gHf_s, WHh_s, Y_s, 1280, 10, 400,
                                         gHf_p, WHh_p, Y_p, 768, 6);
    contract_k<1><<<NB*2*2, 256, 0, stream>>>(Y_s, Y_p, PxS, PxP, Mbig_s, Mbig_p,
                                              H, Z, Hf_s, Hf_p, H);
  }
  readout_k<<<NB, 256, 0, stream>>>(H, W_ro, b_ro, W_ag, b_ag, out);
}